// Round 1
// baseline (2741.055 us; speedup 1.0000x reference)
//
#include <hip/hip_runtime.h>

#define HC 128      // hidden / latent channels
#define FIN 64
#define DHID 1024
#define ZK 134      // LAT + 6

// ---------------------------------------------------------------- utility
__global__ void k_fill(float* p, float v, int n) {
    int i = blockIdx.x * blockDim.x + threadIdx.x;
    if (i < n) p[i] = v;
}

__global__ void k_deg(const int* __restrict__ dst, float* __restrict__ deg, int E) {
    int i = blockIdx.x * blockDim.x + threadIdx.x;
    if (i < E) atomicAdd(&deg[dst[i]], 1.0f);
}

__global__ void k_rsqrt(float* p, int n) {
    int i = blockIdx.x * blockDim.x + threadIdx.x;
    if (i < n) p[i] = rsqrtf(p[i]);
}

// agg[r][c] = xW[r][c] * dinv[r]^2   (self-loop term, also initializes agg)
__global__ void k_selfloop(const float* __restrict__ xW, const float* __restrict__ dinv,
                           float* __restrict__ agg, int total) {
    int i = blockIdx.x * blockDim.x + threadIdx.x;
    if (i < total) {
        int r = i >> 7;  // /HC
        float d = dinv[r];
        agg[i] = xW[i] * d * d;
    }
}

// one wave (64 lanes) per edge; each lane handles 2 of 128 features
__global__ void k_edge_mp(const float* __restrict__ xW, const int* __restrict__ src,
                          const int* __restrict__ dst, const float* __restrict__ dinv,
                          float* __restrict__ agg, int E) {
    int gtid = blockIdx.x * blockDim.x + threadIdx.x;
    int e = gtid >> 6;
    int lane = gtid & 63;
    if (e >= E) return;
    int s = src[e], d = dst[e];
    float nrm = dinv[s] * dinv[d];
    float2 v = ((const float2*)(xW + (size_t)s * HC))[lane];
    float* o = agg + (size_t)d * HC + lane * 2;
    atomicAdd(o,     v.x * nrm);
    atomicAdd(o + 1, v.y * nrm);
}

// ---------------------------------------------------------------- batchnorm
__global__ void k_bn_reduce(const float* __restrict__ x, float* __restrict__ sum,
                            float* __restrict__ sumsq, int N) {
    int f = threadIdx.x & (HC - 1);
    int half = threadIdx.x >> 7;  // 0/1
    int rpb = (N + gridDim.x - 1) / gridDim.x;
    int r0 = blockIdx.x * rpb;
    int r1 = min(N, r0 + rpb);
    float s = 0.f, ss = 0.f;
    for (int r = r0 + half; r < r1; r += 2) {
        float v = x[(size_t)r * HC + f];
        s += v; ss += v * v;
    }
    __shared__ float sh[256], shq[256];
    sh[threadIdx.x] = s; shq[threadIdx.x] = ss;
    __syncthreads();
    if (half == 0) {
        atomicAdd(&sum[f],   sh[threadIdx.x] + sh[threadIdx.x + HC]);
        atomicAdd(&sumsq[f], shq[threadIdx.x] + shq[threadIdx.x + HC]);
    }
}

__global__ void k_bn_stats(const float* __restrict__ sum, const float* __restrict__ sumsq,
                           const float* __restrict__ gamma, const float* __restrict__ beta,
                           float* __restrict__ scale, float* __restrict__ shift, float invN) {
    int f = threadIdx.x;
    float m = sum[f] * invN;
    float var = sumsq[f] * invN - m * m;
    float istd = rsqrtf(var + 1e-5f);
    float sc = gamma[f] * istd;
    scale[f] = sc;
    shift[f] = beta[f] - m * sc;
}

template <bool RELU>
__global__ void k_bn_apply(const float* __restrict__ x, const float* __restrict__ scale,
                           const float* __restrict__ shift, float* __restrict__ y, int total) {
    int i = blockIdx.x * blockDim.x + threadIdx.x;
    if (i < total) {
        int f = i & (HC - 1);
        float v = x[i] * scale[f] + shift[f];
        if (RELU) v = fmaxf(v, 0.f);
        y[i] = v;
    }
}

// ---------------------------------------------------------------- pooling
// batch is sorted; accumulate locally, flush on segment change
__global__ void k_pool(const float* __restrict__ h, const int* __restrict__ batch,
                       float* __restrict__ pooled, float* __restrict__ cnt, int N) {
    int t = threadIdx.x;  // 0..127
    int rpb = (N + gridDim.x - 1) / gridDim.x;
    int r0 = blockIdx.x * rpb;
    int r1 = min(N, r0 + rpb);
    if (r0 >= r1) return;
    int curb = batch[r0];
    float acc = 0.f; float c = 0.f;
    for (int r = r0; r < r1; ++r) {
        int b = batch[r];
        if (b != curb) {
            atomicAdd(&pooled[curb * HC + t], acc);
            if (t == 0) atomicAdd(&cnt[curb], c);
            curb = b; acc = 0.f; c = 0.f;
        }
        acc += h[(size_t)r * HC + t];
        c += 1.f;
    }
    atomicAdd(&pooled[curb * HC + t], acc);
    if (t == 0) atomicAdd(&cnt[curb], c);
}

__global__ void k_build_z(const float* __restrict__ pooled, const float* __restrict__ cnt,
                          const float* __restrict__ origin, const float* __restrict__ dir,
                          float* __restrict__ z, int G) {
    int g = blockIdx.x;
    int t = threadIdx.x;
    if (t < HC) {
        float c = fmaxf(cnt[g], 1.0f);
        z[g * ZK + t] = pooled[g * HC + t] / c;
    } else if (t < HC + 3) {
        z[g * ZK + t] = origin[g * 3 + (t - HC)];
    } else if (t < HC + 6) {
        z[g * ZK + t] = dir[g * 3 + (t - HC - 3)];
    }
}

// ---------------------------------------------------------------- GEMM (fp32, tiled)
// C[M,N] = A[M,K] @ B[K,N]  (+bias) (+relu); 64x64 tile, BK=16, 256 thr, 4x4/thread
template <bool RELU, bool BIAS>
__global__ __launch_bounds__(256) void gemm_tiled(const float* __restrict__ A,
                                                  const float* __restrict__ B,
                                                  const float* __restrict__ bias,
                                                  float* __restrict__ C,
                                                  int M, int N, int K) {
    __shared__ float As[16][65];
    __shared__ float Bs[16][65];
    int bm = blockIdx.y * 64, bn = blockIdx.x * 64;
    int tid = threadIdx.x;
    int tc = tid & 15, tr = tid >> 4;
    float acc[4][4] = {};
    for (int k0 = 0; k0 < K; k0 += 16) {
        #pragma unroll
        for (int i = 0; i < 4; ++i) {
            int idx = tid + i * 256;
            int m = idx >> 4, kk = idx & 15;
            float v = 0.f;
            if (bm + m < M && k0 + kk < K) v = A[(size_t)(bm + m) * K + k0 + kk];
            As[kk][m] = v;
        }
        #pragma unroll
        for (int i = 0; i < 4; ++i) {
            int idx = tid + i * 256;
            int kk = idx >> 6, n = idx & 63;
            float v = 0.f;
            if (bn + n < N && k0 + kk < K) v = B[(size_t)(k0 + kk) * N + bn + n];
            Bs[kk][n] = v;
        }
        __syncthreads();
        #pragma unroll
        for (int kk = 0; kk < 16; ++kk) {
            float a[4], b[4];
            #pragma unroll
            for (int i = 0; i < 4; ++i) a[i] = As[kk][tr * 4 + i];
            #pragma unroll
            for (int j = 0; j < 4; ++j) b[j] = Bs[kk][tc * 4 + j];
            #pragma unroll
            for (int i = 0; i < 4; ++i)
                #pragma unroll
                for (int j = 0; j < 4; ++j) acc[i][j] += a[i] * b[j];
        }
        __syncthreads();
    }
    #pragma unroll
    for (int i = 0; i < 4; ++i) {
        int m = bm + tr * 4 + i;
        if (m >= M) continue;
        #pragma unroll
        for (int j = 0; j < 4; ++j) {
            int n = bn + tc * 4 + j;
            if (n >= N) continue;
            float v = acc[i][j];
            if (BIAS) v += bias[n];
            if (RELU) v = fmaxf(v, 0.f);
            C[(size_t)m * N + n] = v;
        }
    }
}

// final [G,DH] @ [DH,3] + bout
__global__ void k_dense_out(const float* __restrict__ z, const float* __restrict__ W,
                            const float* __restrict__ b, float* __restrict__ out, int K) {
    int g = blockIdx.x;
    const float* zr = z + (size_t)g * K;
    float a0 = 0.f, a1 = 0.f, a2 = 0.f;
    for (int k = threadIdx.x; k < K; k += blockDim.x) {
        float zv = zr[k];
        a0 += zv * W[k * 3 + 0];
        a1 += zv * W[k * 3 + 1];
        a2 += zv * W[k * 3 + 2];
    }
    __shared__ float s[768];
    s[threadIdx.x] = a0; s[256 + threadIdx.x] = a1; s[512 + threadIdx.x] = a2;
    __syncthreads();
    for (int off = 128; off > 0; off >>= 1) {
        if ((int)threadIdx.x < off) {
            s[threadIdx.x]       += s[threadIdx.x + off];
            s[256 + threadIdx.x] += s[256 + threadIdx.x + off];
            s[512 + threadIdx.x] += s[512 + threadIdx.x + off];
        }
        __syncthreads();
    }
    if (threadIdx.x == 0) {
        out[g * 3 + 0] = s[0]   + b[0];
        out[g * 3 + 1] = s[256] + b[1];
        out[g * 3 + 2] = s[512] + b[2];
    }
}

// ---------------------------------------------------------------- launch
extern "C" void kernel_launch(void* const* d_in, const int* in_sizes, int n_in,
                              void* d_out, int out_size, void* d_ws, size_t ws_size,
                              hipStream_t stream) {
    const float* x         = (const float*)d_in[0];
    const float* origin    = (const float*)d_in[1];
    const float* direction = (const float*)d_in[2];
    const int*   eidx      = (const int*)d_in[3];
    const int*   batch     = (const int*)d_in[4];
    const float* W1 = (const float*)d_in[5];
    const float* W2 = (const float*)d_in[7];
    const float* W3 = (const float*)d_in[9];
    const float* g1 = (const float*)d_in[11]; const float* be1 = (const float*)d_in[12];
    const float* g2 = (const float*)d_in[13]; const float* be2 = (const float*)d_in[14];
    const float* g3 = (const float*)d_in[15]; const float* be3 = (const float*)d_in[16];
    const float* Wd0 = (const float*)d_in[17]; const float* bd0 = (const float*)d_in[18];
    const float* Wd1 = (const float*)d_in[19]; const float* bd1 = (const float*)d_in[20];
    const float* Wd2 = (const float*)d_in[21]; const float* bd2 = (const float*)d_in[22];
    const float* Wout = (const float*)d_in[23]; const float* bout = (const float*)d_in[24];
    float* out = (float*)d_out;

    const int N = in_sizes[4];
    const int E = in_sizes[3] / 2;
    const int G = in_sizes[1] / 3;
    const int* src = eidx;
    const int* dst = eidx + E;

    char* ws = (char*)d_ws;
    size_t off = 0;
    auto alloc = [&](size_t nbytes) -> float* {
        float* p = (float*)(ws + off);
        off += (nbytes + 255) & ~(size_t)255;
        return p;
    };
    float* dinv     = alloc((size_t)N * 4);
    float* bufA     = alloc((size_t)N * HC * 4);
    float* bufB     = alloc((size_t)N * HC * 4);
    float* bufC     = alloc((size_t)N * HC * 4);
    float* colsum   = alloc(HC * 4);
    float* colsumsq = alloc(HC * 4);
    float* scale    = alloc(HC * 4);
    float* shift    = alloc(HC * 4);
    float* pooled   = alloc((size_t)G * HC * 4);
    float* cnt      = alloc((size_t)G * 4);
    float* zbuf     = alloc((size_t)G * ZK * 4);
    float* t0       = alloc((size_t)G * DHID * 4);
    float* t1       = alloc((size_t)G * DHID * 4);
    (void)ws_size;

    const int total = N * HC;

    // degrees (with self-loop) -> dinv
    k_fill<<<(N + 255) / 256, 256, 0, stream>>>(dinv, 1.0f, N);
    k_deg<<<(E + 255) / 256, 256, 0, stream>>>(dst, dinv, E);
    k_rsqrt<<<(N + 255) / 256, 256, 0, stream>>>(dinv, N);

    auto gcn_layer = [&](const float* hin, int K, const float* W,
                         const float* gam, const float* bet, bool relu) {
        dim3 gb(HC / 64, (N + 63) / 64);
        gemm_tiled<false, false><<<gb, 256, 0, stream>>>(hin, W, nullptr, bufA, N, HC, K);
        k_selfloop<<<(total + 255) / 256, 256, 0, stream>>>(bufA, dinv, bufB, total);
        k_edge_mp<<<((size_t)E * 64 + 255) / 256, 256, 0, stream>>>(bufA, src, dst, dinv, bufB, E);
        hipMemsetAsync(colsum, 0, HC * 4, stream);
        hipMemsetAsync(colsumsq, 0, HC * 4, stream);
        k_bn_reduce<<<256, 256, 0, stream>>>(bufB, colsum, colsumsq, N);
        k_bn_stats<<<1, HC, 0, stream>>>(colsum, colsumsq, gam, bet, scale, shift, 1.0f / N);
        if (relu)
            k_bn_apply<true><<<(total + 255) / 256, 256, 0, stream>>>(bufB, scale, shift, bufC, total);
        else
            k_bn_apply<false><<<(total + 255) / 256, 256, 0, stream>>>(bufB, scale, shift, bufC, total);
    };

    gcn_layer(x,    FIN, W1, g1, be1, true);
    gcn_layer(bufC, HC,  W2, g2, be2, true);
    gcn_layer(bufC, HC,  W3, g3, be3, false);

    // global mean pool
    hipMemsetAsync(pooled, 0, (size_t)G * HC * 4, stream);
    hipMemsetAsync(cnt, 0, (size_t)G * 4, stream);
    k_pool<<<512, HC, 0, stream>>>(bufC, batch, pooled, cnt, N);
    k_build_z<<<G, 192, 0, stream>>>(pooled, cnt, origin, direction, zbuf, G);

    // dense head
    dim3 g0(DHID / 64, (G + 63) / 64);
    gemm_tiled<true, true><<<g0, 256, 0, stream>>>(zbuf, Wd0, bd0, t0, G, DHID, ZK);
    gemm_tiled<true, true><<<g0, 256, 0, stream>>>(t0, Wd1, bd1, t1, G, DHID, DHID);
    gemm_tiled<true, true><<<g0, 256, 0, stream>>>(t1, Wd2, bd2, t0, G, DHID, DHID);
    k_dense_out<<<G, 256, 0, stream>>>(t0, Wout, bout, out, DHID);
}

// Round 2
// 1031.875 us; speedup vs baseline: 2.6564x; 2.6564x over previous
//
#include <hip/hip_runtime.h>

#define HC 128      // hidden / latent channels
#define FIN 64
#define DHID 1024
#define ZK 134      // LAT + 6

// ---------------------------------------------------------------- small utils
__global__ void k_zero_i(int* p, int n) {
    int i = blockIdx.x * blockDim.x + threadIdx.x;
    if (i < n) p[i] = 0;
}

__global__ void k_deg_i(const int* __restrict__ dst, int* __restrict__ cnt, int E) {
    int i = blockIdx.x * blockDim.x + threadIdx.x;
    if (i < E) atomicAdd(&cnt[dst[i]], 1);
}

__global__ void k_dinv(const int* __restrict__ cnt, float* __restrict__ dinv, int N) {
    int i = blockIdx.x * blockDim.x + threadIdx.x;
    if (i < N) dinv[i] = rsqrtf((float)cnt[i] + 1.0f);
}

// ---------------------------------------------------------------- scan (CSR row offsets)
__global__ void k_scan1(const int* __restrict__ cnt, int* __restrict__ part,
                        int* __restrict__ bsum, int N) {
    __shared__ int sh[256];
    int t = threadIdx.x, i = blockIdx.x * 256 + t;
    int v = (i < N) ? cnt[i] : 0;
    sh[t] = v; __syncthreads();
    #pragma unroll
    for (int off = 1; off < 256; off <<= 1) {
        int tv = (t >= off) ? sh[t - off] : 0;
        __syncthreads();
        sh[t] += tv;
        __syncthreads();
    }
    if (i < N) part[i] = sh[t] - v;          // exclusive within block
    if (t == 255) bsum[blockIdx.x] = sh[255];
}

__global__ void k_scan2(int* __restrict__ bsum, int nb) {
    __shared__ int sh[256];
    int t = threadIdx.x;
    int v = (t < nb) ? bsum[t] : 0;
    sh[t] = v; __syncthreads();
    #pragma unroll
    for (int off = 1; off < 256; off <<= 1) {
        int tv = (t >= off) ? sh[t - off] : 0;
        __syncthreads();
        sh[t] += tv;
        __syncthreads();
    }
    if (t < nb) bsum[t] = sh[t] - v;         // exclusive
}

__global__ void k_scan3(const int* __restrict__ part, const int* __restrict__ bsum,
                        int* __restrict__ row_start, int N) {
    int i = blockIdx.x * 256 + threadIdx.x;
    if (i < N) row_start[i] = part[i] + bsum[blockIdx.x];
}

// scatter edges into CSR order keyed by dst; precompute per-edge norm
__global__ void k_scatter(const int* __restrict__ src, const int* __restrict__ dst,
                          const float* __restrict__ dinv, const int* __restrict__ row_start,
                          int* __restrict__ cur, int* __restrict__ csr_src,
                          float* __restrict__ csr_nrm, int E) {
    int e = blockIdx.x * blockDim.x + threadIdx.x;
    if (e >= E) return;
    int s = src[e], d = dst[e];
    int pos = row_start[d] + atomicAdd(&cur[d], 1);
    csr_src[pos] = s;
    csr_nrm[pos] = dinv[s] * dinv[d];
}

// ---------------------------------------------------------------- gather aggregation
// one wave per node: acc = xW[n]*dinv[n]^2 + sum_{incoming e} xW[src]*nrm
__global__ __launch_bounds__(256) void k_gather(const float* __restrict__ xW,
                                                const int* __restrict__ csr_src,
                                                const float* __restrict__ csr_nrm,
                                                const int* __restrict__ row_start,
                                                const int* __restrict__ cnt,
                                                const float* __restrict__ dinv,
                                                float* __restrict__ agg, int N) {
    int node = blockIdx.x * 4 + (threadIdx.x >> 6);
    int lane = threadIdx.x & 63;
    if (node >= N) return;
    int beg = row_start[node];
    int end = beg + cnt[node];
    float d = dinv[node];
    float2 acc = ((const float2*)(xW + (size_t)node * HC))[lane];
    acc.x *= d * d; acc.y *= d * d;
    int j = beg;
    for (; j + 2 <= end; j += 2) {
        int   s0 = csr_src[j],     s1 = csr_src[j + 1];
        float n0 = csr_nrm[j],     n1 = csr_nrm[j + 1];
        float2 v0 = ((const float2*)(xW + (size_t)s0 * HC))[lane];
        float2 v1 = ((const float2*)(xW + (size_t)s1 * HC))[lane];
        acc.x += v0.x * n0 + v1.x * n1;
        acc.y += v0.y * n0 + v1.y * n1;
    }
    if (j < end) {
        int s0 = csr_src[j];
        float n0 = csr_nrm[j];
        float2 v0 = ((const float2*)(xW + (size_t)s0 * HC))[lane];
        acc.x += v0.x * n0;
        acc.y += v0.y * n0;
    }
    ((float2*)(agg + (size_t)node * HC))[lane] = acc;
}

// ---------------------------------------------------------------- batchnorm
__global__ void k_bn_reduce(const float* __restrict__ x, float* __restrict__ sum,
                            float* __restrict__ sumsq, int N) {
    int f = threadIdx.x & (HC - 1);
    int half = threadIdx.x >> 7;  // 0/1
    int rpb = (N + gridDim.x - 1) / gridDim.x;
    int r0 = blockIdx.x * rpb;
    int r1 = min(N, r0 + rpb);
    float s = 0.f, ss = 0.f;
    for (int r = r0 + half; r < r1; r += 2) {
        float v = x[(size_t)r * HC + f];
        s += v; ss += v * v;
    }
    __shared__ float sh[256], shq[256];
    sh[threadIdx.x] = s; shq[threadIdx.x] = ss;
    __syncthreads();
    if (half == 0) {
        atomicAdd(&sum[f],   sh[threadIdx.x] + sh[threadIdx.x + HC]);
        atomicAdd(&sumsq[f], shq[threadIdx.x] + shq[threadIdx.x + HC]);
    }
}

__global__ void k_bn_stats(const float* __restrict__ sum, const float* __restrict__ sumsq,
                           const float* __restrict__ gamma, const float* __restrict__ beta,
                           float* __restrict__ scale, float* __restrict__ shift, float invN) {
    int f = threadIdx.x;
    float m = sum[f] * invN;
    float var = sumsq[f] * invN - m * m;
    float istd = rsqrtf(var + 1e-5f);
    float sc = gamma[f] * istd;
    scale[f] = sc;
    shift[f] = beta[f] - m * sc;
}

template <bool RELU>
__global__ void k_bn_apply(const float* __restrict__ x, const float* __restrict__ scale,
                           const float* __restrict__ shift, float* __restrict__ y, int total) {
    int i = blockIdx.x * blockDim.x + threadIdx.x;
    if (i < total) {
        int f = i & (HC - 1);
        float v = x[i] * scale[f] + shift[f];
        if (RELU) v = fmaxf(v, 0.f);
        y[i] = v;
    }
}

// ---------------------------------------------------------------- pooling
__global__ void k_pool(const float* __restrict__ h, const int* __restrict__ batch,
                       float* __restrict__ pooled, float* __restrict__ cnt, int N) {
    int t = threadIdx.x;  // 0..127
    int rpb = (N + gridDim.x - 1) / gridDim.x;
    int r0 = blockIdx.x * rpb;
    int r1 = min(N, r0 + rpb);
    if (r0 >= r1) return;
    int curb = batch[r0];
    float acc = 0.f; float c = 0.f;
    for (int r = r0; r < r1; ++r) {
        int b = batch[r];
        if (b != curb) {
            atomicAdd(&pooled[curb * HC + t], acc);
            if (t == 0) atomicAdd(&cnt[curb], c);
            curb = b; acc = 0.f; c = 0.f;
        }
        acc += h[(size_t)r * HC + t];
        c += 1.f;
    }
    atomicAdd(&pooled[curb * HC + t], acc);
    if (t == 0) atomicAdd(&cnt[curb], c);
}

__global__ void k_build_z(const float* __restrict__ pooled, const float* __restrict__ cnt,
                          const float* __restrict__ origin, const float* __restrict__ dir,
                          float* __restrict__ z, int G) {
    int g = blockIdx.x;
    int t = threadIdx.x;
    if (t < HC) {
        float c = fmaxf(cnt[g], 1.0f);
        z[g * ZK + t] = pooled[g * HC + t] / c;
    } else if (t < HC + 3) {
        z[g * ZK + t] = origin[g * 3 + (t - HC)];
    } else if (t < HC + 6) {
        z[g * ZK + t] = dir[g * 3 + (t - HC - 3)];
    }
}

// ---------------------------------------------------------------- GEMM 128x128 tile
// C[M,N] = A[M,K] @ B[K,N]; 256 thr, 8x8 micro-tile, BK=16
template <bool RELU, bool BIAS>
__global__ __launch_bounds__(256) void gemm128(const float* __restrict__ A,
                                               const float* __restrict__ B,
                                               const float* __restrict__ bias,
                                               float* __restrict__ C,
                                               int M, int N, int K) {
    __shared__ float As[16][132];
    __shared__ float Bs[16][132];
    int bm = blockIdx.y * 128, bn = blockIdx.x * 128;
    int tid = threadIdx.x;
    int tx = tid & 15, ty = tid >> 4;
    float acc[8][8] = {};
    for (int k0 = 0; k0 < K; k0 += 16) {
        #pragma unroll
        for (int i = 0; i < 8; ++i) {
            int idx = tid + i * 256;
            int m = idx >> 4, kk = idx & 15;
            float v = 0.f;
            int gm = bm + m;
            if (gm < M && k0 + kk < K) v = A[(size_t)gm * K + k0 + kk];
            As[kk][m] = v;
        }
        #pragma unroll
        for (int i = 0; i < 8; ++i) {
            int idx = tid + i * 256;
            int kk = idx >> 7, n = idx & 127;
            float v = 0.f;
            int gn = bn + n;
            if (gn < N && k0 + kk < K) v = B[(size_t)(k0 + kk) * N + gn];
            Bs[kk][n] = v;
        }
        __syncthreads();
        #pragma unroll
        for (int kk = 0; kk < 16; ++kk) {
            float a[8], b[8];
            #pragma unroll
            for (int i = 0; i < 8; ++i) a[i] = As[kk][ty * 8 + i];
            #pragma unroll
            for (int j = 0; j < 8; ++j) b[j] = Bs[kk][tx * 8 + j];
            #pragma unroll
            for (int i = 0; i < 8; ++i)
                #pragma unroll
                for (int j = 0; j < 8; ++j) acc[i][j] += a[i] * b[j];
        }
        __syncthreads();
    }
    #pragma unroll
    for (int i = 0; i < 8; ++i) {
        int m = bm + ty * 8 + i;
        if (m >= M) continue;
        #pragma unroll
        for (int j = 0; j < 8; ++j) {
            int n = bn + tx * 8 + j;
            if (n >= N) continue;
            float v = acc[i][j];
            if (BIAS) v += bias[n];
            if (RELU) v = fmaxf(v, 0.f);
            C[(size_t)m * N + n] = v;
        }
    }
}

// 64x64 tile GEMM for the dense head (arbitrary K, small M)
template <bool RELU, bool BIAS>
__global__ __launch_bounds__(256) void gemm_tiled(const float* __restrict__ A,
                                                  const float* __restrict__ B,
                                                  const float* __restrict__ bias,
                                                  float* __restrict__ C,
                                                  int M, int N, int K) {
    __shared__ float As[16][65];
    __shared__ float Bs[16][65];
    int bm = blockIdx.y * 64, bn = blockIdx.x * 64;
    int tid = threadIdx.x;
    int tc = tid & 15, tr = tid >> 4;
    float acc[4][4] = {};
    for (int k0 = 0; k0 < K; k0 += 16) {
        #pragma unroll
        for (int i = 0; i < 4; ++i) {
            int idx = tid + i * 256;
            int m = idx >> 4, kk = idx & 15;
            float v = 0.f;
            if (bm + m < M && k0 + kk < K) v = A[(size_t)(bm + m) * K + k0 + kk];
            As[kk][m] = v;
        }
        #pragma unroll
        for (int i = 0; i < 4; ++i) {
            int idx = tid + i * 256;
            int kk = idx >> 6, n = idx & 63;
            float v = 0.f;
            if (bn + n < N && k0 + kk < K) v = B[(size_t)(k0 + kk) * N + bn + n];
            Bs[kk][n] = v;
        }
        __syncthreads();
        #pragma unroll
        for (int kk = 0; kk < 16; ++kk) {
            float a[4], b[4];
            #pragma unroll
            for (int i = 0; i < 4; ++i) a[i] = As[kk][tr * 4 + i];
            #pragma unroll
            for (int j = 0; j < 4; ++j) b[j] = Bs[kk][tc * 4 + j];
            #pragma unroll
            for (int i = 0; i < 4; ++i)
                #pragma unroll
                for (int j = 0; j < 4; ++j) acc[i][j] += a[i] * b[j];
        }
        __syncthreads();
    }
    #pragma unroll
    for (int i = 0; i < 4; ++i) {
        int m = bm + tr * 4 + i;
        if (m >= M) continue;
        #pragma unroll
        for (int j = 0; j < 4; ++j) {
            int n = bn + tc * 4 + j;
            if (n >= N) continue;
            float v = acc[i][j];
            if (BIAS) v += bias[n];
            if (RELU) v = fmaxf(v, 0.f);
            C[(size_t)m * N + n] = v;
        }
    }
}

// final [G,DH] @ [DH,3] + bout
__global__ void k_dense_out(const float* __restrict__ z, const float* __restrict__ W,
                            const float* __restrict__ b, float* __restrict__ out, int K) {
    int g = blockIdx.x;
    const float* zr = z + (size_t)g * K;
    float a0 = 0.f, a1 = 0.f, a2 = 0.f;
    for (int k = threadIdx.x; k < K; k += blockDim.x) {
        float zv = zr[k];
        a0 += zv * W[k * 3 + 0];
        a1 += zv * W[k * 3 + 1];
        a2 += zv * W[k * 3 + 2];
    }
    __shared__ float s[768];
    s[threadIdx.x] = a0; s[256 + threadIdx.x] = a1; s[512 + threadIdx.x] = a2;
    __syncthreads();
    for (int off = 128; off > 0; off >>= 1) {
        if ((int)threadIdx.x < off) {
            s[threadIdx.x]       += s[threadIdx.x + off];
            s[256 + threadIdx.x] += s[256 + threadIdx.x + off];
            s[512 + threadIdx.x] += s[512 + threadIdx.x + off];
        }
        __syncthreads();
    }
    if (threadIdx.x == 0) {
        out[g * 3 + 0] = s[0]   + b[0];
        out[g * 3 + 1] = s[256] + b[1];
        out[g * 3 + 2] = s[512] + b[2];
    }
}

// ---------------------------------------------------------------- launch
extern "C" void kernel_launch(void* const* d_in, const int* in_sizes, int n_in,
                              void* d_out, int out_size, void* d_ws, size_t ws_size,
                              hipStream_t stream) {
    const float* x         = (const float*)d_in[0];
    const float* origin    = (const float*)d_in[1];
    const float* direction = (const float*)d_in[2];
    const int*   eidx      = (const int*)d_in[3];
    const int*   batch     = (const int*)d_in[4];
    const float* W1 = (const float*)d_in[5];
    const float* W2 = (const float*)d_in[7];
    const float* W3 = (const float*)d_in[9];
    const float* g1 = (const float*)d_in[11]; const float* be1 = (const float*)d_in[12];
    const float* g2 = (const float*)d_in[13]; const float* be2 = (const float*)d_in[14];
    const float* g3 = (const float*)d_in[15]; const float* be3 = (const float*)d_in[16];
    const float* Wd0 = (const float*)d_in[17]; const float* bd0 = (const float*)d_in[18];
    const float* Wd1 = (const float*)d_in[19]; const float* bd1 = (const float*)d_in[20];
    const float* Wd2 = (const float*)d_in[21]; const float* bd2 = (const float*)d_in[22];
    const float* Wout = (const float*)d_in[23]; const float* bout = (const float*)d_in[24];
    float* out = (float*)d_out;

    const int N = in_sizes[4];
    const int E = in_sizes[3] / 2;
    const int G = in_sizes[1] / 3;
    const int* src = eidx;
    const int* dst = eidx + E;

    char* ws = (char*)d_ws;
    size_t off = 0;
    auto alloc = [&](size_t nbytes) -> void* {
        void* p = (void*)(ws + off);
        off += (nbytes + 255) & ~(size_t)255;
        return p;
    };
    float* dinv     = (float*)alloc((size_t)N * 4);
    int*   degcnt   = (int*)alloc((size_t)N * 4);
    int*   part     = (int*)alloc((size_t)N * 4);
    int*   bsum     = (int*)alloc(256 * 4);
    int*   row_start= (int*)alloc((size_t)N * 4);
    int*   cur      = (int*)alloc((size_t)N * 4);
    int*   csr_src  = (int*)alloc((size_t)E * 4);
    float* csr_nrm  = (float*)alloc((size_t)E * 4);
    float* bufA     = (float*)alloc((size_t)N * HC * 4);
    float* bufB     = (float*)alloc((size_t)N * HC * 4);
    float* bufC     = (float*)alloc((size_t)N * HC * 4);
    float* colsum   = (float*)alloc(HC * 4);
    float* colsumsq = (float*)alloc(HC * 4);
    float* scale    = (float*)alloc(HC * 4);
    float* shift    = (float*)alloc(HC * 4);
    float* pooled   = (float*)alloc((size_t)G * HC * 4);
    float* cntf     = (float*)alloc((size_t)G * 4);
    float* zbuf     = (float*)alloc((size_t)G * ZK * 4);
    float* t0       = (float*)alloc((size_t)G * DHID * 4);
    float* t1       = (float*)alloc((size_t)G * DHID * 4);
    (void)ws_size;

    const int total = N * HC;
    const int nScanBlk = (N + 255) / 256;

    // ---- CSR build (once) ----
    k_zero_i<<<(N + 255) / 256, 256, 0, stream>>>(degcnt, N);
    k_deg_i<<<(E + 255) / 256, 256, 0, stream>>>(dst, degcnt, E);
    k_dinv<<<(N + 255) / 256, 256, 0, stream>>>(degcnt, dinv, N);
    k_scan1<<<nScanBlk, 256, 0, stream>>>(degcnt, part, bsum, N);
    k_scan2<<<1, 256, 0, stream>>>(bsum, nScanBlk);
    k_scan3<<<nScanBlk, 256, 0, stream>>>(part, bsum, row_start, N);
    k_zero_i<<<(N + 255) / 256, 256, 0, stream>>>(cur, N);
    k_scatter<<<(E + 255) / 256, 256, 0, stream>>>(src, dst, dinv, row_start, cur,
                                                   csr_src, csr_nrm, E);

    auto gcn_layer = [&](const float* hin, int K, const float* W,
                         const float* gam, const float* bet, bool relu) {
        dim3 gb(1, (N + 127) / 128);
        gemm128<false, false><<<gb, 256, 0, stream>>>(hin, W, nullptr, bufA, N, HC, K);
        k_gather<<<(N + 3) / 4, 256, 0, stream>>>(bufA, csr_src, csr_nrm, row_start,
                                                  degcnt, dinv, bufB, N);
        hipMemsetAsync(colsum, 0, HC * 4, stream);
        hipMemsetAsync(colsumsq, 0, HC * 4, stream);
        k_bn_reduce<<<256, 256, 0, stream>>>(bufB, colsum, colsumsq, N);
        k_bn_stats<<<1, HC, 0, stream>>>(colsum, colsumsq, gam, bet, scale, shift, 1.0f / N);
        if (relu)
            k_bn_apply<true><<<(total + 255) / 256, 256, 0, stream>>>(bufB, scale, shift, bufC, total);
        else
            k_bn_apply<false><<<(total + 255) / 256, 256, 0, stream>>>(bufB, scale, shift, bufC, total);
    };

    gcn_layer(x,    FIN, W1, g1, be1, true);
    gcn_layer(bufC, HC,  W2, g2, be2, true);
    gcn_layer(bufC, HC,  W3, g3, be3, false);

    // global mean pool
    hipMemsetAsync(pooled, 0, (size_t)G * HC * 4, stream);
    hipMemsetAsync(cntf, 0, (size_t)G * 4, stream);
    k_pool<<<512, HC, 0, stream>>>(bufC, batch, pooled, cntf, N);
    k_build_z<<<G, 192, 0, stream>>>(pooled, cntf, origin, direction, zbuf, G);

    // dense head
    dim3 g0(DHID / 64, (G + 63) / 64);
    gemm_tiled<true, true><<<g0, 256, 0, stream>>>(zbuf, Wd0, bd0, t0, G, DHID, ZK);
    gemm_tiled<true, true><<<g0, 256, 0, stream>>>(t0, Wd1, bd1, t1, G, DHID, DHID);
    gemm_tiled<true, true><<<g0, 256, 0, stream>>>(t1, Wd2, bd2, t0, G, DHID, DHID);
    k_dense_out<<<G, 256, 0, stream>>>(t0, Wout, bout, out, DHID);
}

// Round 3
// 726.137 us; speedup vs baseline: 3.7748x; 1.4210x over previous
//
#include <hip/hip_runtime.h>

#define HC 128      // hidden / latent channels
#define FIN 64
#define DHID 1024
#define ZK 134      // LAT + 6

// ---------------------------------------------------------------- small utils
__global__ void k_zero_i(int* p, int n) {
    int i = blockIdx.x * blockDim.x + threadIdx.x;
    if (i < n) p[i] = 0;
}

__global__ void k_deg_i(const int* __restrict__ dst, int* __restrict__ cnt, int E) {
    int i = blockIdx.x * blockDim.x + threadIdx.x;
    if (i < E) atomicAdd(&cnt[dst[i]], 1);
}

__global__ void k_dinv(const int* __restrict__ cnt, float* __restrict__ dinv, int N) {
    int i = blockIdx.x * blockDim.x + threadIdx.x;
    if (i < N) dinv[i] = rsqrtf((float)cnt[i] + 1.0f);
}

// ---------------------------------------------------------------- scan (CSR row offsets)
__global__ void k_scan1(const int* __restrict__ cnt, int* __restrict__ part,
                        int* __restrict__ bsum, int N) {
    __shared__ int sh[256];
    int t = threadIdx.x, i = blockIdx.x * 256 + t;
    int v = (i < N) ? cnt[i] : 0;
    sh[t] = v; __syncthreads();
    #pragma unroll
    for (int off = 1; off < 256; off <<= 1) {
        int tv = (t >= off) ? sh[t - off] : 0;
        __syncthreads();
        sh[t] += tv;
        __syncthreads();
    }
    if (i < N) part[i] = sh[t] - v;          // exclusive within block
    if (t == 255) bsum[blockIdx.x] = sh[255];
}

__global__ void k_scan2(int* __restrict__ bsum, int nb) {
    __shared__ int sh[256];
    int t = threadIdx.x;
    int v = (t < nb) ? bsum[t] : 0;
    sh[t] = v; __syncthreads();
    #pragma unroll
    for (int off = 1; off < 256; off <<= 1) {
        int tv = (t >= off) ? sh[t - off] : 0;
        __syncthreads();
        sh[t] += tv;
        __syncthreads();
    }
    if (t < nb) bsum[t] = sh[t] - v;         // exclusive
}

__global__ void k_scan3(const int* __restrict__ part, const int* __restrict__ bsum,
                        int* __restrict__ row_start, int N) {
    int i = blockIdx.x * 256 + threadIdx.x;
    if (i < N) row_start[i] = part[i] + bsum[blockIdx.x];
}

// scatter edges into CSR order keyed by dst; precompute per-edge norm
__global__ void k_scatter(const int* __restrict__ src, const int* __restrict__ dst,
                          const float* __restrict__ dinv, const int* __restrict__ row_start,
                          int* __restrict__ cur, int* __restrict__ csr_src,
                          float* __restrict__ csr_nrm, int E) {
    int e = blockIdx.x * blockDim.x + threadIdx.x;
    if (e >= E) return;
    int s = src[e], d = dst[e];
    int pos = row_start[d] + atomicAdd(&cur[d], 1);
    csr_src[pos] = s;
    csr_nrm[pos] = dinv[s] * dinv[d];
}

// ---------------------------------------------------------------- gather aggregation
// one wave per node: acc = xW[n]*dinv[n]^2 + sum_{incoming e} xW[src]*nrm
__global__ __launch_bounds__(256) void k_gather(const float* __restrict__ xW,
                                                const int* __restrict__ csr_src,
                                                const float* __restrict__ csr_nrm,
                                                const int* __restrict__ row_start,
                                                const int* __restrict__ cnt,
                                                const float* __restrict__ dinv,
                                                float* __restrict__ agg, int N) {
    int node = blockIdx.x * 4 + (threadIdx.x >> 6);
    int lane = threadIdx.x & 63;
    if (node >= N) return;
    int beg = row_start[node];
    int end = beg + cnt[node];
    float d = dinv[node];
    float2 acc = ((const float2*)(xW + (size_t)node * HC))[lane];
    acc.x *= d * d; acc.y *= d * d;
    int j = beg;
    for (; j + 2 <= end; j += 2) {
        int   s0 = csr_src[j],     s1 = csr_src[j + 1];
        float n0 = csr_nrm[j],     n1 = csr_nrm[j + 1];
        float2 v0 = ((const float2*)(xW + (size_t)s0 * HC))[lane];
        float2 v1 = ((const float2*)(xW + (size_t)s1 * HC))[lane];
        acc.x += v0.x * n0 + v1.x * n1;
        acc.y += v0.y * n0 + v1.y * n1;
    }
    if (j < end) {
        int s0 = csr_src[j];
        float n0 = csr_nrm[j];
        float2 v0 = ((const float2*)(xW + (size_t)s0 * HC))[lane];
        acc.x += v0.x * n0;
        acc.y += v0.y * n0;
    }
    ((float2*)(agg + (size_t)node * HC))[lane] = acc;
}

// ---------------------------------------------------------------- batchnorm
__global__ void k_bn_reduce(const float* __restrict__ x, float* __restrict__ sum,
                            float* __restrict__ sumsq, int N) {
    int f = threadIdx.x & (HC - 1);
    int half = threadIdx.x >> 7;  // 0/1
    int rpb = (N + gridDim.x - 1) / gridDim.x;
    int r0 = blockIdx.x * rpb;
    int r1 = min(N, r0 + rpb);
    float s = 0.f, ss = 0.f;
    for (int r = r0 + half; r < r1; r += 2) {
        float v = x[(size_t)r * HC + f];
        s += v; ss += v * v;
    }
    __shared__ float sh[256], shq[256];
    sh[threadIdx.x] = s; shq[threadIdx.x] = ss;
    __syncthreads();
    if (half == 0) {
        atomicAdd(&sum[f],   sh[threadIdx.x] + sh[threadIdx.x + HC]);
        atomicAdd(&sumsq[f], shq[threadIdx.x] + shq[threadIdx.x + HC]);
    }
}

__global__ void k_bn_stats(const float* __restrict__ sum, const float* __restrict__ sumsq,
                           const float* __restrict__ gamma, const float* __restrict__ beta,
                           float* __restrict__ scale, float* __restrict__ shift, float invN) {
    int f = threadIdx.x;
    float m = sum[f] * invN;
    float var = sumsq[f] * invN - m * m;
    float istd = rsqrtf(var + 1e-5f);
    float sc = gamma[f] * istd;
    scale[f] = sc;
    shift[f] = beta[f] - m * sc;
}

template <bool RELU>
__global__ void k_bn_apply(const float* __restrict__ x, const float* __restrict__ scale,
                           const float* __restrict__ shift, float* __restrict__ y, int total) {
    int i = blockIdx.x * blockDim.x + threadIdx.x;
    if (i < total) {
        int f = i & (HC - 1);
        float v = x[i] * scale[f] + shift[f];
        if (RELU) v = fmaxf(v, 0.f);
        y[i] = v;
    }
}

// ---------------------------------------------------------------- pooling
__global__ void k_pool(const float* __restrict__ h, const int* __restrict__ batch,
                       float* __restrict__ pooled, float* __restrict__ cnt, int N) {
    int t = threadIdx.x;  // 0..127
    int rpb = (N + gridDim.x - 1) / gridDim.x;
    int r0 = blockIdx.x * rpb;
    int r1 = min(N, r0 + rpb);
    if (r0 >= r1) return;
    int curb = batch[r0];
    float acc = 0.f; float c = 0.f;
    for (int r = r0; r < r1; ++r) {
        int b = batch[r];
        if (b != curb) {
            atomicAdd(&pooled[curb * HC + t], acc);
            if (t == 0) atomicAdd(&cnt[curb], c);
            curb = b; acc = 0.f; c = 0.f;
        }
        acc += h[(size_t)r * HC + t];
        c += 1.f;
    }
    atomicAdd(&pooled[curb * HC + t], acc);
    if (t == 0) atomicAdd(&cnt[curb], c);
}

__global__ void k_build_z(const float* __restrict__ pooled, const float* __restrict__ cnt,
                          const float* __restrict__ origin, const float* __restrict__ dir,
                          float* __restrict__ z, int G) {
    int g = blockIdx.x;
    int t = threadIdx.x;
    if (t < HC) {
        float c = fmaxf(cnt[g], 1.0f);
        z[g * ZK + t] = pooled[g * HC + t] / c;
    } else if (t < HC + 3) {
        z[g * ZK + t] = origin[g * 3 + (t - HC)];
    } else if (t < HC + 6) {
        z[g * ZK + t] = dir[g * 3 + (t - HC - 3)];
    }
}

// ---------------------------------------------------------------- GEMM 128x128 tile (node features)
template <bool RELU, bool BIAS>
__global__ __launch_bounds__(256) void gemm128(const float* __restrict__ A,
                                               const float* __restrict__ B,
                                               const float* __restrict__ bias,
                                               float* __restrict__ C,
                                               int M, int N, int K) {
    __shared__ float As[16][132];
    __shared__ float Bs[16][132];
    int bm = blockIdx.y * 128, bn = blockIdx.x * 128;
    int tid = threadIdx.x;
    int tx = tid & 15, ty = tid >> 4;
    float acc[8][8] = {};
    for (int k0 = 0; k0 < K; k0 += 16) {
        #pragma unroll
        for (int i = 0; i < 8; ++i) {
            int idx = tid + i * 256;
            int m = idx >> 4, kk = idx & 15;
            float v = 0.f;
            int gm = bm + m;
            if (gm < M && k0 + kk < K) v = A[(size_t)gm * K + k0 + kk];
            As[kk][m] = v;
        }
        #pragma unroll
        for (int i = 0; i < 8; ++i) {
            int idx = tid + i * 256;
            int kk = idx >> 7, n = idx & 127;
            float v = 0.f;
            int gn = bn + n;
            if (gn < N && k0 + kk < K) v = B[(size_t)(k0 + kk) * N + gn];
            Bs[kk][n] = v;
        }
        __syncthreads();
        #pragma unroll
        for (int kk = 0; kk < 16; ++kk) {
            float a[8], b[8];
            #pragma unroll
            for (int i = 0; i < 8; ++i) a[i] = As[kk][ty * 8 + i];
            #pragma unroll
            for (int j = 0; j < 8; ++j) b[j] = Bs[kk][tx * 8 + j];
            #pragma unroll
            for (int i = 0; i < 8; ++i)
                #pragma unroll
                for (int j = 0; j < 8; ++j) acc[i][j] += a[i] * b[j];
        }
        __syncthreads();
    }
    #pragma unroll
    for (int i = 0; i < 8; ++i) {
        int m = bm + ty * 8 + i;
        if (m >= M) continue;
        #pragma unroll
        for (int j = 0; j < 8; ++j) {
            int n = bn + tx * 8 + j;
            if (n >= N) continue;
            float v = acc[i][j];
            if (BIAS) v += bias[n];
            if (RELU) v = fmaxf(v, 0.f);
            C[(size_t)m * N + n] = v;
        }
    }
}

// ---------------------------------------------------------------- split-K GEMM (dense head)
// partial C[z][M,N] for K-slice z; 64x64 tile, BK=16, 4x4 micro-tile
__global__ __launch_bounds__(256) void gemm_splitk(const float* __restrict__ A,
                                                   const float* __restrict__ B,
                                                   float* __restrict__ Cpart,
                                                   int M, int N, int K, int slice) {
    __shared__ float As[16][68];
    __shared__ float Bs[16][68];
    int z = blockIdx.z;
    int kbeg = z * slice;
    int kend = min(K, kbeg + slice);
    int bm = blockIdx.y * 64, bn = blockIdx.x * 64;
    int tid = threadIdx.x;
    int tc = tid & 15, tr = tid >> 4;
    float acc[4][4] = {};
    for (int k0 = kbeg; k0 < kend; k0 += 16) {
        #pragma unroll
        for (int i = 0; i < 4; ++i) {
            int idx = tid + i * 256;
            int m = idx >> 4, kk = idx & 15;
            float v = 0.f;
            if (bm + m < M && k0 + kk < kend) v = A[(size_t)(bm + m) * K + k0 + kk];
            As[kk][m] = v;
        }
        #pragma unroll
        for (int i = 0; i < 4; ++i) {
            int idx = tid + i * 256;
            int kk = idx >> 6, n = idx & 63;
            float v = 0.f;
            if (bn + n < N && k0 + kk < kend) v = B[(size_t)(k0 + kk) * N + bn + n];
            Bs[kk][n] = v;
        }
        __syncthreads();
        #pragma unroll
        for (int kk = 0; kk < 16; ++kk) {
            float a[4], b[4];
            #pragma unroll
            for (int i = 0; i < 4; ++i) a[i] = As[kk][tr * 4 + i];
            #pragma unroll
            for (int j = 0; j < 4; ++j) b[j] = Bs[kk][tc * 4 + j];
            #pragma unroll
            for (int i = 0; i < 4; ++i)
                #pragma unroll
                for (int j = 0; j < 4; ++j) acc[i][j] += a[i] * b[j];
        }
        __syncthreads();
    }
    float* Cz = Cpart + (size_t)z * M * N;
    #pragma unroll
    for (int i = 0; i < 4; ++i) {
        int m = bm + tr * 4 + i;
        if (m >= M) continue;
        #pragma unroll
        for (int j = 0; j < 4; ++j) {
            int n = bn + tc * 4 + j;
            if (n >= N) continue;
            Cz[(size_t)m * N + n] = acc[i][j];
        }
    }
}

// sum NZ partials + bias (+relu); N must be a power of two (here DHID)
template <bool RELU>
__global__ void k_reduce_br(const float* __restrict__ part, const float* __restrict__ bias,
                            float* __restrict__ C, int MN, int Nmask, int NZ) {
    int i = (blockIdx.x * blockDim.x + threadIdx.x) * 4;
    if (i >= MN) return;
    float4 acc = *(const float4*)(part + i);
    for (int zz = 1; zz < NZ; ++zz) {
        float4 p = *(const float4*)(part + (size_t)zz * MN + i);
        acc.x += p.x; acc.y += p.y; acc.z += p.z; acc.w += p.w;
    }
    int n = i & Nmask;
    acc.x += bias[n]; acc.y += bias[n + 1]; acc.z += bias[n + 2]; acc.w += bias[n + 3];
    if (RELU) {
        acc.x = fmaxf(acc.x, 0.f); acc.y = fmaxf(acc.y, 0.f);
        acc.z = fmaxf(acc.z, 0.f); acc.w = fmaxf(acc.w, 0.f);
    }
    *(float4*)(C + i) = acc;
}

// final [G,DH] @ [DH,3] + bout
__global__ void k_dense_out(const float* __restrict__ z, const float* __restrict__ W,
                            const float* __restrict__ b, float* __restrict__ out, int K) {
    int g = blockIdx.x;
    const float* zr = z + (size_t)g * K;
    float a0 = 0.f, a1 = 0.f, a2 = 0.f;
    for (int k = threadIdx.x; k < K; k += blockDim.x) {
        float zv = zr[k];
        a0 += zv * W[k * 3 + 0];
        a1 += zv * W[k * 3 + 1];
        a2 += zv * W[k * 3 + 2];
    }
    __shared__ float s[768];
    s[threadIdx.x] = a0; s[256 + threadIdx.x] = a1; s[512 + threadIdx.x] = a2;
    __syncthreads();
    for (int off = 128; off > 0; off >>= 1) {
        if ((int)threadIdx.x < off) {
            s[threadIdx.x]       += s[threadIdx.x + off];
            s[256 + threadIdx.x] += s[256 + threadIdx.x + off];
            s[512 + threadIdx.x] += s[512 + threadIdx.x + off];
        }
        __syncthreads();
    }
    if (threadIdx.x == 0) {
        out[g * 3 + 0] = s[0]   + b[0];
        out[g * 3 + 1] = s[256] + b[1];
        out[g * 3 + 2] = s[512] + b[2];
    }
}

// ---------------------------------------------------------------- launch
extern "C" void kernel_launch(void* const* d_in, const int* in_sizes, int n_in,
                              void* d_out, int out_size, void* d_ws, size_t ws_size,
                              hipStream_t stream) {
    const float* x         = (const float*)d_in[0];
    const float* origin    = (const float*)d_in[1];
    const float* direction = (const float*)d_in[2];
    const int*   eidx      = (const int*)d_in[3];
    const int*   batch     = (const int*)d_in[4];
    const float* W1 = (const float*)d_in[5];
    const float* W2 = (const float*)d_in[7];
    const float* W3 = (const float*)d_in[9];
    const float* g1 = (const float*)d_in[11]; const float* be1 = (const float*)d_in[12];
    const float* g2 = (const float*)d_in[13]; const float* be2 = (const float*)d_in[14];
    const float* g3 = (const float*)d_in[15]; const float* be3 = (const float*)d_in[16];
    const float* Wd0 = (const float*)d_in[17]; const float* bd0 = (const float*)d_in[18];
    const float* Wd1 = (const float*)d_in[19]; const float* bd1 = (const float*)d_in[20];
    const float* Wd2 = (const float*)d_in[21]; const float* bd2 = (const float*)d_in[22];
    const float* Wout = (const float*)d_in[23]; const float* bout = (const float*)d_in[24];
    float* out = (float*)d_out;

    const int N = in_sizes[4];
    const int E = in_sizes[3] / 2;
    const int G = in_sizes[1] / 3;
    const int* src = eidx;
    const int* dst = eidx + E;

    char* ws = (char*)d_ws;
    size_t off = 0;
    auto alloc = [&](size_t nbytes) -> void* {
        void* p = (void*)(ws + off);
        off += (nbytes + 255) & ~(size_t)255;
        return p;
    };
    float* dinv     = (float*)alloc((size_t)N * 4);
    int*   degcnt   = (int*)alloc((size_t)N * 4);
    int*   part     = (int*)alloc((size_t)N * 4);
    int*   bsum     = (int*)alloc(256 * 4);
    int*   row_start= (int*)alloc((size_t)N * 4);
    int*   cur      = (int*)alloc((size_t)N * 4);
    int*   csr_src  = (int*)alloc((size_t)E * 4);
    float* csr_nrm  = (float*)alloc((size_t)E * 4);
    float* bufA     = (float*)alloc((size_t)N * HC * 4);   // xW; reused as split-K partials in head
    float* bufB     = (float*)alloc((size_t)N * HC * 4);
    float* bufC     = (float*)alloc((size_t)N * HC * 4);
    float* colsum   = (float*)alloc(HC * 4);
    float* colsumsq = (float*)alloc(HC * 4);
    float* scale    = (float*)alloc(HC * 4);
    float* shift    = (float*)alloc(HC * 4);
    float* pooled   = (float*)alloc((size_t)G * HC * 4);
    float* cntf     = (float*)alloc((size_t)G * 4);
    float* zbuf     = (float*)alloc((size_t)G * ZK * 4);
    float* t0       = (float*)alloc((size_t)G * DHID * 4);
    float* t1       = (float*)alloc((size_t)G * DHID * 4);
    (void)ws_size;

    const int total = N * HC;
    const int nScanBlk = (N + 255) / 256;

    // ---- CSR build (once) ----
    k_zero_i<<<(N + 255) / 256, 256, 0, stream>>>(degcnt, N);
    k_deg_i<<<(E + 255) / 256, 256, 0, stream>>>(dst, degcnt, E);
    k_dinv<<<(N + 255) / 256, 256, 0, stream>>>(degcnt, dinv, N);
    k_scan1<<<nScanBlk, 256, 0, stream>>>(degcnt, part, bsum, N);
    k_scan2<<<1, 256, 0, stream>>>(bsum, nScanBlk);
    k_scan3<<<nScanBlk, 256, 0, stream>>>(part, bsum, row_start, N);
    k_zero_i<<<(N + 255) / 256, 256, 0, stream>>>(cur, N);
    k_scatter<<<(E + 255) / 256, 256, 0, stream>>>(src, dst, dinv, row_start, cur,
                                                   csr_src, csr_nrm, E);

    auto gcn_layer = [&](const float* hin, int K, const float* W,
                         const float* gam, const float* bet, bool relu) {
        dim3 gb(1, (N + 127) / 128);
        gemm128<false, false><<<gb, 256, 0, stream>>>(hin, W, nullptr, bufA, N, HC, K);
        k_gather<<<(N + 3) / 4, 256, 0, stream>>>(bufA, csr_src, csr_nrm, row_start,
                                                  degcnt, dinv, bufB, N);
        hipMemsetAsync(colsum, 0, HC * 4, stream);
        hipMemsetAsync(colsumsq, 0, HC * 4, stream);
        k_bn_reduce<<<256, 256, 0, stream>>>(bufB, colsum, colsumsq, N);
        k_bn_stats<<<1, HC, 0, stream>>>(colsum, colsumsq, gam, bet, scale, shift, 1.0f / N);
        if (relu)
            k_bn_apply<true><<<(total + 255) / 256, 256, 0, stream>>>(bufB, scale, shift, bufC, total);
        else
            k_bn_apply<false><<<(total + 255) / 256, 256, 0, stream>>>(bufB, scale, shift, bufC, total);
    };

    gcn_layer(x,    FIN, W1, g1, be1, true);
    gcn_layer(bufC, HC,  W2, g2, be2, true);
    gcn_layer(bufC, HC,  W3, g3, be3, false);

    // global mean pool
    hipMemsetAsync(pooled, 0, (size_t)G * HC * 4, stream);
    hipMemsetAsync(cntf, 0, (size_t)G * 4, stream);
    k_pool<<<512, HC, 0, stream>>>(bufC, batch, pooled, cntf, N);
    k_build_z<<<G, 192, 0, stream>>>(pooled, cntf, origin, direction, zbuf, G);

    // ---- dense head via split-K ----
    float* kpart = bufA;              // 25.6 MB >> 8 MB needed
    const int MN = G * DHID;
    const int rblk = (MN / 4 + 255) / 256;

    // layer 0: K = ZK (134), 2 slices
    gemm_splitk<<<dim3(DHID / 64, (G + 63) / 64, 2), 256, 0, stream>>>(
        zbuf, Wd0, kpart, G, DHID, ZK, (ZK + 1) / 2);
    k_reduce_br<true><<<rblk, 256, 0, stream>>>(kpart, bd0, t0, MN, DHID - 1, 2);

    // layer 1: K = 1024, 8 slices of 128
    gemm_splitk<<<dim3(DHID / 64, (G + 63) / 64, 8), 256, 0, stream>>>(
        t0, Wd1, kpart, G, DHID, DHID, DHID / 8);
    k_reduce_br<true><<<rblk, 256, 0, stream>>>(kpart, bd1, t1, MN, DHID - 1, 8);

    // layer 2: K = 1024, 8 slices of 128
    gemm_splitk<<<dim3(DHID / 64, (G + 63) / 64, 8), 256, 0, stream>>>(
        t1, Wd2, kpart, G, DHID, DHID, DHID / 8);
    k_reduce_br<true><<<rblk, 256, 0, stream>>>(kpart, bd2, t0, MN, DHID - 1, 8);

    k_dense_out<<<G, 256, 0, stream>>>(t0, Wout, bout, out, DHID);
}

// Round 4
// 619.914 us; speedup vs baseline: 4.4217x; 1.1714x over previous
//
#include <hip/hip_runtime.h>

#define HC 128      // hidden / latent channels
#define FIN 64
#define DHID 1024
#define ZK 134      // LAT + 6

typedef __attribute__((ext_vector_type(8))) short short8;
typedef __attribute__((ext_vector_type(8))) __bf16 bf16x8;
typedef __attribute__((ext_vector_type(4))) float f32x4;

union FragU { short8 s; bf16x8 b; };

__device__ inline unsigned short rne_bf16(float x) {
    union { float f; unsigned u; } v; v.f = x;
    unsigned u = v.u;
    unsigned r = (u + 0x7fffu + ((u >> 16) & 1u)) >> 16;
    return (unsigned short)r;
}
__device__ inline float bf16_to_f(unsigned short h) {
    union { unsigned u; float f; } v; v.u = ((unsigned)h) << 16;
    return v.f;
}

// ---------------------------------------------------------------- small utils
__global__ void k_zero_i(int* p, int n) {
    int i = blockIdx.x * blockDim.x + threadIdx.x;
    if (i < n) p[i] = 0;
}

__global__ void k_deg_i(const int* __restrict__ dst, int* __restrict__ cnt, int E) {
    int i = blockIdx.x * blockDim.x + threadIdx.x;
    if (i < E) atomicAdd(&cnt[dst[i]], 1);
}

__global__ void k_dinv(const int* __restrict__ cnt, float* __restrict__ dinv, int N) {
    int i = blockIdx.x * blockDim.x + threadIdx.x;
    if (i < N) dinv[i] = rsqrtf((float)cnt[i] + 1.0f);
}

// ---------------------------------------------------------------- scan (CSR row offsets)
__global__ void k_scan1(const int* __restrict__ cnt, int* __restrict__ part,
                        int* __restrict__ bsum, int N) {
    __shared__ int sh[256];
    int t = threadIdx.x, i = blockIdx.x * 256 + t;
    int v = (i < N) ? cnt[i] : 0;
    sh[t] = v; __syncthreads();
    #pragma unroll
    for (int off = 1; off < 256; off <<= 1) {
        int tv = (t >= off) ? sh[t - off] : 0;
        __syncthreads();
        sh[t] += tv;
        __syncthreads();
    }
    if (i < N) part[i] = sh[t] - v;          // exclusive within block
    if (t == 255) bsum[blockIdx.x] = sh[255];
}

__global__ void k_scan2(int* __restrict__ bsum, int nb) {
    __shared__ int sh[256];
    int t = threadIdx.x;
    int v = (t < nb) ? bsum[t] : 0;
    sh[t] = v; __syncthreads();
    #pragma unroll
    for (int off = 1; off < 256; off <<= 1) {
        int tv = (t >= off) ? sh[t - off] : 0;
        __syncthreads();
        sh[t] += tv;
        __syncthreads();
    }
    if (t < nb) bsum[t] = sh[t] - v;         // exclusive
}

__global__ void k_scan3(const int* __restrict__ part, const int* __restrict__ bsum,
                        int* __restrict__ row_start, int N) {
    int i = blockIdx.x * 256 + threadIdx.x;
    if (i < N) row_start[i] = part[i] + bsum[blockIdx.x];
}

// scatter edges into CSR order keyed by dst; precompute per-edge norm
__global__ void k_scatter(const int* __restrict__ src, const int* __restrict__ dst,
                          const float* __restrict__ dinv, const int* __restrict__ row_start,
                          int* __restrict__ cur, int* __restrict__ csr_src,
                          float* __restrict__ csr_nrm, int E) {
    int e = blockIdx.x * blockDim.x + threadIdx.x;
    if (e >= E) return;
    int s = src[e], d = dst[e];
    int pos = row_start[d] + atomicAdd(&cur[d], 1);
    csr_src[pos] = s;
    csr_nrm[pos] = dinv[s] * dinv[d];
}

// ---------------------------------------------------------------- gather aggregation
__global__ __launch_bounds__(256) void k_gather(const float* __restrict__ xW,
                                                const int* __restrict__ csr_src,
                                                const float* __restrict__ csr_nrm,
                                                const int* __restrict__ row_start,
                                                const int* __restrict__ cnt,
                                                const float* __restrict__ dinv,
                                                float* __restrict__ agg, int N) {
    int node = blockIdx.x * 4 + (threadIdx.x >> 6);
    int lane = threadIdx.x & 63;
    if (node >= N) return;
    int beg = row_start[node];
    int end = beg + cnt[node];
    float d = dinv[node];
    float2 acc = ((const float2*)(xW + (size_t)node * HC))[lane];
    acc.x *= d * d; acc.y *= d * d;
    int j = beg;
    for (; j + 2 <= end; j += 2) {
        int   s0 = csr_src[j],     s1 = csr_src[j + 1];
        float n0 = csr_nrm[j],     n1 = csr_nrm[j + 1];
        float2 v0 = ((const float2*)(xW + (size_t)s0 * HC))[lane];
        float2 v1 = ((const float2*)(xW + (size_t)s1 * HC))[lane];
        acc.x += v0.x * n0 + v1.x * n1;
        acc.y += v0.y * n0 + v1.y * n1;
    }
    if (j < end) {
        int s0 = csr_src[j];
        float n0 = csr_nrm[j];
        float2 v0 = ((const float2*)(xW + (size_t)s0 * HC))[lane];
        acc.x += v0.x * n0;
        acc.y += v0.y * n0;
    }
    ((float2*)(agg + (size_t)node * HC))[lane] = acc;
}

// ---------------------------------------------------------------- batchnorm stats
__global__ void k_bn_reduce(const float* __restrict__ x, float* __restrict__ sum,
                            float* __restrict__ sumsq, int N) {
    int f = threadIdx.x & (HC - 1);
    int half = threadIdx.x >> 7;  // 0/1
    int rpb = (N + gridDim.x - 1) / gridDim.x;
    int r0 = blockIdx.x * rpb;
    int r1 = min(N, r0 + rpb);
    float s = 0.f, ss = 0.f;
    for (int r = r0 + half; r < r1; r += 2) {
        float v = x[(size_t)r * HC + f];
        s += v; ss += v * v;
    }
    __shared__ float sh[256], shq[256];
    sh[threadIdx.x] = s; shq[threadIdx.x] = ss;
    __syncthreads();
    if (half == 0) {
        atomicAdd(&sum[f],   sh[threadIdx.x] + sh[threadIdx.x + HC]);
        atomicAdd(&sumsq[f], shq[threadIdx.x] + shq[threadIdx.x + HC]);
    }
}

__global__ void k_bn_stats(const float* __restrict__ sum, const float* __restrict__ sumsq,
                           const float* __restrict__ gamma, const float* __restrict__ beta,
                           float* __restrict__ scale, float* __restrict__ shift, float invN) {
    int f = threadIdx.x;
    float m = sum[f] * invN;
    float var = sumsq[f] * invN - m * m;
    float istd = rsqrtf(var + 1e-5f);
    float sc = gamma[f] * istd;
    scale[f] = sc;
    shift[f] = beta[f] - m * sc;
}

// ---------------------------------------------------------------- pooling (BN3 fused)
__global__ void k_pool(const float* __restrict__ h, const int* __restrict__ batch,
                       const float* __restrict__ sc, const float* __restrict__ sh,
                       float* __restrict__ pooled, float* __restrict__ cnt, int N) {
    int t = threadIdx.x;  // 0..127
    float scv = sc[t], shv = sh[t];
    int rpb = (N + gridDim.x - 1) / gridDim.x;
    int r0 = blockIdx.x * rpb;
    int r1 = min(N, r0 + rpb);
    if (r0 >= r1) return;
    int curb = batch[r0];
    float acc = 0.f; float c = 0.f;
    for (int r = r0; r < r1; ++r) {
        int b = batch[r];
        if (b != curb) {
            atomicAdd(&pooled[curb * HC + t], acc);
            if (t == 0) atomicAdd(&cnt[curb], c);
            curb = b; acc = 0.f; c = 0.f;
        }
        acc += h[(size_t)r * HC + t] * scv + shv;
        c += 1.f;
    }
    atomicAdd(&pooled[curb * HC + t], acc);
    if (t == 0) atomicAdd(&cnt[curb], c);
}

__global__ void k_build_z(const float* __restrict__ pooled, const float* __restrict__ cnt,
                          const float* __restrict__ origin, const float* __restrict__ dir,
                          float* __restrict__ z, int G) {
    int g = blockIdx.x;
    int t = threadIdx.x;
    if (t < HC) {
        float c = fmaxf(cnt[g], 1.0f);
        z[g * ZK + t] = pooled[g * HC + t] / c;
    } else if (t < HC + 3) {
        z[g * ZK + t] = origin[g * 3 + (t - HC)];
    } else if (t < HC + 6) {
        z[g * ZK + t] = dir[g * 3 + (t - HC - 3)];
    }
}

// ---------------------------------------------------------------- W prep: fp32 [K][128] -> bf16 hi/lo transposed [128][K]
__global__ void k_wprep(const float* __restrict__ W, unsigned short* __restrict__ wth,
                        unsigned short* __restrict__ wtl, int K) {
    int i = blockIdx.x * blockDim.x + threadIdx.x;
    if (i >= K * HC) return;
    int k = i >> 7, n = i & (HC - 1);
    float w = W[i];
    unsigned short h = rne_bf16(w);
    unsigned short l = rne_bf16(w - bf16_to_f(h));
    wth[n * K + k] = h;
    wtl[n * K + k] = l;
}

// ---------------------------------------------------------------- MFMA node GEMM
// C[M,128] = act(A)[M,KK] @ W[KK,128], act = optional BN(scale,shift)+ReLU on A.
// Split-bf16: A=ah+al, W=wh+wl; C ~= ah*wh + ah*wl + al*wh.
// Block: 256 thr = 4 waves = 2 row-waves x 2 col-waves; wave = 16 rows x 64 cols.
template <int KK, bool BN>
__global__ __launch_bounds__(256) void gemm_node(const float* __restrict__ A,
                                                 const unsigned short* __restrict__ wth,
                                                 const unsigned short* __restrict__ wtl,
                                                 const float* __restrict__ sc,
                                                 const float* __restrict__ sh,
                                                 float* __restrict__ C, int M) {
    constexpr int KS = KK / 32;
    int tid = threadIdx.x;
    int lane = tid & 63, wid = tid >> 6;
    int rw = wid & 1, cw = wid >> 1;
    int l15 = lane & 15, l4 = lane >> 4;
    int m0 = blockIdx.x * 32 + rw * 16;
    int cbase = cw * 64;

    // hoist W fragments into registers (same for every block; L1/L2-hot)
    FragU bh[4][KS], bl[4][KS];
    #pragma unroll
    for (int ct = 0; ct < 4; ++ct) {
        int n = cbase + ct * 16 + l15;
        #pragma unroll
        for (int ks = 0; ks < KS; ++ks) {
            int k = ks * 32 + l4 * 8;
            bh[ct][ks].s = *(const short8*)(wth + (size_t)n * KK + k);
            bl[ct][ks].s = *(const short8*)(wtl + (size_t)n * KK + k);
        }
    }
    if (m0 >= M) return;

    int arow = m0 + l15;
    f32x4 zero = {0.f, 0.f, 0.f, 0.f};
    f32x4 acc[4] = {zero, zero, zero, zero};

    #pragma unroll
    for (int ks = 0; ks < KS; ++ks) {
        int k0 = ks * 32 + l4 * 8;
        const float4 p0 = *(const float4*)(A + (size_t)arow * KK + k0);
        const float4 p1 = *(const float4*)(A + (size_t)arow * KK + k0 + 4);
        float av[8] = {p0.x, p0.y, p0.z, p0.w, p1.x, p1.y, p1.z, p1.w};
        if (BN) {
            const float4 s0 = *(const float4*)(sc + k0);
            const float4 s1 = *(const float4*)(sc + k0 + 4);
            const float4 h0 = *(const float4*)(sh + k0);
            const float4 h1 = *(const float4*)(sh + k0 + 4);
            float scv[8] = {s0.x, s0.y, s0.z, s0.w, s1.x, s1.y, s1.z, s1.w};
            float shv[8] = {h0.x, h0.y, h0.z, h0.w, h1.x, h1.y, h1.z, h1.w};
            #pragma unroll
            for (int i = 0; i < 8; ++i) av[i] = fmaxf(av[i] * scv[i] + shv[i], 0.f);
        }
        FragU ah, al;
        #pragma unroll
        for (int i = 0; i < 8; ++i) {
            unsigned short h = rne_bf16(av[i]);
            ah.s[i] = (short)h;
            al.s[i] = (short)rne_bf16(av[i] - bf16_to_f(h));
        }
        #pragma unroll
        for (int ct = 0; ct < 4; ++ct) {
            acc[ct] = __builtin_amdgcn_mfma_f32_16x16x32_bf16(ah.b, bh[ct][ks].b, acc[ct], 0, 0, 0);
            acc[ct] = __builtin_amdgcn_mfma_f32_16x16x32_bf16(ah.b, bl[ct][ks].b, acc[ct], 0, 0, 0);
            acc[ct] = __builtin_amdgcn_mfma_f32_16x16x32_bf16(al.b, bh[ct][ks].b, acc[ct], 0, 0, 0);
        }
    }

    // C/D layout: col = lane&15, row = (lane>>4)*4 + reg
    #pragma unroll
    for (int ct = 0; ct < 4; ++ct) {
        int col = cbase + ct * 16 + l15;
        #pragma unroll
        for (int r = 0; r < 4; ++r) {
            int row = m0 + l4 * 4 + r;
            C[(size_t)row * HC + col] = acc[ct][r];
        }
    }
}

// ---------------------------------------------------------------- split-K GEMM (dense head)
__global__ __launch_bounds__(256) void gemm_splitk(const float* __restrict__ A,
                                                   const float* __restrict__ B,
                                                   float* __restrict__ Cpart,
                                                   int M, int N, int K, int slice) {
    __shared__ float As[16][68];
    __shared__ float Bs[16][68];
    int z = blockIdx.z;
    int kbeg = z * slice;
    int kend = min(K, kbeg + slice);
    int bm = blockIdx.y * 64, bn = blockIdx.x * 64;
    int tid = threadIdx.x;
    int tc = tid & 15, tr = tid >> 4;
    float acc[4][4] = {};
    for (int k0 = kbeg; k0 < kend; k0 += 16) {
        #pragma unroll
        for (int i = 0; i < 4; ++i) {
            int idx = tid + i * 256;
            int m = idx >> 4, kk = idx & 15;
            float v = 0.f;
            if (bm + m < M && k0 + kk < kend) v = A[(size_t)(bm + m) * K + k0 + kk];
            As[kk][m] = v;
        }
        #pragma unroll
        for (int i = 0; i < 4; ++i) {
            int idx = tid + i * 256;
            int kk = idx >> 6, n = idx & 63;
            float v = 0.f;
            if (bn + n < N && k0 + kk < kend) v = B[(size_t)(k0 + kk) * N + bn + n];
            Bs[kk][n] = v;
        }
        __syncthreads();
        #pragma unroll
        for (int kk = 0; kk < 16; ++kk) {
            float a[4], b[4];
            #pragma unroll
            for (int i = 0; i < 4; ++i) a[i] = As[kk][tr * 4 + i];
            #pragma unroll
            for (int j = 0; j < 4; ++j) b[j] = Bs[kk][tc * 4 + j];
            #pragma unroll
            for (int i = 0; i < 4; ++i)
                #pragma unroll
                for (int j = 0; j < 4; ++j) acc[i][j] += a[i] * b[j];
        }
        __syncthreads();
    }
    float* Cz = Cpart + (size_t)z * M * N;
    #pragma unroll
    for (int i = 0; i < 4; ++i) {
        int m = bm + tr * 4 + i;
        if (m >= M) continue;
        #pragma unroll
        for (int j = 0; j < 4; ++j) {
            int n = bn + tc * 4 + j;
            if (n >= N) continue;
            Cz[(size_t)m * N + n] = acc[i][j];
        }
    }
}

template <bool RELU>
__global__ void k_reduce_br(const float* __restrict__ part, const float* __restrict__ bias,
                            float* __restrict__ C, int MN, int Nmask, int NZ) {
    int i = (blockIdx.x * blockDim.x + threadIdx.x) * 4;
    if (i >= MN) return;
    float4 acc = *(const float4*)(part + i);
    for (int zz = 1; zz < NZ; ++zz) {
        float4 p = *(const float4*)(part + (size_t)zz * MN + i);
        acc.x += p.x; acc.y += p.y; acc.z += p.z; acc.w += p.w;
    }
    int n = i & Nmask;
    acc.x += bias[n]; acc.y += bias[n + 1]; acc.z += bias[n + 2]; acc.w += bias[n + 3];
    if (RELU) {
        acc.x = fmaxf(acc.x, 0.f); acc.y = fmaxf(acc.y, 0.f);
        acc.z = fmaxf(acc.z, 0.f); acc.w = fmaxf(acc.w, 0.f);
    }
    *(float4*)(C + i) = acc;
}

// final [G,DH] @ [DH,3] + bout
__global__ void k_dense_out(const float* __restrict__ z, const float* __restrict__ W,
                            const float* __restrict__ b, float* __restrict__ out, int K) {
    int g = blockIdx.x;
    const float* zr = z + (size_t)g * K;
    float a0 = 0.f, a1 = 0.f, a2 = 0.f;
    for (int k = threadIdx.x; k < K; k += blockDim.x) {
        float zv = zr[k];
        a0 += zv * W[k * 3 + 0];
        a1 += zv * W[k * 3 + 1];
        a2 += zv * W[k * 3 + 2];
    }
    __shared__ float s[768];
    s[threadIdx.x] = a0; s[256 + threadIdx.x] = a1; s[512 + threadIdx.x] = a2;
    __syncthreads();
    for (int off = 128; off > 0; off >>= 1) {
        if ((int)threadIdx.x < off) {
            s[threadIdx.x]       += s[threadIdx.x + off];
            s[256 + threadIdx.x] += s[256 + threadIdx.x + off];
            s[512 + threadIdx.x] += s[512 + threadIdx.x + off];
        }
        __syncthreads();
    }
    if (threadIdx.x == 0) {
        out[g * 3 + 0] = s[0]   + b[0];
        out[g * 3 + 1] = s[256] + b[1];
        out[g * 3 + 2] = s[512] + b[2];
    }
}

// ---------------------------------------------------------------- launch
extern "C" void kernel_launch(void* const* d_in, const int* in_sizes, int n_in,
                              void* d_out, int out_size, void* d_ws, size_t ws_size,
                              hipStream_t stream) {
    const float* x         = (const float*)d_in[0];
    const float* origin    = (const float*)d_in[1];
    const float* direction = (const float*)d_in[2];
    const int*   eidx      = (const int*)d_in[3];
    const int*   batch     = (const int*)d_in[4];
    const float* W1 = (const float*)d_in[5];
    const float* W2 = (const float*)d_in[7];
    const float* W3 = (const float*)d_in[9];
    const float* g1 = (const float*)d_in[11]; const float* be1 = (const float*)d_in[12];
    const float* g2 = (const float*)d_in[13]; const float* be2 = (const float*)d_in[14];
    const float* g3 = (const float*)d_in[15]; const float* be3 = (const float*)d_in[16];
    const float* Wd0 = (const float*)d_in[17]; const float* bd0 = (const float*)d_in[18];
    const float* Wd1 = (const float*)d_in[19]; const float* bd1 = (const float*)d_in[20];
    const float* Wd2 = (const float*)d_in[21]; const float* bd2 = (const float*)d_in[22];
    const float* Wout = (const float*)d_in[23]; const float* bout = (const float*)d_in[24];
    float* out = (float*)d_out;

    const int N = in_sizes[4];
    const int E = in_sizes[3] / 2;
    const int G = in_sizes[1] / 3;
    const int* src = eidx;
    const int* dst = eidx + E;

    char* ws = (char*)d_ws;
    size_t off = 0;
    auto alloc = [&](size_t nbytes) -> void* {
        void* p = (void*)(ws + off);
        off += (nbytes + 255) & ~(size_t)255;
        return p;
    };
    float* dinv     = (float*)alloc((size_t)N * 4);
    int*   degcnt   = (int*)alloc((size_t)N * 4);
    int*   part     = (int*)alloc((size_t)N * 4);
    int*   bsum     = (int*)alloc(256 * 4);
    int*   row_start= (int*)alloc((size_t)N * 4);
    int*   cur      = (int*)alloc((size_t)N * 4);
    int*   csr_src  = (int*)alloc((size_t)E * 4);
    float* csr_nrm  = (float*)alloc((size_t)E * 4);
    float* bufA     = (float*)alloc((size_t)N * HC * 4);   // xW; reused as split-K partials in head
    float* bufB     = (float*)alloc((size_t)N * HC * 4);   // agg (gather output)
    unsigned short* wt1h = (unsigned short*)alloc((size_t)FIN * HC * 2);
    unsigned short* wt1l = (unsigned short*)alloc((size_t)FIN * HC * 2);
    unsigned short* wt2h = (unsigned short*)alloc((size_t)HC * HC * 2);
    unsigned short* wt2l = (unsigned short*)alloc((size_t)HC * HC * 2);
    unsigned short* wt3h = (unsigned short*)alloc((size_t)HC * HC * 2);
    unsigned short* wt3l = (unsigned short*)alloc((size_t)HC * HC * 2);
    float* colsum   = (float*)alloc(HC * 4);
    float* colsumsq = (float*)alloc(HC * 4);
    float* scale1   = (float*)alloc(HC * 4);
    float* shift1   = (float*)alloc(HC * 4);
    float* scale2   = (float*)alloc(HC * 4);
    float* shift2   = (float*)alloc(HC * 4);
    float* scale3   = (float*)alloc(HC * 4);
    float* shift3   = (float*)alloc(HC * 4);
    float* pooled   = (float*)alloc((size_t)G * HC * 4);
    float* cntf     = (float*)alloc((size_t)G * 4);
    float* zbuf     = (float*)alloc((size_t)G * ZK * 4);
    float* t0       = (float*)alloc((size_t)G * DHID * 4);
    float* t1       = (float*)alloc((size_t)G * DHID * 4);
    (void)ws_size;

    const int nScanBlk = (N + 255) / 256;
    const int gemmBlk = (N + 31) / 32;

    // ---- weight prep (bf16 hi/lo, transposed) ----
    k_wprep<<<(FIN * HC + 255) / 256, 256, 0, stream>>>(W1, wt1h, wt1l, FIN);
    k_wprep<<<(HC * HC + 255) / 256, 256, 0, stream>>>(W2, wt2h, wt2l, HC);
    k_wprep<<<(HC * HC + 255) / 256, 256, 0, stream>>>(W3, wt3h, wt3l, HC);

    // ---- CSR build (once) ----
    k_zero_i<<<(N + 255) / 256, 256, 0, stream>>>(degcnt, N);
    k_deg_i<<<(E + 255) / 256, 256, 0, stream>>>(dst, degcnt, E);
    k_dinv<<<(N + 255) / 256, 256, 0, stream>>>(degcnt, dinv, N);
    k_scan1<<<nScanBlk, 256, 0, stream>>>(degcnt, part, bsum, N);
    k_scan2<<<1, 256, 0, stream>>>(bsum, nScanBlk);
    k_scan3<<<nScanBlk, 256, 0, stream>>>(part, bsum, row_start, N);
    k_zero_i<<<(N + 255) / 256, 256, 0, stream>>>(cur, N);
    k_scatter<<<(E + 255) / 256, 256, 0, stream>>>(src, dst, dinv, row_start, cur,
                                                   csr_src, csr_nrm, E);

    auto post_gemm = [&](const float* gam, const float* bet, float* scl, float* shf) {
        k_gather<<<(N + 3) / 4, 256, 0, stream>>>(bufA, csr_src, csr_nrm, row_start,
                                                  degcnt, dinv, bufB, N);
        hipMemsetAsync(colsum, 0, HC * 4, stream);
        hipMemsetAsync(colsumsq, 0, HC * 4, stream);
        k_bn_reduce<<<256, 256, 0, stream>>>(bufB, colsum, colsumsq, N);
        k_bn_stats<<<1, HC, 0, stream>>>(colsum, colsumsq, gam, bet, scl, shf, 1.0f / N);
    };

    // layer 1: A = x (no BN on input)
    gemm_node<FIN, false><<<gemmBlk, 256, 0, stream>>>(x, wt1h, wt1l, nullptr, nullptr, bufA, N);
    post_gemm(g1, be1, scale1, shift1);
    // layer 2: A = bufB with BN1+ReLU fused
    gemm_node<HC, true><<<gemmBlk, 256, 0, stream>>>(bufB, wt2h, wt2l, scale1, shift1, bufA, N);
    post_gemm(g2, be2, scale2, shift2);
    // layer 3: A = bufB with BN2+ReLU fused
    gemm_node<HC, true><<<gemmBlk, 256, 0, stream>>>(bufB, wt3h, wt3l, scale2, shift2, bufA, N);
    post_gemm(g3, be3, scale3, shift3);

    // global mean pool (BN3 fused, no ReLU)
    hipMemsetAsync(pooled, 0, (size_t)G * HC * 4, stream);
    hipMemsetAsync(cntf, 0, (size_t)G * 4, stream);
    k_pool<<<512, HC, 0, stream>>>(bufB, batch, scale3, shift3, pooled, cntf, N);
    k_build_z<<<G, 192, 0, stream>>>(pooled, cntf, origin, direction, zbuf, G);

    // ---- dense head via split-K ----
    float* kpart = bufA;              // 25.6 MB >> 8 MB needed
    const int MN = G * DHID;
    const int rblk = (MN / 4 + 255) / 256;

    gemm_splitk<<<dim3(DHID / 64, (G + 63) / 64, 2), 256, 0, stream>>>(
        zbuf, Wd0, kpart, G, DHID, ZK, (ZK + 1) / 2);
    k_reduce_br<true><<<rblk, 256, 0, stream>>>(kpart, bd0, t0, MN, DHID - 1, 2);

    gemm_splitk<<<dim3(DHID / 64, (G + 63) / 64, 8), 256, 0, stream>>>(
        t0, Wd1, kpart, G, DHID, DHID, DHID / 8);
    k_reduce_br<true><<<rblk, 256, 0, stream>>>(kpart, bd1, t1, MN, DHID - 1, 8);

    gemm_splitk<<<dim3(DHID / 64, (G + 63) / 64, 8), 256, 0, stream>>>(
        t1, Wd2, kpart, G, DHID, DHID, DHID / 8);
    k_reduce_br<true><<<rblk, 256, 0, stream>>>(kpart, bd2, t0, MN, DHID - 1, 8);

    k_dense_out<<<G, 256, 0, stream>>>(t0, Wout, bout, out, DHID);
}

// Round 5
// 616.130 us; speedup vs baseline: 4.4488x; 1.0061x over previous
//
#include <hip/hip_runtime.h>

#define HC 128      // hidden / latent channels
#define FIN 64
#define DHID 1024
#define ZK 134      // LAT + 6
#define ZKP 160     // ZK padded to multiple of 32 for MFMA head

typedef __attribute__((ext_vector_type(8))) short short8;
typedef __attribute__((ext_vector_type(8))) __bf16 bf16x8;
typedef __attribute__((ext_vector_type(4))) float f32x4;

union FragU { short8 s; bf16x8 b; };

__device__ inline unsigned short rne_bf16(float x) {
    union { float f; unsigned u; } v; v.f = x;
    unsigned u = v.u;
    unsigned r = (u + 0x7fffu + ((u >> 16) & 1u)) >> 16;
    return (unsigned short)r;
}
__device__ inline float bf16_to_f(unsigned short h) {
    union { unsigned u; float f; } v; v.u = ((unsigned)h) << 16;
    return v.f;
}

// ---------------------------------------------------------------- small utils
__global__ void k_zero_i(int* p, int n) {
    int i = blockIdx.x * blockDim.x + threadIdx.x;
    if (i < n) p[i] = 0;
}

__global__ void k_deg_i(const int* __restrict__ dst, int* __restrict__ cnt, int E) {
    int i = blockIdx.x * blockDim.x + threadIdx.x;
    if (i < E) atomicAdd(&cnt[dst[i]], 1);
}

__global__ void k_dinv(const int* __restrict__ cnt, float* __restrict__ dinv, int N) {
    int i = blockIdx.x * blockDim.x + threadIdx.x;
    if (i < N) dinv[i] = rsqrtf((float)cnt[i] + 1.0f);
}

// ---------------------------------------------------------------- scan (CSR row offsets)
__global__ void k_scan1(const int* __restrict__ cnt, int* __restrict__ part,
                        int* __restrict__ bsum, int N) {
    __shared__ int sh[256];
    int t = threadIdx.x, i = blockIdx.x * 256 + t;
    int v = (i < N) ? cnt[i] : 0;
    sh[t] = v; __syncthreads();
    #pragma unroll
    for (int off = 1; off < 256; off <<= 1) {
        int tv = (t >= off) ? sh[t - off] : 0;
        __syncthreads();
        sh[t] += tv;
        __syncthreads();
    }
    if (i < N) part[i] = sh[t] - v;          // exclusive within block
    if (t == 255) bsum[blockIdx.x] = sh[255];
}

__global__ void k_scan2(int* __restrict__ bsum, int nb) {
    __shared__ int sh[256];
    int t = threadIdx.x;
    int v = (t < nb) ? bsum[t] : 0;
    sh[t] = v; __syncthreads();
    #pragma unroll
    for (int off = 1; off < 256; off <<= 1) {
        int tv = (t >= off) ? sh[t - off] : 0;
        __syncthreads();
        sh[t] += tv;
        __syncthreads();
    }
    if (t < nb) bsum[t] = sh[t] - v;         // exclusive
}

__global__ void k_scan3(const int* __restrict__ part, const int* __restrict__ bsum,
                        int* __restrict__ row_start, int N) {
    int i = blockIdx.x * 256 + threadIdx.x;
    if (i < N) row_start[i] = part[i] + bsum[blockIdx.x];
}

// scatter edges into CSR order keyed by dst; pack (src, norm) in one int2
__global__ void k_scatter(const int* __restrict__ src, const int* __restrict__ dst,
                          const float* __restrict__ dinv, const int* __restrict__ row_start,
                          int* __restrict__ cur, int2* __restrict__ csr, int E) {
    int e = blockIdx.x * blockDim.x + threadIdx.x;
    if (e >= E) return;
    int s = src[e], d = dst[e];
    int pos = row_start[d] + atomicAdd(&cur[d], 1);
    int2 pk; pk.x = s; pk.y = __float_as_int(dinv[s] * dinv[d]);
    csr[pos] = pk;
}

// ---------------------------------------------------------------- gather aggregation
template <int RF> struct VecT;
template <> struct VecT<64>  { using T = float2; };
template <> struct VecT<128> { using T = float4; };

__device__ inline void fmad(float2& a, const float2 v, float n) {
    a.x += v.x * n; a.y += v.y * n;
}
__device__ inline void fmad(float4& a, const float4 v, float n) {
    a.x += v.x * n; a.y += v.y * n; a.z += v.z * n; a.w += v.w * n;
}
__device__ inline void scl(float2& a, float s) { a.x *= s; a.y *= s; }
__device__ inline void scl(float4& a, float s) { a.x *= s; a.y *= s; a.z *= s; a.w *= s; }

// half-wave (32 lanes) per node; lane reads 1/32 of the row as a wide vector
template <int RF>
__global__ __launch_bounds__(256) void k_gather2(const float* __restrict__ T,
                                                 const int2* __restrict__ csr,
                                                 const int* __restrict__ row_start,
                                                 const int* __restrict__ cnt,
                                                 const float* __restrict__ dinv,
                                                 float* __restrict__ agg, int N) {
    using vec = typename VecT<RF>::T;
    int tid = threadIdx.x;
    int node = blockIdx.x * 8 + (tid >> 5);
    int q = tid & 31;
    if (node >= N) return;
    int beg = row_start[node];
    int end = beg + cnt[node];
    float d = dinv[node];
    vec acc = ((const vec*)(T + (size_t)node * RF))[q];
    scl(acc, d * d);
    int j = beg;
    for (; j + 4 <= end; j += 4) {
        int2 e0 = csr[j], e1 = csr[j + 1], e2 = csr[j + 2], e3 = csr[j + 3];
        vec v0 = ((const vec*)(T + (size_t)e0.x * RF))[q];
        vec v1 = ((const vec*)(T + (size_t)e1.x * RF))[q];
        vec v2 = ((const vec*)(T + (size_t)e2.x * RF))[q];
        vec v3 = ((const vec*)(T + (size_t)e3.x * RF))[q];
        fmad(acc, v0, __int_as_float(e0.y));
        fmad(acc, v1, __int_as_float(e1.y));
        fmad(acc, v2, __int_as_float(e2.y));
        fmad(acc, v3, __int_as_float(e3.y));
    }
    for (; j < end; ++j) {
        int2 e0 = csr[j];
        vec v0 = ((const vec*)(T + (size_t)e0.x * RF))[q];
        fmad(acc, v0, __int_as_float(e0.y));
    }
    ((vec*)(agg + (size_t)node * RF))[q] = acc;
}

// ---------------------------------------------------------------- batchnorm stats
__global__ void k_bn_reduce(const float* __restrict__ x, float* __restrict__ sum,
                            float* __restrict__ sumsq, int N) {
    int f = threadIdx.x & (HC - 1);
    int half = threadIdx.x >> 7;  // 0/1
    int rpb = (N + gridDim.x - 1) / gridDim.x;
    int r0 = blockIdx.x * rpb;
    int r1 = min(N, r0 + rpb);
    float s = 0.f, ss = 0.f;
    for (int r = r0 + half; r < r1; r += 2) {
        float v = x[(size_t)r * HC + f];
        s += v; ss += v * v;
    }
    __shared__ float sh[256], shq[256];
    sh[threadIdx.x] = s; shq[threadIdx.x] = ss;
    __syncthreads();
    if (half == 0) {
        atomicAdd(&sum[f],   sh[threadIdx.x] + sh[threadIdx.x + HC]);
        atomicAdd(&sumsq[f], shq[threadIdx.x] + shq[threadIdx.x + HC]);
    }
}

__global__ void k_bn_stats(const float* __restrict__ sum, const float* __restrict__ sumsq,
                           const float* __restrict__ gamma, const float* __restrict__ beta,
                           float* __restrict__ scale, float* __restrict__ shift, float invN) {
    int f = threadIdx.x;
    float m = sum[f] * invN;
    float var = sumsq[f] * invN - m * m;
    float istd = rsqrtf(var + 1e-5f);
    float sc = gamma[f] * istd;
    scale[f] = sc;
    shift[f] = beta[f] - m * sc;
}

// ---------------------------------------------------------------- pooling (BN3 fused)
__global__ void k_pool(const float* __restrict__ h, const int* __restrict__ batch,
                       const float* __restrict__ sc, const float* __restrict__ sh,
                       float* __restrict__ pooled, float* __restrict__ cnt, int N) {
    int t = threadIdx.x;  // 0..127
    float scv = sc[t], shv = sh[t];
    int rpb = (N + gridDim.x - 1) / gridDim.x;
    int r0 = blockIdx.x * rpb;
    int r1 = min(N, r0 + rpb);
    if (r0 >= r1) return;
    int curb = batch[r0];
    float acc = 0.f; float c = 0.f;
    for (int r = r0; r < r1; ++r) {
        int b = batch[r];
        if (b != curb) {
            atomicAdd(&pooled[curb * HC + t], acc);
            if (t == 0) atomicAdd(&cnt[curb], c);
            curb = b; acc = 0.f; c = 0.f;
        }
        acc += h[(size_t)r * HC + t] * scv + shv;
        c += 1.f;
    }
    atomicAdd(&pooled[curb * HC + t], acc);
    if (t == 0) atomicAdd(&cnt[curb], c);
}

// build z padded to ZKP cols (pad = 0)
__global__ void k_build_z(const float* __restrict__ pooled, const float* __restrict__ cnt,
                          const float* __restrict__ origin, const float* __restrict__ dir,
                          float* __restrict__ z, int G) {
    int g = blockIdx.x;
    int t = threadIdx.x;
    if (t >= ZKP) return;
    float v = 0.f;
    if (t < HC) {
        float c = fmaxf(cnt[g], 1.0f);
        v = pooled[g * HC + t] / c;
    } else if (t < HC + 3) {
        v = origin[g * 3 + (t - HC)];
    } else if (t < HC + 6) {
        v = dir[g * 3 + (t - HC - 3)];
    }
    z[g * ZKP + t] = v;
}

// ---------------------------------------------------------------- W prep (node GCN weights): fp32 [K][128] -> bf16 hi/lo transposed [128][K]
__global__ void k_wprep(const float* __restrict__ W, unsigned short* __restrict__ wth,
                        unsigned short* __restrict__ wtl, int K) {
    int i = blockIdx.x * blockDim.x + threadIdx.x;
    if (i >= K * HC) return;
    int k = i >> 7, n = i & (HC - 1);
    float w = W[i];
    unsigned short h = rne_bf16(w);
    unsigned short l = rne_bf16(w - bf16_to_f(h));
    wth[n * K + k] = h;
    wtl[n * K + k] = l;
}

// ---------------------------------------------------------------- W prep (head): fp32 [K][NC] -> bf16 hi/lo transposed [NC][KP], LDS tiled
__global__ __launch_bounds__(256) void k_wprep2(const float* __restrict__ W,
                                                unsigned short* __restrict__ th,
                                                unsigned short* __restrict__ tl,
                                                int K, int KP, int NC) {
    __shared__ float tile[32][33];
    int kt = blockIdx.x * 32, nt = blockIdx.y * 32;
    int tx = threadIdx.x & 31, ty0 = threadIdx.x >> 5;
    #pragma unroll
    for (int i = 0; i < 4; ++i) {
        int ty = ty0 + i * 8;
        int k = kt + ty;
        float v = (k < K) ? W[(size_t)k * NC + nt + tx] : 0.f;
        tile[ty][tx] = v;
    }
    __syncthreads();
    #pragma unroll
    for (int i = 0; i < 4; ++i) {
        int ty = ty0 + i * 8;           // n offset within tile
        int n = nt + ty;
        int k = kt + tx;
        float w = tile[tx][ty];
        unsigned short h = rne_bf16(w);
        th[(size_t)n * KP + k] = h;
        tl[(size_t)n * KP + k] = rne_bf16(w - bf16_to_f(h));
    }
}

// ---------------------------------------------------------------- MFMA node GEMM
// C[M,128] = act(A)[M,KK] @ W[KK,128]; act = optional BN+ReLU on A (split-bf16).
template <int KK, bool BN>
__global__ __launch_bounds__(256) void gemm_node(const float* __restrict__ A,
                                                 const unsigned short* __restrict__ wth,
                                                 const unsigned short* __restrict__ wtl,
                                                 const float* __restrict__ sc,
                                                 const float* __restrict__ sh,
                                                 float* __restrict__ C, int M) {
    constexpr int KS = KK / 32;
    int tid = threadIdx.x;
    int lane = tid & 63, wid = tid >> 6;
    int rw = wid & 1, cw = wid >> 1;
    int l15 = lane & 15, l4 = lane >> 4;
    int m0 = blockIdx.x * 32 + rw * 16;
    int cbase = cw * 64;

    FragU bh[4][KS], bl[4][KS];
    #pragma unroll
    for (int ct = 0; ct < 4; ++ct) {
        int n = cbase + ct * 16 + l15;
        #pragma unroll
        for (int ks = 0; ks < KS; ++ks) {
            int k = ks * 32 + l4 * 8;
            bh[ct][ks].s = *(const short8*)(wth + (size_t)n * KK + k);
            bl[ct][ks].s = *(const short8*)(wtl + (size_t)n * KK + k);
        }
    }
    if (m0 >= M) return;

    int arow = m0 + l15;
    f32x4 zero = {0.f, 0.f, 0.f, 0.f};
    f32x4 acc[4] = {zero, zero, zero, zero};

    #pragma unroll
    for (int ks = 0; ks < KS; ++ks) {
        int k0 = ks * 32 + l4 * 8;
        const float4 p0 = *(const float4*)(A + (size_t)arow * KK + k0);
        const float4 p1 = *(const float4*)(A + (size_t)arow * KK + k0 + 4);
        float av[8] = {p0.x, p0.y, p0.z, p0.w, p1.x, p1.y, p1.z, p1.w};
        if (BN) {
            const float4 s0 = *(const float4*)(sc + k0);
            const float4 s1 = *(const float4*)(sc + k0 + 4);
            const float4 h0 = *(const float4*)(sh + k0);
            const float4 h1 = *(const float4*)(sh + k0 + 4);
            float scv[8] = {s0.x, s0.y, s0.z, s0.w, s1.x, s1.y, s1.z, s1.w};
            float shv[8] = {h0.x, h0.y, h0.z, h0.w, h1.x, h1.y, h1.z, h1.w};
            #pragma unroll
            for (int i = 0; i < 8; ++i) av[i] = fmaxf(av[i] * scv[i] + shv[i], 0.f);
        }
        FragU ah, al;
        #pragma unroll
        for (int i = 0; i < 8; ++i) {
            unsigned short h = rne_bf16(av[i]);
            ah.s[i] = (short)h;
            al.s[i] = (short)rne_bf16(av[i] - bf16_to_f(h));
        }
        #pragma unroll
        for (int ct = 0; ct < 4; ++ct) {
            acc[ct] = __builtin_amdgcn_mfma_f32_16x16x32_bf16(ah.b, bh[ct][ks].b, acc[ct], 0, 0, 0);
            acc[ct] = __builtin_amdgcn_mfma_f32_16x16x32_bf16(ah.b, bl[ct][ks].b, acc[ct], 0, 0, 0);
            acc[ct] = __builtin_amdgcn_mfma_f32_16x16x32_bf16(al.b, bh[ct][ks].b, acc[ct], 0, 0, 0);
        }
    }

    #pragma unroll
    for (int ct = 0; ct < 4; ++ct) {
        int col = cbase + ct * 16 + l15;
        #pragma unroll
        for (int r = 0; r < 4; ++r) {
            int row = m0 + l4 * 4 + r;
            C[(size_t)row * HC + col] = acc[ct][r];
        }
    }
}

// ---------------------------------------------------------------- MFMA head GEMM
// C[M,N] = relu(A[M,K] @ W[K,N] + bias); W pre-split bf16 hi/lo transposed [N][K].
// Block: 32 rows x 128 cols; K multiple of 32 (runtime).
__global__ __launch_bounds__(256) void gemm_head(const float* __restrict__ A,
                                                 const unsigned short* __restrict__ wth,
                                                 const unsigned short* __restrict__ wtl,
                                                 const float* __restrict__ bias,
                                                 float* __restrict__ C,
                                                 int M, int N, int K) {
    int tid = threadIdx.x;
    int lane = tid & 63, wid = tid >> 6;
    int rw = wid & 1, cw = wid >> 1;
    int l15 = lane & 15, l4 = lane >> 4;
    int m0 = blockIdx.y * 32 + rw * 16;
    int cb = blockIdx.x * 128 + cw * 64;
    if (m0 >= M) return;

    int arow = m0 + l15;
    f32x4 zero = {0.f, 0.f, 0.f, 0.f};
    f32x4 acc[4] = {zero, zero, zero, zero};
    int KS = K >> 5;

    for (int ks = 0; ks < KS; ++ks) {
        int k0 = ks * 32 + l4 * 8;
        const float4 p0 = *(const float4*)(A + (size_t)arow * K + k0);
        const float4 p1 = *(const float4*)(A + (size_t)arow * K + k0 + 4);
        float av[8] = {p0.x, p0.y, p0.z, p0.w, p1.x, p1.y, p1.z, p1.w};
        FragU ah, al;
        #pragma unroll
        for (int i = 0; i < 8; ++i) {
            unsigned short h = rne_bf16(av[i]);
            ah.s[i] = (short)h;
            al.s[i] = (short)rne_bf16(av[i] - bf16_to_f(h));
        }
        #pragma unroll
        for (int ct = 0; ct < 4; ++ct) {
            int n = cb + ct * 16 + l15;
            FragU bh, bl;
            bh.s = *(const short8*)(wth + (size_t)n * K + k0);
            bl.s = *(const short8*)(wtl + (size_t)n * K + k0);
            acc[ct] = __builtin_amdgcn_mfma_f32_16x16x32_bf16(ah.b, bh.b, acc[ct], 0, 0, 0);
            acc[ct] = __builtin_amdgcn_mfma_f32_16x16x32_bf16(ah.b, bl.b, acc[ct], 0, 0, 0);
            acc[ct] = __builtin_amdgcn_mfma_f32_16x16x32_bf16(al.b, bh.b, acc[ct], 0, 0, 0);
        }
    }

    #pragma unroll
    for (int ct = 0; ct < 4; ++ct) {
        int col = cb + ct * 16 + l15;
        float bv = bias[col];
        #pragma unroll
        for (int r = 0; r < 4; ++r) {
            int row = m0 + l4 * 4 + r;
            float v = fmaxf(acc[ct][r] + bv, 0.f);
            C[(size_t)row * N + col] = v;
        }
    }
}

// final [G,DH] @ [DH,3] + bout
__global__ void k_dense_out(const float* __restrict__ z, const float* __restrict__ W,
                            const float* __restrict__ b, float* __restrict__ out, int K) {
    int g = blockIdx.x;
    const float* zr = z + (size_t)g * K;
    float a0 = 0.f, a1 = 0.f, a2 = 0.f;
    for (int k = threadIdx.x; k < K; k += blockDim.x) {
        float zv = zr[k];
        a0 += zv * W[k * 3 + 0];
        a1 += zv * W[k * 3 + 1];
        a2 += zv * W[k * 3 + 2];
    }
    __shared__ float s[768];
    s[threadIdx.x] = a0; s[256 + threadIdx.x] = a1; s[512 + threadIdx.x] = a2;
    __syncthreads();
    for (int off = 128; off > 0; off >>= 1) {
        if ((int)threadIdx.x < off) {
            s[threadIdx.x]       += s[threadIdx.x + off];
            s[256 + threadIdx.x] += s[256 + threadIdx.x + off];
            s[512 + threadIdx.x] += s[512 + threadIdx.x + off];
        }
        __syncthreads();
    }
    if (threadIdx.x == 0) {
        out[g * 3 + 0] = s[0]   + b[0];
        out[g * 3 + 1] = s[256] + b[1];
        out[g * 3 + 2] = s[512] + b[2];
    }
}

// ---------------------------------------------------------------- launch
extern "C" void kernel_launch(void* const* d_in, const int* in_sizes, int n_in,
                              void* d_out, int out_size, void* d_ws, size_t ws_size,
                              hipStream_t stream) {
    const float* x         = (const float*)d_in[0];
    const float* origin    = (const float*)d_in[1];
    const float* direction = (const float*)d_in[2];
    const int*   eidx      = (const int*)d_in[3];
    const int*   batch     = (const int*)d_in[4];
    const float* W1 = (const float*)d_in[5];
    const float* W2 = (const float*)d_in[7];
    const float* W3 = (const float*)d_in[9];
    const float* g1 = (const float*)d_in[11]; const float* be1 = (const float*)d_in[12];
    const float* g2 = (const float*)d_in[13]; const float* be2 = (const float*)d_in[14];
    const float* g3 = (const float*)d_in[15]; const float* be3 = (const float*)d_in[16];
    const float* Wd0 = (const float*)d_in[17]; const float* bd0 = (const float*)d_in[18];
    const float* Wd1 = (const float*)d_in[19]; const float* bd1 = (const float*)d_in[20];
    const float* Wd2 = (const float*)d_in[21]; const float* bd2 = (const float*)d_in[22];
    const float* Wout = (const float*)d_in[23]; const float* bout = (const float*)d_in[24];
    float* out = (float*)d_out;

    const int N = in_sizes[4];
    const int E = in_sizes[3] / 2;
    const int G = in_sizes[1] / 3;
    const int* src = eidx;
    const int* dst = eidx + E;

    char* ws = (char*)d_ws;
    size_t off = 0;
    auto alloc = [&](size_t nbytes) -> void* {
        void* p = (void*)(ws + off);
        off += (nbytes + 255) & ~(size_t)255;
        return p;
    };
    float* dinv     = (float*)alloc((size_t)N * 4);
    int*   degcnt   = (int*)alloc((size_t)N * 4);
    int*   part     = (int*)alloc((size_t)N * 4);
    int*   bsum     = (int*)alloc(256 * 4);
    int*   row_start= (int*)alloc((size_t)N * 4);
    int*   cur      = (int*)alloc((size_t)N * 4);
    int2*  csr      = (int2*)alloc((size_t)E * 8);
    float* aggx     = (float*)alloc((size_t)N * FIN * 4);
    float* bufA     = (float*)alloc((size_t)N * HC * 4);
    float* bufB     = (float*)alloc((size_t)N * HC * 4);
    unsigned short* wt1h = (unsigned short*)alloc((size_t)FIN * HC * 2);
    unsigned short* wt1l = (unsigned short*)alloc((size_t)FIN * HC * 2);
    unsigned short* wt2h = (unsigned short*)alloc((size_t)HC * HC * 2);
    unsigned short* wt2l = (unsigned short*)alloc((size_t)HC * HC * 2);
    unsigned short* wt3h = (unsigned short*)alloc((size_t)HC * HC * 2);
    unsigned short* wt3l = (unsigned short*)alloc((size_t)HC * HC * 2);
    unsigned short* wd0h = (unsigned short*)alloc((size_t)DHID * ZKP * 2);
    unsigned short* wd0l = (unsigned short*)alloc((size_t)DHID * ZKP * 2);
    unsigned short* wd1h = (unsigned short*)alloc((size_t)DHID * DHID * 2);
    unsigned short* wd1l = (unsigned short*)alloc((size_t)DHID * DHID * 2);
    unsigned short* wd2h = (unsigned short*)alloc((size_t)DHID * DHID * 2);
    unsigned short* wd2l = (unsigned short*)alloc((size_t)DHID * DHID * 2);
    float* colsum   = (float*)alloc(HC * 4);
    float* colsumsq = (float*)alloc(HC * 4);
    float* scale1   = (float*)alloc(HC * 4);
    float* shift1   = (float*)alloc(HC * 4);
    float* scale2   = (float*)alloc(HC * 4);
    float* shift2   = (float*)alloc(HC * 4);
    float* scale3   = (float*)alloc(HC * 4);
    float* shift3   = (float*)alloc(HC * 4);
    float* pooled   = (float*)alloc((size_t)G * HC * 4);
    float* cntf     = (float*)alloc((size_t)G * 4);
    float* zbuf     = (float*)alloc((size_t)G * ZKP * 4);
    float* t0       = (float*)alloc((size_t)G * DHID * 4);
    float* t1       = (float*)alloc((size_t)G * DHID * 4);
    (void)ws_size;

    const int nScanBlk = (N + 255) / 256;
    const int gemmBlk = (N + 31) / 32;
    const int gatherBlk = (N + 7) / 8;

    // ---- weight prep ----
    k_wprep<<<(FIN * HC + 255) / 256, 256, 0, stream>>>(W1, wt1h, wt1l, FIN);
    k_wprep<<<(HC * HC + 255) / 256, 256, 0, stream>>>(W2, wt2h, wt2l, HC);
    k_wprep<<<(HC * HC + 255) / 256, 256, 0, stream>>>(W3, wt3h, wt3l, HC);
    k_wprep2<<<dim3(ZKP / 32, DHID / 32), 256, 0, stream>>>(Wd0, wd0h, wd0l, ZK, ZKP, DHID);
    k_wprep2<<<dim3(DHID / 32, DHID / 32), 256, 0, stream>>>(Wd1, wd1h, wd1l, DHID, DHID, DHID);
    k_wprep2<<<dim3(DHID / 32, DHID / 32), 256, 0, stream>>>(Wd2, wd2h, wd2l, DHID, DHID, DHID);

    // ---- CSR build (once) ----
    k_zero_i<<<(N + 255) / 256, 256, 0, stream>>>(degcnt, N);
    k_deg_i<<<(E + 255) / 256, 256, 0, stream>>>(dst, degcnt, E);
    k_dinv<<<(N + 255) / 256, 256, 0, stream>>>(degcnt, dinv, N);
    k_scan1<<<nScanBlk, 256, 0, stream>>>(degcnt, part, bsum, N);
    k_scan2<<<1, 256, 0, stream>>>(bsum, nScanBlk);
    k_scan3<<<nScanBlk, 256, 0, stream>>>(part, bsum, row_start, N);
    k_zero_i<<<(N + 255) / 256, 256, 0, stream>>>(cur, N);
    k_scatter<<<(E + 255) / 256, 256, 0, stream>>>(src, dst, dinv, row_start, cur, csr, E);

    auto stats = [&](const float* buf, const float* gam, const float* bet,
                     float* scl, float* shf) {
        hipMemsetAsync(colsum, 0, HC * 4, stream);
        hipMemsetAsync(colsumsq, 0, HC * 4, stream);
        k_bn_reduce<<<256, 256, 0, stream>>>(buf, colsum, colsumsq, N);
        k_bn_stats<<<1, HC, 0, stream>>>(colsum, colsumsq, gam, bet, scl, shf, 1.0f / N);
    };

    // layer 1: aggregate first (Â x) then GEMM  [table = N x 64]
    k_gather2<FIN><<<gatherBlk, 256, 0, stream>>>(x, csr, row_start, degcnt, dinv, aggx, N);
    gemm_node<FIN, false><<<gemmBlk, 256, 0, stream>>>(aggx, wt1h, wt1l, nullptr, nullptr, bufA, N);
    stats(bufA, g1, be1, scale1, shift1);

    // layer 2: GEMM (BN1+ReLU fused on load) then gather
    gemm_node<HC, true><<<gemmBlk, 256, 0, stream>>>(bufA, wt2h, wt2l, scale1, shift1, bufB, N);
    k_gather2<HC><<<gatherBlk, 256, 0, stream>>>(bufB, csr, row_start, degcnt, dinv, bufA, N);
    stats(bufA, g2, be2, scale2, shift2);

    // layer 3
    gemm_node<HC, true><<<gemmBlk, 256, 0, stream>>>(bufA, wt3h, wt3l, scale2, shift2, bufB, N);
    k_gather2<HC><<<gatherBlk, 256, 0, stream>>>(bufB, csr, row_start, degcnt, dinv, bufA, N);
    stats(bufA, g3, be3, scale3, shift3);

    // global mean pool (BN3 fused, no ReLU)
    hipMemsetAsync(pooled, 0, (size_t)G * HC * 4, stream);
    hipMemsetAsync(cntf, 0, (size_t)G * 4, stream);
    k_pool<<<512, HC, 0, stream>>>(bufA, batch, scale3, shift3, pooled, cntf, N);
    k_build_z<<<G, 192, 0, stream>>>(pooled, cntf, origin, direction, zbuf, G);

    // ---- dense head (MFMA, bias+relu fused) ----
    gemm_head<<<dim3(DHID / 128, (G + 31) / 32), 256, 0, stream>>>(
        zbuf, wd0h, wd0l, bd0, t0, G, DHID, ZKP);
    gemm_head<<<dim3(DHID / 128, (G + 31) / 32), 256, 0, stream>>>(
        t0, wd1h, wd1l, bd1, t1, G, DHID, DHID);
    gemm_head<<<dim3(DHID / 128, (G + 31) / 32), 256, 0, stream>>>(
        t1, wd2h, wd2l, bd2, t0, G, DHID, DHID);

    k_dense_out<<<G, 256, 0, stream>>>(t0, Wout, bout, out, DHID);
}

// Round 6
// 522.719 us; speedup vs baseline: 5.2438x; 1.1787x over previous
//
#include <hip/hip_runtime.h>

#define HC 128      // hidden / latent channels
#define FIN 64
#define DHID 1024
#define ZK 134      // LAT + 6
#define ZKP 160     // ZK padded to multiple of 32 for MFMA head

typedef __attribute__((ext_vector_type(8))) short short8;
typedef __attribute__((ext_vector_type(8))) __bf16 bf16x8;
typedef __attribute__((ext_vector_type(4))) float f32x4;
typedef __attribute__((ext_vector_type(8))) unsigned short u16x8;
typedef __attribute__((ext_vector_type(4))) unsigned short u16x4;

union FragU { short8 s; bf16x8 b; u16x8 u; };

__device__ inline unsigned short rne_bf16(float x) {
    union { float f; unsigned u; } v; v.f = x;
    unsigned u = v.u;
    unsigned r = (u + 0x7fffu + ((u >> 16) & 1u)) >> 16;
    return (unsigned short)r;
}
__device__ inline float bf16_to_f(unsigned short h) {
    union { unsigned u; float f; } v; v.u = ((unsigned)h) << 16;
    return v.f;
}

// ---------------------------------------------------------------- small utils
__global__ void k_zero_i(int* p, int n) {
    int i = blockIdx.x * blockDim.x + threadIdx.x;
    if (i < n) p[i] = 0;
}

__global__ void k_deg_i(const int* __restrict__ dst, int* __restrict__ cnt, int E) {
    int i = blockIdx.x * blockDim.x + threadIdx.x;
    if (i < E) atomicAdd(&cnt[dst[i]], 1);
}

// x fp32 -> bf16 table
__global__ void k_xtobf(const float* __restrict__ x, unsigned short* __restrict__ xb, int n4) {
    int i = blockIdx.x * blockDim.x + threadIdx.x;
    if (i >= n4) return;
    float4 v = ((const float4*)x)[i];
    u16x4 o;
    o[0] = rne_bf16(v.x); o[1] = rne_bf16(v.y);
    o[2] = rne_bf16(v.z); o[3] = rne_bf16(v.w);
    ((u16x4*)xb)[i] = o;
}

// ---------------------------------------------------------------- scan (CSR row offsets) + dinv
__global__ void k_scan1(const int* __restrict__ cnt, int* __restrict__ part,
                        int* __restrict__ bsum, float* __restrict__ dinv, int N) {
    __shared__ int sh[256];
    int t = threadIdx.x, i = blockIdx.x * 256 + t;
    int v = (i < N) ? cnt[i] : 0;
    if (i < N) dinv[i] = rsqrtf((float)v + 1.0f);
    sh[t] = v; __syncthreads();
    #pragma unroll
    for (int off = 1; off < 256; off <<= 1) {
        int tv = (t >= off) ? sh[t - off] : 0;
        __syncthreads();
        sh[t] += tv;
        __syncthreads();
    }
    if (i < N) part[i] = sh[t] - v;
    if (t == 255) bsum[blockIdx.x] = sh[255];
}

__global__ void k_scan2(int* __restrict__ bsum, int nb) {
    __shared__ int sh[256];
    int t = threadIdx.x;
    int v = (t < nb) ? bsum[t] : 0;
    sh[t] = v; __syncthreads();
    #pragma unroll
    for (int off = 1; off < 256; off <<= 1) {
        int tv = (t >= off) ? sh[t - off] : 0;
        __syncthreads();
        sh[t] += tv;
        __syncthreads();
    }
    if (t < nb) bsum[t] = sh[t] - v;
}

__global__ void k_scan3(const int* __restrict__ part, const int* __restrict__ bsum,
                        int* __restrict__ row_start, int* __restrict__ cur, int N) {
    int i = blockIdx.x * 256 + threadIdx.x;
    if (i < N) { row_start[i] = part[i] + bsum[blockIdx.x]; cur[i] = 0; }
}

__global__ void k_scatter(const int* __restrict__ src, const int* __restrict__ dst,
                          const float* __restrict__ dinv, const int* __restrict__ row_start,
                          int* __restrict__ cur, int2* __restrict__ csr, int E) {
    int e = blockIdx.x * blockDim.x + threadIdx.x;
    if (e >= E) return;
    int s = src[e], d = dst[e];
    int pos = row_start[d] + atomicAdd(&cur[d], 1);
    int2 pk; pk.x = s; pk.y = __float_as_int(dinv[s] * dinv[d]);
    csr[pos] = pk;
}

// ---------------------------------------------------------------- gather (bf16 table -> bf16 out, fp32 accum)
template <int RF> struct BVec;
template <> struct BVec<64>  { using T = u16x4; static const int VPL = 4; };
template <> struct BVec<128> { using T = u16x8; static const int VPL = 8; };

// quarter-wave (16 lanes) per node; lane reads RF/16 features as one vector
template <int RF>
__global__ __launch_bounds__(256) void k_gather2b(const unsigned short* __restrict__ T,
                                                  const int2* __restrict__ csr,
                                                  const int* __restrict__ row_start,
                                                  const int* __restrict__ cnt,
                                                  const float* __restrict__ dinv,
                                                  unsigned short* __restrict__ agg, int N) {
    using vec = typename BVec<RF>::T;
    constexpr int VPL = BVec<RF>::VPL;
    int tid = threadIdx.x;
    int node = blockIdx.x * 16 + (tid >> 4);
    int q = tid & 15;
    if (node >= N) return;
    int beg = row_start[node];
    int end = beg + cnt[node];
    float d = dinv[node];
    vec sv = ((const vec*)(T + (size_t)node * RF))[q];
    float acc[VPL];
    #pragma unroll
    for (int i = 0; i < VPL; ++i) acc[i] = bf16_to_f(sv[i]) * d * d;
    int j = beg;
    for (; j + 4 <= end; j += 4) {
        int2 e0 = csr[j], e1 = csr[j + 1], e2 = csr[j + 2], e3 = csr[j + 3];
        vec v0 = ((const vec*)(T + (size_t)e0.x * RF))[q];
        vec v1 = ((const vec*)(T + (size_t)e1.x * RF))[q];
        vec v2 = ((const vec*)(T + (size_t)e2.x * RF))[q];
        vec v3 = ((const vec*)(T + (size_t)e3.x * RF))[q];
        float n0 = __int_as_float(e0.y), n1 = __int_as_float(e1.y);
        float n2 = __int_as_float(e2.y), n3 = __int_as_float(e3.y);
        #pragma unroll
        for (int i = 0; i < VPL; ++i) {
            acc[i] += bf16_to_f(v0[i]) * n0 + bf16_to_f(v1[i]) * n1
                    + bf16_to_f(v2[i]) * n2 + bf16_to_f(v3[i]) * n3;
        }
    }
    for (; j < end; ++j) {
        int2 e0 = csr[j];
        vec v0 = ((const vec*)(T + (size_t)e0.x * RF))[q];
        float n0 = __int_as_float(e0.y);
        #pragma unroll
        for (int i = 0; i < VPL; ++i) acc[i] += bf16_to_f(v0[i]) * n0;
    }
    vec o;
    #pragma unroll
    for (int i = 0; i < VPL; ++i) o[i] = rne_bf16(acc[i]);
    ((vec*)(agg + (size_t)node * RF))[q] = o;
}

// ---------------------------------------------------------------- batchnorm stats (bf16 input)
__global__ void k_bn_reduce(const unsigned short* __restrict__ x, float* __restrict__ stat, int N) {
    int f = threadIdx.x & (HC - 1);
    int half = threadIdx.x >> 7;  // 0/1
    int rpb = (N + gridDim.x - 1) / gridDim.x;
    int r0 = blockIdx.x * rpb;
    int r1 = min(N, r0 + rpb);
    float s = 0.f, ss = 0.f;
    for (int r = r0 + half; r < r1; r += 2) {
        float v = bf16_to_f(x[(size_t)r * HC + f]);
        s += v; ss += v * v;
    }
    __shared__ float sh[256], shq[256];
    sh[threadIdx.x] = s; shq[threadIdx.x] = ss;
    __syncthreads();
    if (half == 0) {
        atomicAdd(&stat[f],      sh[threadIdx.x] + sh[threadIdx.x + HC]);
        atomicAdd(&stat[HC + f], shq[threadIdx.x] + shq[threadIdx.x + HC]);
    }
}

// ---------------------------------------------------------------- pooling (BN3 inline, bf16 input)
__global__ void k_pool(const unsigned short* __restrict__ h, const int* __restrict__ batch,
                       const float* __restrict__ stat, const float* __restrict__ gam,
                       const float* __restrict__ bet, float invN,
                       float* __restrict__ pooled, float* __restrict__ cnt, int N) {
    int t = threadIdx.x;  // 0..127
    float m = stat[t] * invN;
    float var = stat[HC + t] * invN - m * m;
    float istd = rsqrtf(var + 1e-5f);
    float scv = gam[t] * istd;
    float shv = bet[t] - m * scv;
    int rpb = (N + gridDim.x - 1) / gridDim.x;
    int r0 = blockIdx.x * rpb;
    int r1 = min(N, r0 + rpb);
    if (r0 >= r1) return;
    int curb = batch[r0];
    float acc = 0.f; float c = 0.f;
    for (int r = r0; r < r1; ++r) {
        int b = batch[r];
        if (b != curb) {
            atomicAdd(&pooled[curb * HC + t], acc);
            if (t == 0) atomicAdd(&cnt[curb], c);
            curb = b; acc = 0.f; c = 0.f;
        }
        acc += bf16_to_f(h[(size_t)r * HC + t]) * scv + shv;
        c += 1.f;
    }
    atomicAdd(&pooled[curb * HC + t], acc);
    if (t == 0) atomicAdd(&cnt[curb], c);
}

// build z padded to ZKP cols (pad = 0)
__global__ void k_build_z(const float* __restrict__ pooled, const float* __restrict__ cnt,
                          const float* __restrict__ origin, const float* __restrict__ dir,
                          float* __restrict__ z, int G) {
    int g = blockIdx.x;
    int t = threadIdx.x;
    if (t >= ZKP) return;
    float v = 0.f;
    if (t < HC) {
        float c = fmaxf(cnt[g], 1.0f);
        v = pooled[g * HC + t] / c;
    } else if (t < HC + 3) {
        v = origin[g * 3 + (t - HC)];
    } else if (t < HC + 6) {
        v = dir[g * 3 + (t - HC - 3)];
    }
    z[g * ZKP + t] = v;
}

// ---------------------------------------------------------------- W prep (all 3 GCN weights): fp32 [K][128] -> bf16 hi/lo transposed [128][K]
__global__ void k_wprep_all(const float* __restrict__ W1, const float* __restrict__ W2,
                            const float* __restrict__ W3,
                            unsigned short* __restrict__ w1h, unsigned short* __restrict__ w1l,
                            unsigned short* __restrict__ w2h, unsigned short* __restrict__ w2l,
                            unsigned short* __restrict__ w3h, unsigned short* __restrict__ w3l) {
    int i = blockIdx.x * blockDim.x + threadIdx.x;
    const float* W; unsigned short *th, *tl; int K, idx;
    if (i < FIN * HC)           { W = W1; th = w1h; tl = w1l; K = FIN; idx = i; }
    else if (i < FIN*HC + HC*HC){ W = W2; th = w2h; tl = w2l; K = HC;  idx = i - FIN*HC; }
    else if (i < FIN*HC + 2*HC*HC){ W = W3; th = w3h; tl = w3l; K = HC; idx = i - FIN*HC - HC*HC; }
    else return;
    int k = idx >> 7, n = idx & (HC - 1);
    float w = W[idx];
    unsigned short h = rne_bf16(w);
    th[n * K + k] = h;
    tl[n * K + k] = rne_bf16(w - bf16_to_f(h));
}

// ---------------------------------------------------------------- W prep (head): fp32 [K][NC] -> bf16 hi/lo transposed [NC][KP]
__global__ __launch_bounds__(256) void k_wprep2(const float* __restrict__ W,
                                                unsigned short* __restrict__ th,
                                                unsigned short* __restrict__ tl,
                                                int K, int KP, int NC) {
    __shared__ float tile[32][33];
    int kt = blockIdx.x * 32, nt = blockIdx.y * 32;
    int tx = threadIdx.x & 31, ty0 = threadIdx.x >> 5;
    #pragma unroll
    for (int i = 0; i < 4; ++i) {
        int ty = ty0 + i * 8;
        int k = kt + ty;
        float v = (k < K) ? W[(size_t)k * NC + nt + tx] : 0.f;
        tile[ty][tx] = v;
    }
    __syncthreads();
    #pragma unroll
    for (int i = 0; i < 4; ++i) {
        int ty = ty0 + i * 8;
        int n = nt + ty;
        int k = kt + tx;
        float w = tile[tx][ty];
        unsigned short h = rne_bf16(w);
        th[(size_t)n * KP + k] = h;
        tl[(size_t)n * KP + k] = rne_bf16(w - bf16_to_f(h));
    }
}

// ---------------------------------------------------------------- MFMA node GEMM
// C[M,128] = act(A)[M,KK] @ W[KK,128]; A bf16, optional inline-BN(stats)+ReLU; C bf16.
template <int KK, bool BN>
__global__ __launch_bounds__(256) void gemm_node(const unsigned short* __restrict__ A,
                                                 const unsigned short* __restrict__ wth,
                                                 const unsigned short* __restrict__ wtl,
                                                 const float* __restrict__ stat,
                                                 const float* __restrict__ gam,
                                                 const float* __restrict__ bet,
                                                 float invN,
                                                 unsigned short* __restrict__ C, int M) {
    constexpr int KS = KK / 32;
    int tid = threadIdx.x;
    int lane = tid & 63, wid = tid >> 6;
    int rw = wid & 1, cw = wid >> 1;
    int l15 = lane & 15, l4 = lane >> 4;
    int m0 = blockIdx.x * 32 + rw * 16;
    int cbase = cw * 64;

    FragU bh[4][KS], bl[4][KS];
    #pragma unroll
    for (int ct = 0; ct < 4; ++ct) {
        int n = cbase + ct * 16 + l15;
        #pragma unroll
        for (int ks = 0; ks < KS; ++ks) {
            int k = ks * 32 + l4 * 8;
            bh[ct][ks].s = *(const short8*)(wth + (size_t)n * KK + k);
            bl[ct][ks].s = *(const short8*)(wtl + (size_t)n * KK + k);
        }
    }
    if (m0 >= M) return;

    int arow = m0 + l15;
    f32x4 zero = {0.f, 0.f, 0.f, 0.f};
    f32x4 acc[4] = {zero, zero, zero, zero};

    #pragma unroll
    for (int ks = 0; ks < KS; ++ks) {
        int k0 = ks * 32 + l4 * 8;
        u16x8 a = *(const u16x8*)(A + (size_t)arow * KK + k0);
        float av[8];
        #pragma unroll
        for (int i = 0; i < 8; ++i) av[i] = bf16_to_f(a[i]);
        if (BN) {
            #pragma unroll
            for (int i = 0; i < 8; ++i) {
                int k = k0 + i;
                float m = stat[k] * invN;
                float var = stat[HC + k] * invN - m * m;
                float istd = rsqrtf(var + 1e-5f);
                float sc = gam[k] * istd;
                av[i] = fmaxf(av[i] * sc + (bet[k] - m * sc), 0.f);
            }
        }
        FragU ah, al;
        #pragma unroll
        for (int i = 0; i < 8; ++i) {
            unsigned short h = rne_bf16(av[i]);
            ah.s[i] = (short)h;
            al.s[i] = (short)rne_bf16(av[i] - bf16_to_f(h));
        }
        #pragma unroll
        for (int ct = 0; ct < 4; ++ct) {
            acc[ct] = __builtin_amdgcn_mfma_f32_16x16x32_bf16(ah.b, bh[ct][ks].b, acc[ct], 0, 0, 0);
            acc[ct] = __builtin_amdgcn_mfma_f32_16x16x32_bf16(ah.b, bl[ct][ks].b, acc[ct], 0, 0, 0);
            acc[ct] = __builtin_amdgcn_mfma_f32_16x16x32_bf16(al.b, bh[ct][ks].b, acc[ct], 0, 0, 0);
        }
    }

    #pragma unroll
    for (int ct = 0; ct < 4; ++ct) {
        int col = cbase + ct * 16 + l15;
        #pragma unroll
        for (int r = 0; r < 4; ++r) {
            int row = m0 + l4 * 4 + r;
            C[(size_t)row * HC + col] = rne_bf16(acc[ct][r]);
        }
    }
}

// ---------------------------------------------------------------- MFMA head GEMM
__global__ __launch_bounds__(256) void gemm_head(const float* __restrict__ A,
                                                 const unsigned short* __restrict__ wth,
                                                 const unsigned short* __restrict__ wtl,
                                                 const float* __restrict__ bias,
                                                 float* __restrict__ C,
                                                 int M, int N, int K) {
    int tid = threadIdx.x;
    int lane = tid & 63, wid = tid >> 6;
    int rw = wid & 1, cw = wid >> 1;
    int l15 = lane & 15, l4 = lane >> 4;
    int m0 = blockIdx.y * 32 + rw * 16;
    int cb = blockIdx.x * 128 + cw * 64;
    if (m0 >= M) return;

    int arow = m0 + l15;
    f32x4 zero = {0.f, 0.f, 0.f, 0.f};
    f32x4 acc[4] = {zero, zero, zero, zero};
    int KS = K >> 5;

    for (int ks = 0; ks < KS; ++ks) {
        int k0 = ks * 32 + l4 * 8;
        const float4 p0 = *(const float4*)(A + (size_t)arow * K + k0);
        const float4 p1 = *(const float4*)(A + (size_t)arow * K + k0 + 4);
        float av[8] = {p0.x, p0.y, p0.z, p0.w, p1.x, p1.y, p1.z, p1.w};
        FragU ah, al;
        #pragma unroll
        for (int i = 0; i < 8; ++i) {
            unsigned short h = rne_bf16(av[i]);
            ah.s[i] = (short)h;
            al.s[i] = (short)rne_bf16(av[i] - bf16_to_f(h));
        }
        #pragma unroll
        for (int ct = 0; ct < 4; ++ct) {
            int n = cb + ct * 16 + l15;
            FragU bh, bl;
            bh.s = *(const short8*)(wth + (size_t)n * K + k0);
            bl.s = *(const short8*)(wtl + (size_t)n * K + k0);
            acc[ct] = __builtin_amdgcn_mfma_f32_16x16x32_bf16(ah.b, bh.b, acc[ct], 0, 0, 0);
            acc[ct] = __builtin_amdgcn_mfma_f32_16x16x32_bf16(ah.b, bl.b, acc[ct], 0, 0, 0);
            acc[ct] = __builtin_amdgcn_mfma_f32_16x16x32_bf16(al.b, bh.b, acc[ct], 0, 0, 0);
        }
    }

    #pragma unroll
    for (int ct = 0; ct < 4; ++ct) {
        int col = cb + ct * 16 + l15;
        float bv = bias[col];
        #pragma unroll
        for (int r = 0; r < 4; ++r) {
            int row = m0 + l4 * 4 + r;
            C[(size_t)row * N + col] = fmaxf(acc[ct][r] + bv, 0.f);
        }
    }
}

// final [G,DH] @ [DH,3] + bout
__global__ void k_dense_out(const float* __restrict__ z, const float* __restrict__ W,
                            const float* __restrict__ b, float* __restrict__ out, int K) {
    int g = blockIdx.x;
    const float* zr = z + (size_t)g * K;
    float a0 = 0.f, a1 = 0.f, a2 = 0.f;
    for (int k = threadIdx.x; k < K; k += blockDim.x) {
        float zv = zr[k];
        a0 += zv * W[k * 3 + 0];
        a1 += zv * W[k * 3 + 1];
        a2 += zv * W[k * 3 + 2];
    }
    __shared__ float s[768];
    s[threadIdx.x] = a0; s[256 + threadIdx.x] = a1; s[512 + threadIdx.x] = a2;
    __syncthreads();
    for (int off = 128; off > 0; off >>= 1) {
        if ((int)threadIdx.x < off) {
            s[threadIdx.x]       += s[threadIdx.x + off];
            s[256 + threadIdx.x] += s[256 + threadIdx.x + off];
            s[512 + threadIdx.x] += s[512 + threadIdx.x + off];
        }
        __syncthreads();
    }
    if (threadIdx.x == 0) {
        out[g * 3 + 0] = s[0]   + b[0];
        out[g * 3 + 1] = s[256] + b[1];
        out[g * 3 + 2] = s[512] + b[2];
    }
}

// ---------------------------------------------------------------- launch
extern "C" void kernel_launch(void* const* d_in, const int* in_sizes, int n_in,
                              void* d_out, int out_size, void* d_ws, size_t ws_size,
                              hipStream_t stream) {
    const float* x         = (const float*)d_in[0];
    const float* origin    = (const float*)d_in[1];
    const float* direction = (const float*)d_in[2];
    const int*   eidx      = (const int*)d_in[3];
    const int*   batch     = (const int*)d_in[4];
    const float* W1 = (const float*)d_in[5];
    const float* W2 = (const float*)d_in[7];
    const float* W3 = (const float*)d_in[9];
    const float* g1 = (const float*)d_in[11]; const float* be1 = (const float*)d_in[12];
    const float* g2 = (const float*)d_in[13]; const float* be2 = (const float*)d_in[14];
    const float* g3 = (const float*)d_in[15]; const float* be3 = (const float*)d_in[16];
    const float* Wd0 = (const float*)d_in[17]; const float* bd0 = (const float*)d_in[18];
    const float* Wd1 = (const float*)d_in[19]; const float* bd1 = (const float*)d_in[20];
    const float* Wd2 = (const float*)d_in[21]; const float* bd2 = (const float*)d_in[22];
    const float* Wout = (const float*)d_in[23]; const float* bout = (const float*)d_in[24];
    float* out = (float*)d_out;

    const int N = in_sizes[4];
    const int E = in_sizes[3] / 2;
    const int G = in_sizes[1] / 3;
    const int* src = eidx;
    const int* dst = eidx + E;

    char* ws = (char*)d_ws;
    size_t off = 0;
    auto alloc = [&](size_t nbytes) -> void* {
        void* p = (void*)(ws + off);
        off += (nbytes + 255) & ~(size_t)255;
        return p;
    };
    // zero-init region (one memset): colstats[3 slots x 2 x HC] | pooled | cntf
    float* colstats = (float*)alloc(3 * 2 * HC * 4);          // 3072 B
    float* pooled   = (float*)alloc((size_t)G * HC * 4);      // 131072 B
    float* cntf     = (float*)alloc((size_t)G * 4);           // 1024 B
    const size_t zeroBytes = 3 * 2 * HC * 4 + (size_t)G * HC * 4 + (size_t)G * 4;

    float* dinv     = (float*)alloc((size_t)N * 4);
    int*   degcnt   = (int*)alloc((size_t)N * 4);
    int*   part     = (int*)alloc((size_t)N * 4);
    int*   bsum     = (int*)alloc(256 * 4);
    int*   row_start= (int*)alloc((size_t)N * 4);
    int*   cur      = (int*)alloc((size_t)N * 4);
    int2*  csr      = (int2*)alloc((size_t)E * 8);
    unsigned short* xb   = (unsigned short*)alloc((size_t)N * FIN * 2);
    unsigned short* aggx = (unsigned short*)alloc((size_t)N * FIN * 2);
    unsigned short* tabA = (unsigned short*)alloc((size_t)N * HC * 2);
    unsigned short* tabB = (unsigned short*)alloc((size_t)N * HC * 2);
    unsigned short* wt1h = (unsigned short*)alloc((size_t)FIN * HC * 2);
    unsigned short* wt1l = (unsigned short*)alloc((size_t)FIN * HC * 2);
    unsigned short* wt2h = (unsigned short*)alloc((size_t)HC * HC * 2);
    unsigned short* wt2l = (unsigned short*)alloc((size_t)HC * HC * 2);
    unsigned short* wt3h = (unsigned short*)alloc((size_t)HC * HC * 2);
    unsigned short* wt3l = (unsigned short*)alloc((size_t)HC * HC * 2);
    unsigned short* wd0h = (unsigned short*)alloc((size_t)DHID * ZKP * 2);
    unsigned short* wd0l = (unsigned short*)alloc((size_t)DHID * ZKP * 2);
    unsigned short* wd1h = (unsigned short*)alloc((size_t)DHID * DHID * 2);
    unsigned short* wd1l = (unsigned short*)alloc((size_t)DHID * DHID * 2);
    unsigned short* wd2h = (unsigned short*)alloc((size_t)DHID * DHID * 2);
    unsigned short* wd2l = (unsigned short*)alloc((size_t)DHID * DHID * 2);
    float* zbuf     = (float*)alloc((size_t)G * ZKP * 4);
    float* t0       = (float*)alloc((size_t)G * DHID * 4);
    float* t1       = (float*)alloc((size_t)G * DHID * 4);
    (void)ws_size;

    const int nScanBlk = (N + 255) / 256;
    const int gemmBlk = (N + 31) / 32;
    const int gatherBlk = (N + 15) / 16;
    const float invN = 1.0f / (float)N;

    hipMemsetAsync(colstats, 0, zeroBytes, stream);

    // ---- weight prep + x conversion ----
    k_xtobf<<<(N * FIN / 4 + 255) / 256, 256, 0, stream>>>(x, xb, N * FIN / 4);
    k_wprep_all<<<(FIN * HC + 2 * HC * HC + 255) / 256, 256, 0, stream>>>(
        W1, W2, W3, wt1h, wt1l, wt2h, wt2l, wt3h, wt3l);
    k_wprep2<<<dim3(ZKP / 32, DHID / 32), 256, 0, stream>>>(Wd0, wd0h, wd0l, ZK, ZKP, DHID);
    k_wprep2<<<dim3(DHID / 32, DHID / 32), 256, 0, stream>>>(Wd1, wd1h, wd1l, DHID, DHID, DHID);
    k_wprep2<<<dim3(DHID / 32, DHID / 32), 256, 0, stream>>>(Wd2, wd2h, wd2l, DHID, DHID, DHID);

    // ---- CSR build ----
    k_zero_i<<<nScanBlk, 256, 0, stream>>>(degcnt, N);
    k_deg_i<<<(E + 255) / 256, 256, 0, stream>>>(dst, degcnt, E);
    k_scan1<<<nScanBlk, 256, 0, stream>>>(degcnt, part, bsum, dinv, N);
    k_scan2<<<1, 256, 0, stream>>>(bsum, nScanBlk);
    k_scan3<<<nScanBlk, 256, 0, stream>>>(part, bsum, row_start, cur, N);
    k_scatter<<<(E + 255) / 256, 256, 0, stream>>>(src, dst, dinv, row_start, cur, csr, E);

    // ---- layer 1: gather(x) -> gemm -> stats0 (on C1 = tabA) ----
    k_gather2b<FIN><<<gatherBlk, 256, 0, stream>>>(xb, csr, row_start, degcnt, dinv, aggx, N);
    gemm_node<FIN, false><<<gemmBlk, 256, 0, stream>>>(aggx, wt1h, wt1l, nullptr, nullptr,
                                                       nullptr, invN, tabA, N);
    k_bn_reduce<<<256, 256, 0, stream>>>(tabA, colstats + 0 * 2 * HC, N);

    // ---- layer 2: gemm(BN1 inline) -> gather -> stats1 (on agg2 = tabA) ----
    gemm_node<HC, true><<<gemmBlk, 256, 0, stream>>>(tabA, wt2h, wt2l, colstats + 0 * 2 * HC,
                                                     g1, be1, invN, tabB, N);
    k_gather2b<HC><<<gatherBlk, 256, 0, stream>>>(tabB, csr, row_start, degcnt, dinv, tabA, N);
    k_bn_reduce<<<256, 256, 0, stream>>>(tabA, colstats + 1 * 2 * HC, N);

    // ---- layer 3 ----
    gemm_node<HC, true><<<gemmBlk, 256, 0, stream>>>(tabA, wt3h, wt3l, colstats + 1 * 2 * HC,
                                                     g2, be2, invN, tabB, N);
    k_gather2b<HC><<<gatherBlk, 256, 0, stream>>>(tabB, csr, row_start, degcnt, dinv, tabA, N);
    k_bn_reduce<<<256, 256, 0, stream>>>(tabA, colstats + 2 * 2 * HC, N);

    // ---- pool (BN3 inline) + z ----
    k_pool<<<512, HC, 0, stream>>>(tabA, batch, colstats + 2 * 2 * HC, g3, be3, invN,
                                   pooled, cntf, N);
    k_build_z<<<G, 192, 0, stream>>>(pooled, cntf, origin, direction, zbuf, G);

    // ---- dense head (MFMA, bias+relu fused) ----
    gemm_head<<<dim3(DHID / 128, (G + 31) / 32), 256, 0, stream>>>(
        zbuf, wd0h, wd0l, bd0, t0, G, DHID, ZKP);
    gemm_head<<<dim3(DHID / 128, (G + 31) / 32), 256, 0, stream>>>(
        t0, wd1h, wd1l, bd1, t1, G, DHID, DHID);
    gemm_head<<<dim3(DHID / 128, (G + 31) / 32), 256, 0, stream>>>(
        t1, wd2h, wd2l, bd2, t0, G, DHID, DHID);

    k_dense_out<<<G, 256, 0, stream>>>(t0, Wout, bout, out, DHID);
}

// Round 7
// 456.606 us; speedup vs baseline: 6.0031x; 1.1448x over previous
//
#include <hip/hip_runtime.h>

#define HC 128      // hidden / latent channels
#define FIN 64
#define DHID 1024
#define ZK 134      // LAT + 6
#define ZKP 160     // ZK padded to multiple of 32 for MFMA head

typedef __attribute__((ext_vector_type(8))) short short8;
typedef __attribute__((ext_vector_type(8))) __bf16 bf16x8;
typedef __attribute__((ext_vector_type(4))) float f32x4;
typedef __attribute__((ext_vector_type(8))) unsigned short u16x8;
typedef __attribute__((ext_vector_type(4))) unsigned short u16x4;

union FragU { short8 s; bf16x8 b; u16x8 u; };

__device__ inline unsigned short rne_bf16(float x) {
    union { float f; unsigned u; } v; v.f = x;
    unsigned u = v.u;
    unsigned r = (u + 0x7fffu + ((u >> 16) & 1u)) >> 16;
    return (unsigned short)r;
}
__device__ inline float bf16_to_f(unsigned short h) {
    union { unsigned u; float f; } v; v.u = ((unsigned)h) << 16;
    return v.f;
}

// ---------------------------------------------------------------- small utils
__global__ void k_zero_i(int* p, int n) {
    int i = blockIdx.x * blockDim.x + threadIdx.x;
    if (i < n) p[i] = 0;
}

__global__ void k_deg_i(const int* __restrict__ dst, int* __restrict__ cnt, int E) {
    int i = blockIdx.x * blockDim.x + threadIdx.x;
    if (i < E) atomicAdd(&cnt[dst[i]], 1);
}

// x fp32 -> bf16 table
__global__ void k_xtobf(const float* __restrict__ x, unsigned short* __restrict__ xb, int n4) {
    int i = blockIdx.x * blockDim.x + threadIdx.x;
    if (i >= n4) return;
    float4 v = ((const float4*)x)[i];
    u16x4 o;
    o[0] = rne_bf16(v.x); o[1] = rne_bf16(v.y);
    o[2] = rne_bf16(v.z); o[3] = rne_bf16(v.w);
    ((u16x4*)xb)[i] = o;
}

// ---------------------------------------------------------------- scan (CSR row offsets) + dinv
__global__ void k_scan1(const int* __restrict__ cnt, int* __restrict__ part,
                        int* __restrict__ bsum, float* __restrict__ dinv, int N) {
    __shared__ int sh[256];
    int t = threadIdx.x, i = blockIdx.x * 256 + t;
    int v = (i < N) ? cnt[i] : 0;
    if (i < N) dinv[i] = rsqrtf((float)v + 1.0f);
    sh[t] = v; __syncthreads();
    #pragma unroll
    for (int off = 1; off < 256; off <<= 1) {
        int tv = (t >= off) ? sh[t - off] : 0;
        __syncthreads();
        sh[t] += tv;
        __syncthreads();
    }
    if (i < N) part[i] = sh[t] - v;
    if (t == 255) bsum[blockIdx.x] = sh[255];
}

__global__ void k_scan2(int* __restrict__ bsum, int nb) {
    __shared__ int sh[256];
    int t = threadIdx.x;
    int v = (t < nb) ? bsum[t] : 0;
    sh[t] = v; __syncthreads();
    #pragma unroll
    for (int off = 1; off < 256; off <<= 1) {
        int tv = (t >= off) ? sh[t - off] : 0;
        __syncthreads();
        sh[t] += tv;
        __syncthreads();
    }
    if (t < nb) bsum[t] = sh[t] - v;
}

__global__ void k_scan3(const int* __restrict__ part, const int* __restrict__ bsum,
                        int* __restrict__ row_start, int* __restrict__ cur, int N) {
    int i = blockIdx.x * 256 + threadIdx.x;
    if (i < N) { row_start[i] = part[i] + bsum[blockIdx.x]; cur[i] = 0; }
}

__global__ void k_scatter(const int* __restrict__ src, const int* __restrict__ dst,
                          const float* __restrict__ dinv, const int* __restrict__ row_start,
                          int* __restrict__ cur, int2* __restrict__ csr, int E) {
    int e = blockIdx.x * blockDim.x + threadIdx.x;
    if (e >= E) return;
    int s = src[e], d = dst[e];
    int pos = row_start[d] + atomicAdd(&cur[d], 1);
    int2 pk; pk.x = s; pk.y = __float_as_int(dinv[s] * dinv[d]);
    csr[pos] = pk;
}

// ---------------------------------------------------------------- gather (bf16 table -> bf16 out, fp32 accum)
template <int RF> struct BVec;
template <> struct BVec<64>  { using T = u16x4; static const int VPL = 4; };
template <> struct BVec<128> { using T = u16x8; static const int VPL = 8; };

// quarter-wave (16 lanes) per node; lane reads RF/16 features as one vector
template <int RF>
__global__ __launch_bounds__(256) void k_gather2b(const unsigned short* __restrict__ T,
                                                  const int2* __restrict__ csr,
                                                  const int* __restrict__ row_start,
                                                  const int* __restrict__ cnt,
                                                  const float* __restrict__ dinv,
                                                  unsigned short* __restrict__ agg, int N) {
    using vec = typename BVec<RF>::T;
    constexpr int VPL = BVec<RF>::VPL;
    int tid = threadIdx.x;
    int node = blockIdx.x * 16 + (tid >> 4);
    int q = tid & 15;
    if (node >= N) return;
    int beg = row_start[node];
    int end = beg + cnt[node];
    float d = dinv[node];
    vec sv = ((const vec*)(T + (size_t)node * RF))[q];
    float acc[VPL];
    #pragma unroll
    for (int i = 0; i < VPL; ++i) acc[i] = bf16_to_f(sv[i]) * d * d;
    int j = beg;
    for (; j + 4 <= end; j += 4) {
        int2 e0 = csr[j], e1 = csr[j + 1], e2 = csr[j + 2], e3 = csr[j + 3];
        vec v0 = ((const vec*)(T + (size_t)e0.x * RF))[q];
        vec v1 = ((const vec*)(T + (size_t)e1.x * RF))[q];
        vec v2 = ((const vec*)(T + (size_t)e2.x * RF))[q];
        vec v3 = ((const vec*)(T + (size_t)e3.x * RF))[q];
        float n0 = __int_as_float(e0.y), n1 = __int_as_float(e1.y);
        float n2 = __int_as_float(e2.y), n3 = __int_as_float(e3.y);
        #pragma unroll
        for (int i = 0; i < VPL; ++i) {
            acc[i] += bf16_to_f(v0[i]) * n0 + bf16_to_f(v1[i]) * n1
                    + bf16_to_f(v2[i]) * n2 + bf16_to_f(v3[i]) * n3;
        }
    }
    for (; j < end; ++j) {
        int2 e0 = csr[j];
        vec v0 = ((const vec*)(T + (size_t)e0.x * RF))[q];
        float n0 = __int_as_float(e0.y);
        #pragma unroll
        for (int i = 0; i < VPL; ++i) acc[i] += bf16_to_f(v0[i]) * n0;
    }
    vec o;
    #pragma unroll
    for (int i = 0; i < VPL; ++i) o[i] = rne_bf16(acc[i]);
    ((vec*)(agg + (size_t)node * RF))[q] = o;
}

// ---------------------------------------------------------------- batchnorm stats (bf16 input)
__global__ void k_bn_reduce(const unsigned short* __restrict__ x, float* __restrict__ stat, int N) {
    int f = threadIdx.x & (HC - 1);
    int half = threadIdx.x >> 7;  // 0/1
    int rpb = (N + gridDim.x - 1) / gridDim.x;
    int r0 = blockIdx.x * rpb;
    int r1 = min(N, r0 + rpb);
    float s = 0.f, ss = 0.f;
    for (int r = r0 + half; r < r1; r += 2) {
        float v = bf16_to_f(x[(size_t)r * HC + f]);
        s += v; ss += v * v;
    }
    __shared__ float sh[256], shq[256];
    sh[threadIdx.x] = s; shq[threadIdx.x] = ss;
    __syncthreads();
    if (half == 0) {
        atomicAdd(&stat[f],      sh[threadIdx.x] + sh[threadIdx.x + HC]);
        atomicAdd(&stat[HC + f], shq[threadIdx.x] + shq[threadIdx.x + HC]);
    }
}

// ---------------------------------------------------------------- pooling (BN3 inline, bf16 input)
__global__ void k_pool(const unsigned short* __restrict__ h, const int* __restrict__ batch,
                       const float* __restrict__ stat, const float* __restrict__ gam,
                       const float* __restrict__ bet, float invN,
                       float* __restrict__ pooled, float* __restrict__ cnt, int N) {
    int t = threadIdx.x;  // 0..127
    float m = stat[t] * invN;
    float var = stat[HC + t] * invN - m * m;
    float istd = rsqrtf(var + 1e-5f);
    float scv = gam[t] * istd;
    float shv = bet[t] - m * scv;
    int rpb = (N + gridDim.x - 1) / gridDim.x;
    int r0 = blockIdx.x * rpb;
    int r1 = min(N, r0 + rpb);
    if (r0 >= r1) return;
    int curb = batch[r0];
    float acc = 0.f; float c = 0.f;
    for (int r = r0; r < r1; ++r) {
        int b = batch[r];
        if (b != curb) {
            atomicAdd(&pooled[curb * HC + t], acc);
            if (t == 0) atomicAdd(&cnt[curb], c);
            curb = b; acc = 0.f; c = 0.f;
        }
        acc += bf16_to_f(h[(size_t)r * HC + t]) * scv + shv;
        c += 1.f;
    }
    atomicAdd(&pooled[curb * HC + t], acc);
    if (t == 0) atomicAdd(&cnt[curb], c);
}

// build z padded to ZKP cols (pad = 0)
__global__ void k_build_z(const float* __restrict__ pooled, const float* __restrict__ cnt,
                          const float* __restrict__ origin, const float* __restrict__ dir,
                          float* __restrict__ z, int G) {
    int g = blockIdx.x;
    int t = threadIdx.x;
    if (t >= ZKP) return;
    float v = 0.f;
    if (t < HC) {
        float c = fmaxf(cnt[g], 1.0f);
        v = pooled[g * HC + t] / c;
    } else if (t < HC + 3) {
        v = origin[g * 3 + (t - HC)];
    } else if (t < HC + 6) {
        v = dir[g * 3 + (t - HC - 3)];
    }
    z[g * ZKP + t] = v;
}

// ---------------------------------------------------------------- W prep (all 3 GCN weights): fp32 [K][128] -> bf16 hi/lo transposed [128][K]
__global__ void k_wprep_all(const float* __restrict__ W1, const float* __restrict__ W2,
                            const float* __restrict__ W3,
                            unsigned short* __restrict__ w1h, unsigned short* __restrict__ w1l,
                            unsigned short* __restrict__ w2h, unsigned short* __restrict__ w2l,
                            unsigned short* __restrict__ w3h, unsigned short* __restrict__ w3l) {
    int i = blockIdx.x * blockDim.x + threadIdx.x;
    const float* W; unsigned short *th, *tl; int K, idx;
    if (i < FIN * HC)           { W = W1; th = w1h; tl = w1l; K = FIN; idx = i; }
    else if (i < FIN*HC + HC*HC){ W = W2; th = w2h; tl = w2l; K = HC;  idx = i - FIN*HC; }
    else if (i < FIN*HC + 2*HC*HC){ W = W3; th = w3h; tl = w3l; K = HC; idx = i - FIN*HC - HC*HC; }
    else return;
    int k = idx >> 7, n = idx & (HC - 1);
    float w = W[idx];
    unsigned short h = rne_bf16(w);
    th[n * K + k] = h;
    tl[n * K + k] = rne_bf16(w - bf16_to_f(h));
}

// ---------------------------------------------------------------- W prep (head): fp32 [K][NC] -> bf16 hi/lo transposed [NC][KP]
__global__ __launch_bounds__(256) void k_wprep2(const float* __restrict__ W,
                                                unsigned short* __restrict__ th,
                                                unsigned short* __restrict__ tl,
                                                int K, int KP, int NC) {
    __shared__ float tile[32][33];
    int kt = blockIdx.x * 32, nt = blockIdx.y * 32;
    int tx = threadIdx.x & 31, ty0 = threadIdx.x >> 5;
    #pragma unroll
    for (int i = 0; i < 4; ++i) {
        int ty = ty0 + i * 8;
        int k = kt + ty;
        float v = (k < K) ? W[(size_t)k * NC + nt + tx] : 0.f;
        tile[ty][tx] = v;
    }
    __syncthreads();
    #pragma unroll
    for (int i = 0; i < 4; ++i) {
        int ty = ty0 + i * 8;
        int n = nt + ty;
        int k = kt + tx;
        float w = tile[tx][ty];
        unsigned short h = rne_bf16(w);
        th[(size_t)n * KP + k] = h;
        tl[(size_t)n * KP + k] = rne_bf16(w - bf16_to_f(h));
    }
}

// ---------------------------------------------------------------- MFMA node GEMM
// C[M,128] = act(A)[M,KK] @ W[KK,128]; A bf16, optional inline-BN(stats)+ReLU; C bf16.
template <int KK, bool BN>
__global__ __launch_bounds__(256) void gemm_node(const unsigned short* __restrict__ A,
                                                 const unsigned short* __restrict__ wth,
                                                 const unsigned short* __restrict__ wtl,
                                                 const float* __restrict__ stat,
                                                 const float* __restrict__ gam,
                                                 const float* __restrict__ bet,
                                                 float invN,
                                                 unsigned short* __restrict__ C, int M) {
    constexpr int KS = KK / 32;
    int tid = threadIdx.x;
    int lane = tid & 63, wid = tid >> 6;
    int rw = wid & 1, cw = wid >> 1;
    int l15 = lane & 15, l4 = lane >> 4;
    int m0 = blockIdx.x * 32 + rw * 16;
    int cbase = cw * 64;

    FragU bh[4][KS], bl[4][KS];
    #pragma unroll
    for (int ct = 0; ct < 4; ++ct) {
        int n = cbase + ct * 16 + l15;
        #pragma unroll
        for (int ks = 0; ks < KS; ++ks) {
            int k = ks * 32 + l4 * 8;
            bh[ct][ks].s = *(const short8*)(wth + (size_t)n * KK + k);
            bl[ct][ks].s = *(const short8*)(wtl + (size_t)n * KK + k);
        }
    }
    if (m0 >= M) return;

    int arow = m0 + l15;
    f32x4 zero = {0.f, 0.f, 0.f, 0.f};
    f32x4 acc[4] = {zero, zero, zero, zero};

    #pragma unroll
    for (int ks = 0; ks < KS; ++ks) {
        int k0 = ks * 32 + l4 * 8;
        u16x8 a = *(const u16x8*)(A + (size_t)arow * KK + k0);
        float av[8];
        #pragma unroll
        for (int i = 0; i < 8; ++i) av[i] = bf16_to_f(a[i]);
        if (BN) {
            #pragma unroll
            for (int i = 0; i < 8; ++i) {
                int k = k0 + i;
                float m = stat[k] * invN;
                float var = stat[HC + k] * invN - m * m;
                float istd = rsqrtf(var + 1e-5f);
                float sc = gam[k] * istd;
                av[i] = fmaxf(av[i] * sc + (bet[k] - m * sc), 0.f);
            }
        }
        FragU ah, al;
        #pragma unroll
        for (int i = 0; i < 8; ++i) {
            unsigned short h = rne_bf16(av[i]);
            ah.s[i] = (short)h;
            al.s[i] = (short)rne_bf16(av[i] - bf16_to_f(h));
        }
        #pragma unroll
        for (int ct = 0; ct < 4; ++ct) {
            acc[ct] = __builtin_amdgcn_mfma_f32_16x16x32_bf16(ah.b, bh[ct][ks].b, acc[ct], 0, 0, 0);
            acc[ct] = __builtin_amdgcn_mfma_f32_16x16x32_bf16(ah.b, bl[ct][ks].b, acc[ct], 0, 0, 0);
            acc[ct] = __builtin_amdgcn_mfma_f32_16x16x32_bf16(al.b, bh[ct][ks].b, acc[ct], 0, 0, 0);
        }
    }

    #pragma unroll
    for (int ct = 0; ct < 4; ++ct) {
        int col = cbase + ct * 16 + l15;
        #pragma unroll
        for (int r = 0; r < 4; ++r) {
            int row = m0 + l4 * 4 + r;
            C[(size_t)row * HC + col] = rne_bf16(acc[ct][r]);
        }
    }
}

// ---------------------------------------------------------------- MFMA head GEMM, split-K
// partial[z][M,N] = A[M, kslice] @ W[kslice, N]; 32 rows x 64 cols per block (2x2 waves)
__global__ __launch_bounds__(256) void gemm_head_sk(const float* __restrict__ A,
                                                    const unsigned short* __restrict__ wth,
                                                    const unsigned short* __restrict__ wtl,
                                                    float* __restrict__ Cpart,
                                                    int M, int N, int K, int slice) {
    int tid = threadIdx.x;
    int lane = tid & 63, wid = tid >> 6;
    int rw = wid & 1, cw = wid >> 1;      // rw: 0/1 rows, cw: 0/1 cols
    int l15 = lane & 15, l4 = lane >> 4;
    int m0 = blockIdx.y * 32 + rw * 16;
    int cb = blockIdx.x * 64 + cw * 32;
    int z = blockIdx.z;
    int kbeg = z * slice;
    int kend = min(K, kbeg + slice);
    if (m0 >= M) return;

    int arow = m0 + l15;
    f32x4 zero = {0.f, 0.f, 0.f, 0.f};
    f32x4 acc[2] = {zero, zero};

    for (int k0 = kbeg; k0 < kend; k0 += 32) {
        int ka = k0 + l4 * 8;
        const float4 p0 = *(const float4*)(A + (size_t)arow * K + ka);
        const float4 p1 = *(const float4*)(A + (size_t)arow * K + ka + 4);
        float av[8] = {p0.x, p0.y, p0.z, p0.w, p1.x, p1.y, p1.z, p1.w};
        FragU ah, al;
        #pragma unroll
        for (int i = 0; i < 8; ++i) {
            unsigned short h = rne_bf16(av[i]);
            ah.s[i] = (short)h;
            al.s[i] = (short)rne_bf16(av[i] - bf16_to_f(h));
        }
        #pragma unroll
        for (int ct = 0; ct < 2; ++ct) {
            int n = cb + ct * 16 + l15;
            FragU bh, bl;
            bh.s = *(const short8*)(wth + (size_t)n * K + ka);
            bl.s = *(const short8*)(wtl + (size_t)n * K + ka);
            acc[ct] = __builtin_amdgcn_mfma_f32_16x16x32_bf16(ah.b, bh.b, acc[ct], 0, 0, 0);
            acc[ct] = __builtin_amdgcn_mfma_f32_16x16x32_bf16(ah.b, bl.b, acc[ct], 0, 0, 0);
            acc[ct] = __builtin_amdgcn_mfma_f32_16x16x32_bf16(al.b, bh.b, acc[ct], 0, 0, 0);
        }
    }

    float* Cz = Cpart + (size_t)z * M * N;
    #pragma unroll
    for (int ct = 0; ct < 2; ++ct) {
        int col = cb + ct * 16 + l15;
        #pragma unroll
        for (int r = 0; r < 4; ++r) {
            int row = m0 + l4 * 4 + r;
            Cz[(size_t)row * N + col] = acc[ct][r];
        }
    }
}

// sum NZ partials + bias + relu; N power of two (DHID)
__global__ void k_reduce_br(const float* __restrict__ part, const float* __restrict__ bias,
                            float* __restrict__ C, int MN, int Nmask, int NZ) {
    int i = (blockIdx.x * blockDim.x + threadIdx.x) * 4;
    if (i >= MN) return;
    float4 acc = *(const float4*)(part + i);
    for (int zz = 1; zz < NZ; ++zz) {
        float4 p = *(const float4*)(part + (size_t)zz * MN + i);
        acc.x += p.x; acc.y += p.y; acc.z += p.z; acc.w += p.w;
    }
    int n = i & Nmask;
    acc.x += bias[n]; acc.y += bias[n + 1]; acc.z += bias[n + 2]; acc.w += bias[n + 3];
    acc.x = fmaxf(acc.x, 0.f); acc.y = fmaxf(acc.y, 0.f);
    acc.z = fmaxf(acc.z, 0.f); acc.w = fmaxf(acc.w, 0.f);
    *(float4*)(C + i) = acc;
}

// final [G,DH] @ [DH,3] + bout
__global__ void k_dense_out(const float* __restrict__ z, const float* __restrict__ W,
                            const float* __restrict__ b, float* __restrict__ out, int K) {
    int g = blockIdx.x;
    const float* zr = z + (size_t)g * K;
    float a0 = 0.f, a1 = 0.f, a2 = 0.f;
    for (int k = threadIdx.x; k < K; k += blockDim.x) {
        float zv = zr[k];
        a0 += zv * W[k * 3 + 0];
        a1 += zv * W[k * 3 + 1];
        a2 += zv * W[k * 3 + 2];
    }
    __shared__ float s[768];
    s[threadIdx.x] = a0; s[256 + threadIdx.x] = a1; s[512 + threadIdx.x] = a2;
    __syncthreads();
    for (int off = 128; off > 0; off >>= 1) {
        if ((int)threadIdx.x < off) {
            s[threadIdx.x]       += s[threadIdx.x + off];
            s[256 + threadIdx.x] += s[256 + threadIdx.x + off];
            s[512 + threadIdx.x] += s[512 + threadIdx.x + off];
        }
        __syncthreads();
    }
    if (threadIdx.x == 0) {
        out[g * 3 + 0] = s[0]   + b[0];
        out[g * 3 + 1] = s[256] + b[1];
        out[g * 3 + 2] = s[512] + b[2];
    }
}

// ---------------------------------------------------------------- launch
extern "C" void kernel_launch(void* const* d_in, const int* in_sizes, int n_in,
                              void* d_out, int out_size, void* d_ws, size_t ws_size,
                              hipStream_t stream) {
    const float* x         = (const float*)d_in[0];
    const float* origin    = (const float*)d_in[1];
    const float* direction = (const float*)d_in[2];
    const int*   eidx      = (const int*)d_in[3];
    const int*   batch     = (const int*)d_in[4];
    const float* W1 = (const float*)d_in[5];
    const float* W2 = (const float*)d_in[7];
    const float* W3 = (const float*)d_in[9];
    const float* g1 = (const float*)d_in[11]; const float* be1 = (const float*)d_in[12];
    const float* g2 = (const float*)d_in[13]; const float* be2 = (const float*)d_in[14];
    const float* g3 = (const float*)d_in[15]; const float* be3 = (const float*)d_in[16];
    const float* Wd0 = (const float*)d_in[17]; const float* bd0 = (const float*)d_in[18];
    const float* Wd1 = (const float*)d_in[19]; const float* bd1 = (const float*)d_in[20];
    const float* Wd2 = (const float*)d_in[21]; const float* bd2 = (const float*)d_in[22];
    const float* Wout = (const float*)d_in[23]; const float* bout = (const float*)d_in[24];
    float* out = (float*)d_out;

    const int N = in_sizes[4];
    const int E = in_sizes[3] / 2;
    const int G = in_sizes[1] / 3;
    const int* src = eidx;
    const int* dst = eidx + E;

    char* ws = (char*)d_ws;
    size_t off = 0;
    auto alloc = [&](size_t nbytes) -> void* {
        void* p = (void*)(ws + off);
        off += (nbytes + 255) & ~(size_t)255;
        return p;
    };
    // zero-init region (one memset): colstats[3 slots x 2 x HC] | pooled | cntf
    float* colstats = (float*)alloc(3 * 2 * HC * 4);
    float* pooled   = (float*)alloc((size_t)G * HC * 4);
    float* cntf     = (float*)alloc((size_t)G * 4);
    const size_t zeroBytes = 3 * 2 * HC * 4 + (size_t)G * HC * 4 + (size_t)G * 4;

    float* dinv     = (float*)alloc((size_t)N * 4);
    int*   degcnt   = (int*)alloc((size_t)N * 4);
    int*   part     = (int*)alloc((size_t)N * 4);
    int*   bsum     = (int*)alloc(256 * 4);
    int*   row_start= (int*)alloc((size_t)N * 4);
    int*   cur      = (int*)alloc((size_t)N * 4);
    int2*  csr      = (int2*)alloc((size_t)E * 8);
    unsigned short* xb   = (unsigned short*)alloc((size_t)N * FIN * 2);
    unsigned short* aggx = (unsigned short*)alloc((size_t)N * FIN * 2);
    unsigned short* tabA = (unsigned short*)alloc((size_t)N * HC * 2);
    unsigned short* tabB = (unsigned short*)alloc((size_t)N * HC * 2);
    unsigned short* wt1h = (unsigned short*)alloc((size_t)FIN * HC * 2);
    unsigned short* wt1l = (unsigned short*)alloc((size_t)FIN * HC * 2);
    unsigned short* wt2h = (unsigned short*)alloc((size_t)HC * HC * 2);
    unsigned short* wt2l = (unsigned short*)alloc((size_t)HC * HC * 2);
    unsigned short* wt3h = (unsigned short*)alloc((size_t)HC * HC * 2);
    unsigned short* wt3l = (unsigned short*)alloc((size_t)HC * HC * 2);
    unsigned short* wd0h = (unsigned short*)alloc((size_t)DHID * ZKP * 2);
    unsigned short* wd0l = (unsigned short*)alloc((size_t)DHID * ZKP * 2);
    unsigned short* wd1h = (unsigned short*)alloc((size_t)DHID * DHID * 2);
    unsigned short* wd1l = (unsigned short*)alloc((size_t)DHID * DHID * 2);
    unsigned short* wd2h = (unsigned short*)alloc((size_t)DHID * DHID * 2);
    unsigned short* wd2l = (unsigned short*)alloc((size_t)DHID * DHID * 2);
    float* zbuf     = (float*)alloc((size_t)G * ZKP * 4);
    float* t0       = (float*)alloc((size_t)G * DHID * 4);
    float* t1       = (float*)alloc((size_t)G * DHID * 4);
    float* kpart    = (float*)alloc((size_t)8 * G * DHID * 4);   // 8 MB split-K partials
    (void)ws_size;

    const int nScanBlk = (N + 255) / 256;
    const int gemmBlk = (N + 31) / 32;
    const int gatherBlk = (N + 15) / 16;
    const float invN = 1.0f / (float)N;

    hipMemsetAsync(colstats, 0, zeroBytes, stream);

    // ---- weight prep + x conversion ----
    k_xtobf<<<(N * FIN / 4 + 255) / 256, 256, 0, stream>>>(x, xb, N * FIN / 4);
    k_wprep_all<<<(FIN * HC + 2 * HC * HC + 255) / 256, 256, 0, stream>>>(
        W1, W2, W3, wt1h, wt1l, wt2h, wt2l, wt3h, wt3l);
    k_wprep2<<<dim3(ZKP / 32, DHID / 32), 256, 0, stream>>>(Wd0, wd0h, wd0l, ZK, ZKP, DHID);
    k_wprep2<<<dim3(DHID / 32, DHID / 32), 256, 0, stream>>>(Wd1, wd1h, wd1l, DHID, DHID, DHID);
    k_wprep2<<<dim3(DHID / 32, DHID / 32), 256, 0, stream>>>(Wd2, wd2h, wd2l, DHID, DHID, DHID);

    // ---- CSR build ----
    k_zero_i<<<nScanBlk, 256, 0, stream>>>(degcnt, N);
    k_deg_i<<<(E + 255) / 256, 256, 0, stream>>>(dst, degcnt, E);
    k_scan1<<<nScanBlk, 256, 0, stream>>>(degcnt, part, bsum, dinv, N);
    k_scan2<<<1, 256, 0, stream>>>(bsum, nScanBlk);
    k_scan3<<<nScanBlk, 256, 0, stream>>>(part, bsum, row_start, cur, N);
    k_scatter<<<(E + 255) / 256, 256, 0, stream>>>(src, dst, dinv, row_start, cur, csr, E);

    // ---- layer 1: gather(x) -> gemm -> stats0 ----
    k_gather2b<FIN><<<gatherBlk, 256, 0, stream>>>(xb, csr, row_start, degcnt, dinv, aggx, N);
    gemm_node<FIN, false><<<gemmBlk, 256, 0, stream>>>(aggx, wt1h, wt1l, nullptr, nullptr,
                                                       nullptr, invN, tabA, N);
    k_bn_reduce<<<256, 256, 0, stream>>>(tabA, colstats + 0 * 2 * HC, N);

    // ---- layer 2 ----
    gemm_node<HC, true><<<gemmBlk, 256, 0, stream>>>(tabA, wt2h, wt2l, colstats + 0 * 2 * HC,
                                                     g1, be1, invN, tabB, N);
    k_gather2b<HC><<<gatherBlk, 256, 0, stream>>>(tabB, csr, row_start, degcnt, dinv, tabA, N);
    k_bn_reduce<<<256, 256, 0, stream>>>(tabA, colstats + 1 * 2 * HC, N);

    // ---- layer 3 ----
    gemm_node<HC, true><<<gemmBlk, 256, 0, stream>>>(tabA, wt3h, wt3l, colstats + 1 * 2 * HC,
                                                     g2, be2, invN, tabB, N);
    k_gather2b<HC><<<gatherBlk, 256, 0, stream>>>(tabB, csr, row_start, degcnt, dinv, tabA, N);
    k_bn_reduce<<<256, 256, 0, stream>>>(tabA, colstats + 2 * 2 * HC, N);

    // ---- pool (BN3 inline) + z ----
    k_pool<<<512, HC, 0, stream>>>(tabA, batch, colstats + 2 * 2 * HC, g3, be3, invN,
                                   pooled, cntf, N);
    k_build_z<<<G, 192, 0, stream>>>(pooled, cntf, origin, direction, zbuf, G);

    // ---- dense head: split-K MFMA + reduce ----
    const int MN = G * DHID;
    const int rblk = (MN / 4 + 255) / 256;

    // layer 0: K = ZKP (160), 5 slices of 32
    gemm_head_sk<<<dim3(DHID / 64, (G + 31) / 32, 5), 256, 0, stream>>>(
        zbuf, wd0h, wd0l, kpart, G, DHID, ZKP, 32);
    k_reduce_br<<<rblk, 256, 0, stream>>>(kpart, bd0, t0, MN, DHID - 1, 5);

    // layer 1: K = 1024, 8 slices of 128
    gemm_head_sk<<<dim3(DHID / 64, (G + 31) / 32, 8), 256, 0, stream>>>(
        t0, wd1h, wd1l, kpart, G, DHID, DHID, 128);
    k_reduce_br<<<rblk, 256, 0, stream>>>(kpart, bd1, t1, MN, DHID - 1, 8);

    // layer 2: K = 1024, 8 slices of 128
    gemm_head_sk<<<dim3(DHID / 64, (G + 31) / 32, 8), 256, 0, stream>>>(
        t1, wd2h, wd2l, kpart, G, DHID, DHID, 128);
    k_reduce_br<<<rblk, 256, 0, stream>>>(kpart, bd2, t0, MN, DHID - 1, 8);

    k_dense_out<<<G, 256, 0, stream>>>(t0, Wout, bout, out, DHID);
}

// Round 8
// 451.677 us; speedup vs baseline: 6.0686x; 1.0109x over previous
//
#include <hip/hip_runtime.h>

#define HC 128      // hidden / latent channels
#define FIN 64
#define DHID 1024
#define ZK 134      // LAT + 6
#define ZKP 160     // ZK padded to multiple of 32 for MFMA head

typedef __attribute__((ext_vector_type(8))) short short8;
typedef __attribute__((ext_vector_type(8))) __bf16 bf16x8;
typedef __attribute__((ext_vector_type(4))) float f32x4;
typedef __attribute__((ext_vector_type(8))) unsigned short u16x8;
typedef __attribute__((ext_vector_type(4))) unsigned short u16x4;

union FragU { short8 s; bf16x8 b; u16x8 u; };

__device__ inline unsigned short rne_bf16(float x) {
    union { float f; unsigned u; } v; v.f = x;
    unsigned u = v.u;
    unsigned r = (u + 0x7fffu + ((u >> 16) & 1u)) >> 16;
    return (unsigned short)r;
}
__device__ inline float bf16_to_f(unsigned short h) {
    union { unsigned u; float f; } v; v.u = ((unsigned)h) << 16;
    return v.f;
}

// ---------------------------------------------------------------- small utils
__global__ void k_zero_i(int* p, int n) {
    int i = blockIdx.x * blockDim.x + threadIdx.x;
    if (i < n) p[i] = 0;
}

__global__ void k_deg_i(const int* __restrict__ dst, int* __restrict__ cnt, int E) {
    int i = blockIdx.x * blockDim.x + threadIdx.x;
    if (i < E) atomicAdd(&cnt[dst[i]], 1);
}

// x fp32 -> bf16 table
__global__ void k_xtobf(const float* __restrict__ x, unsigned short* __restrict__ xb, int n4) {
    int i = blockIdx.x * blockDim.x + threadIdx.x;
    if (i >= n4) return;
    float4 v = ((const float4*)x)[i];
    u16x4 o;
    o[0] = rne_bf16(v.x); o[1] = rne_bf16(v.y);
    o[2] = rne_bf16(v.z); o[3] = rne_bf16(v.w);
    ((u16x4*)xb)[i] = o;
}

// ---------------------------------------------------------------- scan (CSR row offsets) + dinv
__global__ void k_scan1(const int* __restrict__ cnt, int* __restrict__ part,
                        int* __restrict__ bsum, float* __restrict__ dinv, int N) {
    __shared__ int sh[256];
    int t = threadIdx.x, i = blockIdx.x * 256 + t;
    int v = (i < N) ? cnt[i] : 0;
    if (i < N) dinv[i] = rsqrtf((float)v + 1.0f);
    sh[t] = v; __syncthreads();
    #pragma unroll
    for (int off = 1; off < 256; off <<= 1) {
        int tv = (t >= off) ? sh[t - off] : 0;
        __syncthreads();
        sh[t] += tv;
        __syncthreads();
    }
    if (i < N) part[i] = sh[t] - v;
    if (t == 255) bsum[blockIdx.x] = sh[255];
}

__global__ void k_scan2(int* __restrict__ bsum, int nb) {
    __shared__ int sh[256];
    int t = threadIdx.x;
    int v = (t < nb) ? bsum[t] : 0;
    sh[t] = v; __syncthreads();
    #pragma unroll
    for (int off = 1; off < 256; off <<= 1) {
        int tv = (t >= off) ? sh[t - off] : 0;
        __syncthreads();
        sh[t] += tv;
        __syncthreads();
    }
    if (t < nb) bsum[t] = sh[t] - v;
}

__global__ void k_scan3(const int* __restrict__ part, const int* __restrict__ bsum,
                        int* __restrict__ row_start, int* __restrict__ cur, int N) {
    int i = blockIdx.x * 256 + threadIdx.x;
    if (i < N) { row_start[i] = part[i] + bsum[blockIdx.x]; cur[i] = 0; }
}

__global__ void k_scatter(const int* __restrict__ src, const int* __restrict__ dst,
                          const float* __restrict__ dinv, const int* __restrict__ row_start,
                          int* __restrict__ cur, int2* __restrict__ csr, int E) {
    int e = blockIdx.x * blockDim.x + threadIdx.x;
    if (e >= E) return;
    int s = src[e], d = dst[e];
    int pos = row_start[d] + atomicAdd(&cur[d], 1);
    int2 pk; pk.x = s; pk.y = __float_as_int(dinv[s] * dinv[d]);
    csr[pos] = pk;
}

// ---------------------------------------------------------------- gather (bf16 table -> bf16 out, fp32 accum)
template <int RF> struct BVec;
template <> struct BVec<64>  { using T = u16x4; static const int VPL = 4; };
template <> struct BVec<128> { using T = u16x8; static const int VPL = 8; };

// quarter-wave (16 lanes) per node; lane reads RF/16 features as one vector
template <int RF>
__global__ __launch_bounds__(256) void k_gather2b(const unsigned short* __restrict__ T,
                                                  const int2* __restrict__ csr,
                                                  const int* __restrict__ row_start,
                                                  const int* __restrict__ cnt,
                                                  const float* __restrict__ dinv,
                                                  unsigned short* __restrict__ agg, int N) {
    using vec = typename BVec<RF>::T;
    constexpr int VPL = BVec<RF>::VPL;
    int tid = threadIdx.x;
    int node = blockIdx.x * 16 + (tid >> 4);
    int q = tid & 15;
    if (node >= N) return;
    int beg = row_start[node];
    int end = beg + cnt[node];
    float d = dinv[node];
    vec sv = ((const vec*)(T + (size_t)node * RF))[q];
    float acc[VPL];
    #pragma unroll
    for (int i = 0; i < VPL; ++i) acc[i] = bf16_to_f(sv[i]) * d * d;
    int j = beg;
    for (; j + 8 <= end; j += 8) {
        int2 e[8];
        #pragma unroll
        for (int u = 0; u < 8; ++u) e[u] = csr[j + u];
        vec v[8];
        #pragma unroll
        for (int u = 0; u < 8; ++u) v[u] = ((const vec*)(T + (size_t)e[u].x * RF))[q];
        #pragma unroll
        for (int u = 0; u < 8; ++u) {
            float nn = __int_as_float(e[u].y);
            #pragma unroll
            for (int i = 0; i < VPL; ++i) acc[i] += bf16_to_f(v[u][i]) * nn;
        }
    }
    for (; j + 2 <= end; j += 2) {
        int2 e0 = csr[j], e1 = csr[j + 1];
        vec v0 = ((const vec*)(T + (size_t)e0.x * RF))[q];
        vec v1 = ((const vec*)(T + (size_t)e1.x * RF))[q];
        float n0 = __int_as_float(e0.y), n1 = __int_as_float(e1.y);
        #pragma unroll
        for (int i = 0; i < VPL; ++i)
            acc[i] += bf16_to_f(v0[i]) * n0 + bf16_to_f(v1[i]) * n1;
    }
    if (j < end) {
        int2 e0 = csr[j];
        vec v0 = ((const vec*)(T + (size_t)e0.x * RF))[q];
        float n0 = __int_as_float(e0.y);
        #pragma unroll
        for (int i = 0; i < VPL; ++i) acc[i] += bf16_to_f(v0[i]) * n0;
    }
    vec o;
    #pragma unroll
    for (int i = 0; i < VPL; ++i) o[i] = rne_bf16(acc[i]);
    ((vec*)(agg + (size_t)node * RF))[q] = o;
}

// ---------------------------------------------------------------- batchnorm stats (bf16 input)
__global__ void k_bn_reduce(const unsigned short* __restrict__ x, float* __restrict__ stat, int N) {
    int f = threadIdx.x & (HC - 1);
    int half = threadIdx.x >> 7;  // 0/1
    int rpb = (N + gridDim.x - 1) / gridDim.x;
    int r0 = blockIdx.x * rpb;
    int r1 = min(N, r0 + rpb);
    float s = 0.f, ss = 0.f;
    for (int r = r0 + half; r < r1; r += 2) {
        float v = bf16_to_f(x[(size_t)r * HC + f]);
        s += v; ss += v * v;
    }
    __shared__ float sh[256], shq[256];
    sh[threadIdx.x] = s; shq[threadIdx.x] = ss;
    __syncthreads();
    if (half == 0) {
        atomicAdd(&stat[f],      sh[threadIdx.x] + sh[threadIdx.x + HC]);
        atomicAdd(&stat[HC + f], shq[threadIdx.x] + shq[threadIdx.x + HC]);
    }
}

// scale/shift from stats (1 block, HC threads)
__global__ void k_bn_stats2(const float* __restrict__ stat, const float* __restrict__ gam,
                            const float* __restrict__ bet, float invN,
                            float* __restrict__ scale, float* __restrict__ shift) {
    int f = threadIdx.x;
    float m = stat[f] * invN;
    float var = stat[HC + f] * invN - m * m;
    float istd = rsqrtf(var + 1e-5f);
    float sc = gam[f] * istd;
    scale[f] = sc;
    shift[f] = bet[f] - m * sc;
}

// in-place BN+ReLU on bf16 table
__global__ void k_bn_apply2(unsigned short* __restrict__ t, const float* __restrict__ scale,
                            const float* __restrict__ shift, int total8) {
    int i = blockIdx.x * blockDim.x + threadIdx.x;
    if (i >= total8) return;
    int k0 = (i * 8) & (HC - 1);
    u16x8 v = ((const u16x8*)t)[i];
    u16x8 o;
    #pragma unroll
    for (int j = 0; j < 8; ++j) {
        float f = bf16_to_f(v[j]) * scale[k0 + j] + shift[k0 + j];
        o[j] = rne_bf16(fmaxf(f, 0.f));
    }
    ((u16x8*)t)[i] = o;
}

// ---------------------------------------------------------------- pooling (BN3 inline, bf16 input)
__global__ void k_pool(const unsigned short* __restrict__ h, const int* __restrict__ batch,
                       const float* __restrict__ stat, const float* __restrict__ gam,
                       const float* __restrict__ bet, float invN,
                       float* __restrict__ pooled, float* __restrict__ cnt, int N) {
    int t = threadIdx.x;  // 0..127
    float m = stat[t] * invN;
    float var = stat[HC + t] * invN - m * m;
    float istd = rsqrtf(var + 1e-5f);
    float scv = gam[t] * istd;
    float shv = bet[t] - m * scv;
    int rpb = (N + gridDim.x - 1) / gridDim.x;
    int r0 = blockIdx.x * rpb;
    int r1 = min(N, r0 + rpb);
    if (r0 >= r1) return;
    int curb = batch[r0];
    float acc = 0.f; float c = 0.f;
    for (int r = r0; r < r1; ++r) {
        int b = batch[r];
        if (b != curb) {
            atomicAdd(&pooled[curb * HC + t], acc);
            if (t == 0) atomicAdd(&cnt[curb], c);
            curb = b; acc = 0.f; c = 0.f;
        }
        acc += bf16_to_f(h[(size_t)r * HC + t]) * scv + shv;
        c += 1.f;
    }
    atomicAdd(&pooled[curb * HC + t], acc);
    if (t == 0) atomicAdd(&cnt[curb], c);
}

// build z padded to ZKP cols (pad = 0)
__global__ void k_build_z(const float* __restrict__ pooled, const float* __restrict__ cnt,
                          const float* __restrict__ origin, const float* __restrict__ dir,
                          float* __restrict__ z, int G) {
    int g = blockIdx.x;
    int t = threadIdx.x;
    if (t >= ZKP) return;
    float v = 0.f;
    if (t < HC) {
        float c = fmaxf(cnt[g], 1.0f);
        v = pooled[g * HC + t] / c;
    } else if (t < HC + 3) {
        v = origin[g * 3 + (t - HC)];
    } else if (t < HC + 6) {
        v = dir[g * 3 + (t - HC - 3)];
    }
    z[g * ZKP + t] = v;
}

// ---------------------------------------------------------------- W prep (all 3 GCN weights): fp32 [K][128] -> bf16 hi/lo transposed [128][K]
__global__ void k_wprep_all(const float* __restrict__ W1, const float* __restrict__ W2,
                            const float* __restrict__ W3,
                            unsigned short* __restrict__ w1h, unsigned short* __restrict__ w1l,
                            unsigned short* __restrict__ w2h, unsigned short* __restrict__ w2l,
                            unsigned short* __restrict__ w3h, unsigned short* __restrict__ w3l) {
    int i = blockIdx.x * blockDim.x + threadIdx.x;
    const float* W; unsigned short *th, *tl; int K, idx;
    if (i < FIN * HC)           { W = W1; th = w1h; tl = w1l; K = FIN; idx = i; }
    else if (i < FIN*HC + HC*HC){ W = W2; th = w2h; tl = w2l; K = HC;  idx = i - FIN*HC; }
    else if (i < FIN*HC + 2*HC*HC){ W = W3; th = w3h; tl = w3l; K = HC; idx = i - FIN*HC - HC*HC; }
    else return;
    int k = idx >> 7, n = idx & (HC - 1);
    float w = W[idx];
    unsigned short h = rne_bf16(w);
    th[n * K + k] = h;
    tl[n * K + k] = rne_bf16(w - bf16_to_f(h));
}

// ---------------------------------------------------------------- W prep (head): fp32 [K][NC] -> bf16 hi/lo transposed [NC][KP]
__global__ __launch_bounds__(256) void k_wprep2(const float* __restrict__ W,
                                                unsigned short* __restrict__ th,
                                                unsigned short* __restrict__ tl,
                                                int K, int KP, int NC) {
    __shared__ float tile[32][33];
    int kt = blockIdx.x * 32, nt = blockIdx.y * 32;
    int tx = threadIdx.x & 31, ty0 = threadIdx.x >> 5;
    #pragma unroll
    for (int i = 0; i < 4; ++i) {
        int ty = ty0 + i * 8;
        int k = kt + ty;
        float v = (k < K) ? W[(size_t)k * NC + nt + tx] : 0.f;
        tile[ty][tx] = v;
    }
    __syncthreads();
    #pragma unroll
    for (int i = 0; i < 4; ++i) {
        int ty = ty0 + i * 8;
        int n = nt + ty;
        int k = kt + tx;
        float w = tile[tx][ty];
        unsigned short h = rne_bf16(w);
        th[(size_t)n * KP + k] = h;
        tl[(size_t)n * KP + k] = rne_bf16(w - bf16_to_f(h));
    }
}

// ---------------------------------------------------------------- MFMA node GEMM (pure bf16 A)
// C[M,128] = A[M,KK] @ W[KK,128]; A raw bf16 (BN pre-applied), W hi/lo split.
// 512 thr = 8 waves (2 row x 4 col); wave = 16 rows x 32 cols; 64 rows/block.
template <int KK>
__global__ __launch_bounds__(512) void gemm_node2(const unsigned short* __restrict__ A,
                                                  const unsigned short* __restrict__ wth,
                                                  const unsigned short* __restrict__ wtl,
                                                  unsigned short* __restrict__ C, int M) {
    constexpr int KS = KK / 32;
    int tid = threadIdx.x;
    int lane = tid & 63, wid = tid >> 6;
    int rw = wid & 1, cg = wid >> 1;          // rw 0/1, cg 0..3
    int l15 = lane & 15, l4 = lane >> 4;
    int cbase = cg * 32;

    FragU bh[2][KS], bl[2][KS];
    #pragma unroll
    for (int ct = 0; ct < 2; ++ct) {
        int n = cbase + ct * 16 + l15;
        #pragma unroll
        for (int ks = 0; ks < KS; ++ks) {
            int k = ks * 32 + l4 * 8;
            bh[ct][ks].s = *(const short8*)(wth + (size_t)n * KK + k);
            bl[ct][ks].s = *(const short8*)(wtl + (size_t)n * KK + k);
        }
    }

    #pragma unroll
    for (int rt = 0; rt < 2; ++rt) {
        int m0 = blockIdx.x * 64 + rt * 32 + rw * 16;
        if (m0 < M) {
            int arow = min(m0 + l15, M - 1);
            f32x4 zero = {0.f, 0.f, 0.f, 0.f};
            f32x4 acc[2] = {zero, zero};
            #pragma unroll
            for (int ks = 0; ks < KS; ++ks) {
                int k0 = ks * 32 + l4 * 8;
                FragU a;
                a.u = *(const u16x8*)(A + (size_t)arow * KK + k0);
                #pragma unroll
                for (int ct = 0; ct < 2; ++ct) {
                    acc[ct] = __builtin_amdgcn_mfma_f32_16x16x32_bf16(a.b, bh[ct][ks].b, acc[ct], 0, 0, 0);
                    acc[ct] = __builtin_amdgcn_mfma_f32_16x16x32_bf16(a.b, bl[ct][ks].b, acc[ct], 0, 0, 0);
                }
            }
            #pragma unroll
            for (int ct = 0; ct < 2; ++ct) {
                int col = cbase + ct * 16 + l15;
                #pragma unroll
                for (int r = 0; r < 4; ++r) {
                    int row = m0 + l4 * 4 + r;
                    if (row < M)
                        C[(size_t)row * HC + col] = rne_bf16(acc[ct][r]);
                }
            }
        }
    }
}

// ---------------------------------------------------------------- MFMA head GEMM, split-K
__global__ __launch_bounds__(256) void gemm_head_sk(const float* __restrict__ A,
                                                    const unsigned short* __restrict__ wth,
                                                    const unsigned short* __restrict__ wtl,
                                                    float* __restrict__ Cpart,
                                                    int M, int N, int K, int slice) {
    int tid = threadIdx.x;
    int lane = tid & 63, wid = tid >> 6;
    int rw = wid & 1, cw = wid >> 1;
    int l15 = lane & 15, l4 = lane >> 4;
    int m0 = blockIdx.y * 32 + rw * 16;
    int cb = blockIdx.x * 64 + cw * 32;
    int z = blockIdx.z;
    int kbeg = z * slice;
    int kend = min(K, kbeg + slice);
    if (m0 >= M) return;

    int arow = m0 + l15;
    f32x4 zero = {0.f, 0.f, 0.f, 0.f};
    f32x4 acc[2] = {zero, zero};

    for (int k0 = kbeg; k0 < kend; k0 += 32) {
        int ka = k0 + l4 * 8;
        const float4 p0 = *(const float4*)(A + (size_t)arow * K + ka);
        const float4 p1 = *(const float4*)(A + (size_t)arow * K + ka + 4);
        float av[8] = {p0.x, p0.y, p0.z, p0.w, p1.x, p1.y, p1.z, p1.w};
        FragU ah, al;
        #pragma unroll
        for (int i = 0; i < 8; ++i) {
            unsigned short h = rne_bf16(av[i]);
            ah.s[i] = (short)h;
            al.s[i] = (short)rne_bf16(av[i] - bf16_to_f(h));
        }
        #pragma unroll
        for (int ct = 0; ct < 2; ++ct) {
            int n = cb + ct * 16 + l15;
            FragU bh, bl;
            bh.s = *(const short8*)(wth + (size_t)n * K + ka);
            bl.s = *(const short8*)(wtl + (size_t)n * K + ka);
            acc[ct] = __builtin_amdgcn_mfma_f32_16x16x32_bf16(ah.b, bh.b, acc[ct], 0, 0, 0);
            acc[ct] = __builtin_amdgcn_mfma_f32_16x16x32_bf16(ah.b, bl.b, acc[ct], 0, 0, 0);
            acc[ct] = __builtin_amdgcn_mfma_f32_16x16x32_bf16(al.b, bh.b, acc[ct], 0, 0, 0);
        }
    }

    float* Cz = Cpart + (size_t)z * M * N;
    #pragma unroll
    for (int ct = 0; ct < 2; ++ct) {
        int col = cb + ct * 16 + l15;
        #pragma unroll
        for (int r = 0; r < 4; ++r) {
            int row = m0 + l4 * 4 + r;
            Cz[(size_t)row * N + col] = acc[ct][r];
        }
    }
}

// sum NZ partials + bias + relu; N power of two (DHID)
__global__ void k_reduce_br(const float* __restrict__ part, const float* __restrict__ bias,
                            float* __restrict__ C, int MN, int Nmask, int NZ) {
    int i = (blockIdx.x * blockDim.x + threadIdx.x) * 4;
    if (i >= MN) return;
    float4 acc = *(const float4*)(part + i);
    for (int zz = 1; zz < NZ; ++zz) {
        float4 p = *(const float4*)(part + (size_t)zz * MN + i);
        acc.x += p.x; acc.y += p.y; acc.z += p.z; acc.w += p.w;
    }
    int n = i & Nmask;
    acc.x += bias[n]; acc.y += bias[n + 1]; acc.z += bias[n + 2]; acc.w += bias[n + 3];
    acc.x = fmaxf(acc.x, 0.f); acc.y = fmaxf(acc.y, 0.f);
    acc.z = fmaxf(acc.z, 0.f); acc.w = fmaxf(acc.w, 0.f);
    *(float4*)(C + i) = acc;
}

// final [G,DH] @ [DH,3] + bout
__global__ void k_dense_out(const float* __restrict__ z, const float* __restrict__ W,
                            const float* __restrict__ b, float* __restrict__ out, int K) {
    int g = blockIdx.x;
    const float* zr = z + (size_t)g * K;
    float a0 = 0.f, a1 = 0.f, a2 = 0.f;
    for (int k = threadIdx.x; k < K; k += blockDim.x) {
        float zv = zr[k];
        a0 += zv * W[k * 3 + 0];
        a1 += zv * W[k * 3 + 1];
        a2 += zv * W[k * 3 + 2];
    }
    __shared__ float s[768];
    s[threadIdx.x] = a0; s[256 + threadIdx.x] = a1; s[512 + threadIdx.x] = a2;
    __syncthreads();
    for (int off = 128; off > 0; off >>= 1) {
        if ((int)threadIdx.x < off) {
            s[threadIdx.x]       += s[threadIdx.x + off];
            s[256 + threadIdx.x] += s[256 + threadIdx.x + off];
            s[512 + threadIdx.x] += s[512 + threadIdx.x + off];
        }
        __syncthreads();
    }
    if (threadIdx.x == 0) {
        out[g * 3 + 0] = s[0]   + b[0];
        out[g * 3 + 1] = s[256] + b[1];
        out[g * 3 + 2] = s[512] + b[2];
    }
}

// ---------------------------------------------------------------- launch
extern "C" void kernel_launch(void* const* d_in, const int* in_sizes, int n_in,
                              void* d_out, int out_size, void* d_ws, size_t ws_size,
                              hipStream_t stream) {
    const float* x         = (const float*)d_in[0];
    const float* origin    = (const float*)d_in[1];
    const float* direction = (const float*)d_in[2];
    const int*   eidx      = (const int*)d_in[3];
    const int*   batch     = (const int*)d_in[4];
    const float* W1 = (const float*)d_in[5];
    const float* W2 = (const float*)d_in[7];
    const float* W3 = (const float*)d_in[9];
    const float* g1 = (const float*)d_in[11]; const float* be1 = (const float*)d_in[12];
    const float* g2 = (const float*)d_in[13]; const float* be2 = (const float*)d_in[14];
    const float* g3 = (const float*)d_in[15]; const float* be3 = (const float*)d_in[16];
    const float* Wd0 = (const float*)d_in[17]; const float* bd0 = (const float*)d_in[18];
    const float* Wd1 = (const float*)d_in[19]; const float* bd1 = (const float*)d_in[20];
    const float* Wd2 = (const float*)d_in[21]; const float* bd2 = (const float*)d_in[22];
    const float* Wout = (const float*)d_in[23]; const float* bout = (const float*)d_in[24];
    float* out = (float*)d_out;

    const int N = in_sizes[4];
    const int E = in_sizes[3] / 2;
    const int G = in_sizes[1] / 3;
    const int* src = eidx;
    const int* dst = eidx + E;

    char* ws = (char*)d_ws;
    size_t off = 0;
    auto alloc = [&](size_t nbytes) -> void* {
        void* p = (void*)(ws + off);
        off += (nbytes + 255) & ~(size_t)255;
        return p;
    };
    // zero-init region (one memset): colstats[3 slots x 2 x HC] | pooled | cntf
    float* colstats = (float*)alloc(3 * 2 * HC * 4);
    float* pooled   = (float*)alloc((size_t)G * HC * 4);
    float* cntf     = (float*)alloc((size_t)G * 4);
    const size_t zeroBytes = 3 * 2 * HC * 4 + (size_t)G * HC * 4 + (size_t)G * 4;

    float* dinv     = (float*)alloc((size_t)N * 4);
    int*   degcnt   = (int*)alloc((size_t)N * 4);
    int*   part     = (int*)alloc((size_t)N * 4);
    int*   bsum     = (int*)alloc(256 * 4);
    int*   row_start= (int*)alloc((size_t)N * 4);
    int*   cur      = (int*)alloc((size_t)N * 4);
    int2*  csr      = (int2*)alloc((size_t)E * 8);
    unsigned short* xb   = (unsigned short*)alloc((size_t)N * FIN * 2);
    unsigned short* aggx = (unsigned short*)alloc((size_t)N * FIN * 2);
    unsigned short* tabA = (unsigned short*)alloc((size_t)N * HC * 2);
    unsigned short* tabB = (unsigned short*)alloc((size_t)N * HC * 2);
    unsigned short* wt1h = (unsigned short*)alloc((size_t)FIN * HC * 2);
    unsigned short* wt1l = (unsigned short*)alloc((size_t)FIN * HC * 2);
    unsigned short* wt2h = (unsigned short*)alloc((size_t)HC * HC * 2);
    unsigned short* wt2l = (unsigned short*)alloc((size_t)HC * HC * 2);
    unsigned short* wt3h = (unsigned short*)alloc((size_t)HC * HC * 2);
    unsigned short* wt3l = (unsigned short*)alloc((size_t)HC * HC * 2);
    unsigned short* wd0h = (unsigned short*)alloc((size_t)DHID * ZKP * 2);
    unsigned short* wd0l = (unsigned short*)alloc((size_t)DHID * ZKP * 2);
    unsigned short* wd1h = (unsigned short*)alloc((size_t)DHID * DHID * 2);
    unsigned short* wd1l = (unsigned short*)alloc((size_t)DHID * DHID * 2);
    unsigned short* wd2h = (unsigned short*)alloc((size_t)DHID * DHID * 2);
    unsigned short* wd2l = (unsigned short*)alloc((size_t)DHID * DHID * 2);
    float* bnscale  = (float*)alloc(HC * 4);
    float* bnshift  = (float*)alloc(HC * 4);
    float* zbuf     = (float*)alloc((size_t)G * ZKP * 4);
    float* t0       = (float*)alloc((size_t)G * DHID * 4);
    float* t1       = (float*)alloc((size_t)G * DHID * 4);
    float* kpart    = (float*)alloc((size_t)8 * G * DHID * 4);   // 8 MB split-K partials
    (void)ws_size;

    const int nScanBlk = (N + 255) / 256;
    const int gemmBlk = (N + 63) / 64;
    const int gatherBlk = (N + 15) / 16;
    const int total8 = N * HC / 8;
    const float invN = 1.0f / (float)N;

    hipMemsetAsync(colstats, 0, zeroBytes, stream);

    // ---- weight prep + x conversion ----
    k_xtobf<<<(N * FIN / 4 + 255) / 256, 256, 0, stream>>>(x, xb, N * FIN / 4);
    k_wprep_all<<<(FIN * HC + 2 * HC * HC + 255) / 256, 256, 0, stream>>>(
        W1, W2, W3, wt1h, wt1l, wt2h, wt2l, wt3h, wt3l);
    k_wprep2<<<dim3(ZKP / 32, DHID / 32), 256, 0, stream>>>(Wd0, wd0h, wd0l, ZK, ZKP, DHID);
    k_wprep2<<<dim3(DHID / 32, DHID / 32), 256, 0, stream>>>(Wd1, wd1h, wd1l, DHID, DHID, DHID);
    k_wprep2<<<dim3(DHID / 32, DHID / 32), 256, 0, stream>>>(Wd2, wd2h, wd2l, DHID, DHID, DHID);

    // ---- CSR build ----
    k_zero_i<<<nScanBlk, 256, 0, stream>>>(degcnt, N);
    k_deg_i<<<(E + 255) / 256, 256, 0, stream>>>(dst, degcnt, E);
    k_scan1<<<nScanBlk, 256, 0, stream>>>(degcnt, part, bsum, dinv, N);
    k_scan2<<<1, 256, 0, stream>>>(bsum, nScanBlk);
    k_scan3<<<nScanBlk, 256, 0, stream>>>(part, bsum, row_start, cur, N);
    k_scatter<<<(E + 255) / 256, 256, 0, stream>>>(src, dst, dinv, row_start, cur, csr, E);

    // ---- layer 1: gather(x) -> gemm -> stats0 ----
    k_gather2b<FIN><<<gatherBlk, 256, 0, stream>>>(xb, csr, row_start, degcnt, dinv, aggx, N);
    gemm_node2<FIN><<<gemmBlk, 512, 0, stream>>>(aggx, wt1h, wt1l, tabA, N);
    k_bn_reduce<<<256, 256, 0, stream>>>(tabA, colstats + 0 * 2 * HC, N);

    // ---- layer 2: BN1 apply -> gemm -> gather -> stats1 ----
    k_bn_stats2<<<1, HC, 0, stream>>>(colstats + 0 * 2 * HC, g1, be1, invN, bnscale, bnshift);
    k_bn_apply2<<<(total8 + 255) / 256, 256, 0, stream>>>(tabA, bnscale, bnshift, total8);
    gemm_node2<HC><<<gemmBlk, 512, 0, stream>>>(tabA, wt2h, wt2l, tabB, N);
    k_gather2b<HC><<<gatherBlk, 256, 0, stream>>>(tabB, csr, row_start, degcnt, dinv, tabA, N);
    k_bn_reduce<<<256, 256, 0, stream>>>(tabA, colstats + 1 * 2 * HC, N);

    // ---- layer 3 ----
    k_bn_stats2<<<1, HC, 0, stream>>>(colstats + 1 * 2 * HC, g2, be2, invN, bnscale, bnshift);
    k_bn_apply2<<<(total8 + 255) / 256, 256, 0, stream>>>(tabA, bnscale, bnshift, total8);
    gemm_node2<HC><<<gemmBlk, 512, 0, stream>>>(tabA, wt3h, wt3l, tabB, N);
    k_gather2b<HC><<<gatherBlk, 256, 0, stream>>>(tabB, csr, row_start, degcnt, dinv, tabA, N);
    k_bn_reduce<<<256, 256, 0, stream>>>(tabA, colstats + 2 * 2 * HC, N);

    // ---- pool (BN3 inline) + z ----
    k_pool<<<512, HC, 0, stream>>>(tabA, batch, colstats + 2 * 2 * HC, g3, be3, invN,
                                   pooled, cntf, N);
    k_build_z<<<G, 192, 0, stream>>>(pooled, cntf, origin, direction, zbuf, G);

    // ---- dense head: split-K MFMA + reduce ----
    const int MN = G * DHID;
    const int rblk = (MN / 4 + 255) / 256;

    gemm_head_sk<<<dim3(DHID / 64, (G + 31) / 32, 5), 256, 0, stream>>>(
        zbuf, wd0h, wd0l, kpart, G, DHID, ZKP, 32);
    k_reduce_br<<<rblk, 256, 0, stream>>>(kpart, bd0, t0, MN, DHID - 1, 5);

    gemm_head_sk<<<dim3(DHID / 64, (G + 31) / 32, 8), 256, 0, stream>>>(
        t0, wd1h, wd1l, kpart, G, DHID, DHID, 128);
    k_reduce_br<<<rblk, 256, 0, stream>>>(kpart, bd1, t1, MN, DHID - 1, 8);

    gemm_head_sk<<<dim3(DHID / 64, (G + 31) / 32, 8), 256, 0, stream>>>(
        t1, wd2h, wd2l, kpart, G, DHID, DHID, 128);
    k_reduce_br<<<rblk, 256, 0, stream>>>(kpart, bd2, t0, MN, DHID - 1, 8);

    k_dense_out<<<G, 256, 0, stream>>>(t0, Wout, bout, out, DHID);
}